// Round 9
// baseline (865.931 us; speedup 1.0000x reference)
//
#include <hip/hip_runtime.h>
#include <stdint.h>

#define B_ 2
#define T_ 2048
#define C_ 2048
#define F_ 8192
#define M_ 4096   // B_*T_
#define BC_ 4096  // B_*C_
#define CHB 16    // channels per WKV block
#define TCH 16    // time chunks per WKV block
#define LC2 128   // T_/TCH

typedef __attribute__((ext_vector_type(8))) __bf16 bf16x8;
typedef __attribute__((ext_vector_type(4))) float f32x4;

__device__ __forceinline__ unsigned short f2bf(float f) {
  union { float f; unsigned u; } v; v.f = f;
  unsigned r = v.u + 0x7fffu + ((v.u >> 16) & 1u);
  return (unsigned short)(r >> 16);
}
__device__ __forceinline__ float b2f(unsigned short h) {
  union { unsigned u; float f; } v; v.u = ((unsigned)h) << 16; return v.f;
}

__device__ __forceinline__ void gload16(const void* g, void* l) {
  __builtin_amdgcn_global_load_lds((__attribute__((address_space(1))) void*)g,
                                   (__attribute__((address_space(3))) void*)l,
                                   16, 0, 0);
}

// ---------- transpose + f32->bf16: WT[n][k] = W[k][n] ----------
__global__ __launch_bounds__(256) void k_transpose_cast(
    const float* __restrict__ W, unsigned short* __restrict__ WT, int K, int N) {
  __shared__ unsigned short tile[32][33];
  const int n0 = blockIdx.x * 32, k0 = blockIdx.y * 32;
  const int tx = threadIdx.x & 31, ty = threadIdx.x >> 5;
#pragma unroll
  for (int i = 0; i < 4; ++i)
    tile[ty + 8 * i][tx] = f2bf(W[(size_t)(k0 + ty + 8 * i) * N + n0 + tx]);
  __syncthreads();
#pragma unroll
  for (int i = 0; i < 4; ++i)
    WT[(size_t)(n0 + ty + 8 * i) * K + k0 + tx] = tile[tx][ty + 8 * i];
}

// ---------- block-wide row-stat reduction helper (256 thr, 8 vals/thr) ----------
__device__ __forceinline__ void row_stats(const float* lv, float* rs, float* rq,
                                          float& mean, float& inv) {
  float s = 0.f, q = 0.f;
#pragma unroll
  for (int j = 0; j < 8; ++j) { s += lv[j]; q += lv[j] * lv[j]; }
#pragma unroll
  for (int o = 32; o > 0; o >>= 1) { s += __shfl_down(s, o); q += __shfl_down(q, o); }
  if ((threadIdx.x & 63) == 0) { rs[threadIdx.x >> 6] = s; rq[threadIdx.x >> 6] = q; }
  __syncthreads();
  s = rs[0] + rs[1] + rs[2] + rs[3];
  q = rq[0] + rq[1] + rq[2] + rq[3];
  __syncthreads();
  mean = s * (1.f / C_);
  const float var = q * (1.f / C_) - mean * mean;
  inv = 1.f / sqrtf(var + 1e-5f);
}

// ---------- fused LN1 + attention token-shift mix (3 outputs) ----------
__global__ __launch_bounds__(256) void k_ln_mix3(
    const float* __restrict__ x, const float* __restrict__ shift,
    const float* __restrict__ g, const float* __restrict__ be,
    const float* __restrict__ tmk, const float* __restrict__ tmv,
    const float* __restrict__ tmr,
    unsigned short* __restrict__ xk, unsigned short* __restrict__ xv,
    unsigned short* __restrict__ xr, float* __restrict__ last_out) {
  __shared__ float rs[4], rq[4];
  const int row = blockIdx.x;
  const int t = row & (T_ - 1);
  const int bi = row >> 11;
  const int base = threadIdx.x * 8;
  const float* xc = x + (size_t)row * C_;
  float cv[8];
  {
    float4 a = *(const float4*)(xc + base);
    float4 b = *(const float4*)(xc + base + 4);
    cv[0]=a.x; cv[1]=a.y; cv[2]=a.z; cv[3]=a.w; cv[4]=b.x; cv[5]=b.y; cv[6]=b.z; cv[7]=b.w;
  }
  float mean0, inv0;
  row_stats(cv, rs, rq, mean0, inv0);
  float pv[8];
  if (t == 0) {
    const float* sp = shift + (size_t)bi * C_ + base;
#pragma unroll
    for (int j = 0; j < 8; ++j) pv[j] = sp[j];
  } else {
    const float* xp = xc - C_;
    float pw[8];
    float4 a = *(const float4*)(xp + base);
    float4 b = *(const float4*)(xp + base + 4);
    pw[0]=a.x; pw[1]=a.y; pw[2]=a.z; pw[3]=a.w; pw[4]=b.x; pw[5]=b.y; pw[6]=b.z; pw[7]=b.w;
    float mean1, inv1;
    row_stats(pw, rs, rq, mean1, inv1);
#pragma unroll
    for (int j = 0; j < 8; ++j)
      pv[j] = (pw[j] - mean1) * inv1 * g[base + j] + be[base + j];
  }
  unsigned short ok[8], ov[8], orr[8];
  float cl[8];
#pragma unroll
  for (int j = 0; j < 8; ++j) {
    cl[j] = (cv[j] - mean0) * inv0 * g[base + j] + be[base + j];
    const float mk = tmk[base + j], mv = tmv[base + j], mr = tmr[base + j];
    ok[j]  = f2bf(cl[j] * mk + pv[j] * (1.f - mk));
    ov[j]  = f2bf(cl[j] * mv + pv[j] * (1.f - mv));
    orr[j] = f2bf(cl[j] * mr + pv[j] * (1.f - mr));
  }
  const size_t o = (size_t)row * C_ + base;
  *(uint4*)(xk + o) = *(uint4*)ok;
  *(uint4*)(xv + o) = *(uint4*)ov;
  *(uint4*)(xr + o) = *(uint4*)orr;
  if (t == T_ - 1) {
    float* lp = last_out + (size_t)bi * C_ + base;
    *(float4*)lp = make_float4(cl[0], cl[1], cl[2], cl[3]);
    *(float4*)(lp + 4) = make_float4(cl[4], cl[5], cl[6], cl[7]);
  }
}

// ---------- fused LN2 + ffn token-shift mix (2 outputs) ----------
__global__ __launch_bounds__(256) void k_ln_mix2(
    const float* __restrict__ x, const float* __restrict__ shift,
    const float* __restrict__ g, const float* __restrict__ be,
    const float* __restrict__ fmk, const float* __restrict__ fmr,
    unsigned short* __restrict__ xk2, unsigned short* __restrict__ xr2,
    float* __restrict__ last_out) {
  __shared__ float rs[4], rq[4];
  const int row = blockIdx.x;
  const int t = row & (T_ - 1);
  const int bi = row >> 11;
  const int base = threadIdx.x * 8;
  const float* xc = x + (size_t)row * C_;
  float cv[8];
  {
    float4 a = *(const float4*)(xc + base);
    float4 b = *(const float4*)(xc + base + 4);
    cv[0]=a.x; cv[1]=a.y; cv[2]=a.z; cv[3]=a.w; cv[4]=b.x; cv[5]=b.y; cv[6]=b.z; cv[7]=b.w;
  }
  float mean0, inv0;
  row_stats(cv, rs, rq, mean0, inv0);
  float pv[8];
  if (t == 0) {
    const float* sp = shift + (size_t)bi * C_ + base;
#pragma unroll
    for (int j = 0; j < 8; ++j) pv[j] = sp[j];
  } else {
    const float* xp = xc - C_;
    float pw[8];
    float4 a = *(const float4*)(xp + base);
    float4 b = *(const float4*)(xp + base + 4);
    pw[0]=a.x; pw[1]=a.y; pw[2]=a.z; pw[3]=a.w; pw[4]=b.x; pw[5]=b.y; pw[6]=b.z; pw[7]=b.w;
    float mean1, inv1;
    row_stats(pw, rs, rq, mean1, inv1);
#pragma unroll
    for (int j = 0; j < 8; ++j)
      pv[j] = (pw[j] - mean1) * inv1 * g[base + j] + be[base + j];
  }
  unsigned short ok[8], orr[8];
  float cl[8];
#pragma unroll
  for (int j = 0; j < 8; ++j) {
    cl[j] = (cv[j] - mean0) * inv0 * g[base + j] + be[base + j];
    const float mk = fmk[base + j], mr = fmr[base + j];
    ok[j]  = f2bf(cl[j] * mk + pv[j] * (1.f - mk));
    orr[j] = f2bf(cl[j] * mr + pv[j] * (1.f - mr));
  }
  const size_t o = (size_t)row * C_ + base;
  *(uint4*)(xk2 + o) = *(uint4*)ok;
  *(uint4*)(xr2 + o) = *(uint4*)orr;
  if (t == T_ - 1) {
    float* lp = last_out + (size_t)bi * C_ + base;
    *(float4*)lp = make_float4(cl[0], cl[1], cl[2], cl[3]);
    *(float4*)(lp + 4) = make_float4(cl[4], cl[5], cl[6], cl[7]);
  }
}

// ---------- WKV block-local chunked scan, fused with sigmoid(r)*y ----------
__global__ __launch_bounds__(256) void k_wkv_blk(
    const float* __restrict__ kk, const float* __restrict__ vv,
    const unsigned short* __restrict__ rr,
    const float* __restrict__ td, const float* __restrict__ tf,
    const float* __restrict__ st, unsigned short* __restrict__ sry,
    float* __restrict__ out_state) {
  __shared__ float sA[TCH][CHB], sB[TCH][CHB], sP[TCH][CHB];
  const int blk = blockIdx.x;
  const int bi = blk >> 7;
  const int tx = threadIdx.x & 15;
  const int ty = threadIdx.x >> 4;
  const int c = ((blk & 127) * CHB) + tx;
  const float w = -expf(td[c]);
  const float u = tf[c];
  const size_t base = (size_t)bi * T_ * C_ + (size_t)ty * LC2 * C_ + c;
  const float* kp = kk + base;
  const float* vp = vv + base;
  float aa = 0.f, bb = 0.f, pp = -1e38f;
#pragma unroll 8
  for (int i = 0; i < LC2; ++i) {
    const float kt = kp[(size_t)i * C_], vt = vp[(size_t)i * C_];
    const float ww2 = pp + w;
    const float p2 = fmaxf(ww2, kt);
    const float e1b = expf(ww2 - p2), e2b = expf(kt - p2);
    aa = e1b * aa + e2b * vt;
    bb = e1b * bb + e2b;
    pp = p2;
  }
  sA[ty][tx] = aa; sB[ty][tx] = bb; sP[ty][tx] = pp;
  __syncthreads();
  if (ty == 0) {
    const float* s0 = st + (size_t)bi * 3 * C_;
    float ca = s0[c], cb = s0[C_ + c], cp = s0[2 * C_ + c];
    const float wL = w * (float)LC2;
#pragma unroll
    for (int j = 0; j < TCH; ++j) {
      const float a2 = sA[j][tx], b2 = sB[j][tx], p2 = sP[j][tx];
      sA[j][tx] = ca; sB[j][tx] = cb; sP[j][tx] = cp;   // exclusive start
      const float pd = cp + wL;
      const float pm = fmaxf(pd, p2);
      const float e1 = expf(pd - pm), e2 = expf(p2 - pm);
      ca = e1 * ca + e2 * a2;
      cb = e1 * cb + e2 * b2;
      cp = pm;
    }
  }
  __syncthreads();
  aa = sA[ty][tx]; bb = sB[ty][tx]; pp = sP[ty][tx];
  const unsigned short* rp = rr + base;
  unsigned short* sp2 = sry + base;
#pragma unroll 4
  for (int i = 0; i < LC2; ++i) {
    const float kt = kp[(size_t)i * C_], vt = vp[(size_t)i * C_];
    const float ww = u + kt;
    const float p = fmaxf(pp, ww);
    const float e1 = expf(pp - p), e2 = expf(ww - p);
    const float yv = (e1 * aa + e2 * vt) / (e1 * bb + e2);
    const float rv = b2f(rp[(size_t)i * C_]);
    const float sg = 1.f / (1.f + expf(-rv));
    sp2[(size_t)i * C_] = f2bf(sg * yv);
    const float ww2 = pp + w;
    const float p2 = fmaxf(ww2, kt);
    const float e1b = expf(ww2 - p2), e2b = expf(kt - p2);
    aa = e1b * aa + e2b * vt;
    bb = e1b * bb + e2b;
    pp = p2;
  }
  if (ty == TCH - 1) {
    float* ob = out_state + (size_t)bi * 3 * C_;
    ob[c] = aa; ob[C_ + c] = bb; ob[2 * C_ + c] = pp;
  }
}

// ---------- bf16 MFMA GEMM, 128x128 tile, BK=32, global_load_lds ----------
// A: [M][K] bf16 row-major; BT: [N][K] bf16 row-major. C[M][N] = A * BT^T.
// SWZ: XCD-aware bijective block swizzle (only for HBM-bound working sets).
// EPI 0: f32 store; 1: bf16(relu(acc)^2); 2: f32(aux1+acc);
// EPI 3: f32(aux1+sigmoid(acc)*aux2); 4: bf16 plain
template <int EPI, int SWZ>
__global__ __launch_bounds__(256, 2) void k_gemm(
    const unsigned short* __restrict__ A, const unsigned short* __restrict__ BT,
    int K, int Nn, void* __restrict__ out,
    const float* __restrict__ aux1, const float* __restrict__ aux2) {
  __shared__ unsigned short lds_a[128 * 32];
  __shared__ unsigned short lds_b[128 * 32];
  const int tid = threadIdx.x;
  const int lane = tid & 63;
  const int wv = tid >> 6;
  int mBase, nBase;
  if (SWZ) {
    const int gx = gridDim.x;
    int wg = blockIdx.y * gx + blockIdx.x;
    const int nwg = gx * gridDim.y;
    wg = (wg & 7) * (nwg >> 3) + (wg >> 3);   // grids here are multiples of 8
    mBase = (wg / gx) * 128;
    nBase = (wg % gx) * 128;
  } else {
    mBase = blockIdx.y * 128;
    nBase = blockIdx.x * 128;
  }
  const int wr = (wv >> 1) * 64;
  const int wc = (wv & 1) * 64;
  const int r16 = lane & 15, kq = lane >> 4;
  const int srow = lane >> 2;          // row within 16-row chunk
  const int scol = (lane & 3) * 16;    // byte offset within 64B row
  const size_t strideA = (size_t)K * 2;
  f32x4 acc[4][4] = {};

  const int nk = K >> 5;
  for (int kt = 0; kt < nk; ++kt) {
    const size_t kb = (size_t)kt * 64;
#pragma unroll
    for (int i = 0; i < 2; ++i) {
      const int chunk = i * 4 + wv;
      const int row = chunk * 16 + srow;
      gload16((const char*)A + (size_t)(mBase + row) * strideA + kb + scol,
              &lds_a[chunk * 512]);
      gload16((const char*)BT + (size_t)(nBase + row) * strideA + kb + scol,
              &lds_b[chunk * 512]);
    }
    __syncthreads();
    bf16x8 af[4], bfr[4];
#pragma unroll
    for (int m = 0; m < 4; ++m)
      af[m] = *(const bf16x8*)&lds_a[(wr + m * 16 + r16) * 32 + kq * 8];
#pragma unroll
    for (int n = 0; n < 4; ++n)
      bfr[n] = *(const bf16x8*)&lds_b[(wc + n * 16 + r16) * 32 + kq * 8];
#pragma unroll
    for (int m = 0; m < 4; ++m)
#pragma unroll
      for (int n = 0; n < 4; ++n)
        acc[m][n] = __builtin_amdgcn_mfma_f32_16x16x32_bf16(af[m], bfr[n], acc[m][n], 0, 0, 0);
    __syncthreads();
  }

  const int c0 = kq * 4;
#pragma unroll
  for (int m = 0; m < 4; ++m) {
#pragma unroll
    for (int n = 0; n < 4; ++n) {
      const int col = nBase + wc + n * 16 + r16;
#pragma unroll
      for (int e = 0; e < 4; ++e) {
        const int rowg = mBase + wr + m * 16 + c0 + e;
        const size_t idx = (size_t)rowg * Nn + col;
        const float va = acc[m][n][e];
        if (EPI == 0) {
          ((float*)out)[idx] = va;
        } else if (EPI == 1) {
          const float t = va > 0.f ? va : 0.f;
          ((unsigned short*)out)[idx] = f2bf(t * t);
        } else if (EPI == 2) {
          ((float*)out)[idx] = aux1[idx] + va;
        } else if (EPI == 3) {
          const float s = 1.f / (1.f + expf(-va));
          ((float*)out)[idx] = aux1[idx] + s * aux2[idx];
        } else {
          ((unsigned short*)out)[idx] = f2bf(va);
        }
      }
    }
  }
}

extern "C" void kernel_launch(void* const* d_in, const int* in_sizes, int n_in,
                              void* d_out, int out_size, void* d_ws, size_t ws_size,
                              hipStream_t stream) {
  const float* x          = (const float*)d_in[0];
  const float* att_shift  = (const float*)d_in[1];
  const float* wkv_state  = (const float*)d_in[2];
  const float* ffn_shift  = (const float*)d_in[3];
  const float* ln1_g = (const float*)d_in[4];
  const float* ln1_b = (const float*)d_in[5];
  const float* ln2_g = (const float*)d_in[6];
  const float* ln2_b = (const float*)d_in[7];
  const float* tmk = (const float*)d_in[8];
  const float* tmv = (const float*)d_in[9];
  const float* tmr = (const float*)d_in[10];
  const float* time_decay = (const float*)d_in[11];
  const float* time_first = (const float*)d_in[12];
  const float* Wk = (const float*)d_in[13];
  const float* Wv = (const float*)d_in[14];
  const float* Wr = (const float*)d_in[15];
  const float* Wo = (const float*)d_in[16];
  const float* fmk = (const float*)d_in[17];
  const float* fmr = (const float*)d_in[18];
  const float* Fk = (const float*)d_in[19];
  const float* Fr = (const float*)d_in[20];
  const float* Fv = (const float*)d_in[21];

  // ---- 176 MiB workspace, strictly sequential reuse, zero in-flight overlap ----
  const size_t MB = 1ull << 20;
  char* ws = (char*)d_ws;
  if (ws_size < 176 * MB) return;

  unsigned short* Wslot = (unsigned short*)(ws);             //   0.. 32 weight slot
  float*          kBuf  = (float*)(ws + 32 * MB);            //  32.. 64 k f32
  float*          vBuf  = (float*)(ws + 64 * MB);            //  64.. 96 v f32
  float*          yBuf  = (float*)(ws + 96 * MB);            //  96..128 x_att f32
  unsigned short* h1    = (unsigned short*)(ws + 128 * MB);  // 128..144 r bf16
  unsigned short* h2    = (unsigned short*)(ws + 144 * MB);  // 144..160 xk -> sry -> xk2
  unsigned short* h3    = (unsigned short*)(ws + 160 * MB);  // 160..176 xv -> xr2
  unsigned short* xrT   = (unsigned short*)kBuf;             // xr bf16, before k exists
  unsigned short* kf    = (unsigned short*)kBuf;             // 64 MiB: 32..96 (k,v dead)
  float*          kv    = (float*)h1;                        // 32 MiB: 128..160 (r,xk2 dead)

  // ---- f32 outputs, concatenated in reference return order ----
  float* outb    = (float*)d_out;
  float* x1_last = outb + (size_t)M_ * C_;        // [B,C]
  float* wkv_out = x1_last + (size_t)B_ * C_;     // [B,3,C]
  float* x2_last = wkv_out + (size_t)B_ * 3 * C_; // [B,C]

  const dim3 gCC(C_ / 32, C_ / 32);
  const dim3 gC(C_ / 128, M_ / 128);

  // ---- attention path ----
  k_ln_mix3<<<M_, 256, 0, stream>>>(x, att_shift, ln1_g, ln1_b, tmk, tmv, tmr,
                                    h2, h3, xrT, x1_last);                     // xk,xv,xr
  k_transpose_cast<<<gCC, 256, 0, stream>>>(Wr, Wslot, C_, C_);
  k_gemm<4,0><<<gC, 256, 0, stream>>>(xrT, Wslot, C_, C_, h1, nullptr, nullptr); // r bf16 -> h1
  k_transpose_cast<<<gCC, 256, 0, stream>>>(Wk, Wslot, C_, C_);
  k_gemm<0,0><<<gC, 256, 0, stream>>>(h2, Wslot, C_, C_, kBuf, nullptr, nullptr); // k f32 (over xr, dead)
  k_transpose_cast<<<gCC, 256, 0, stream>>>(Wv, Wslot, C_, C_);
  k_gemm<0,0><<<gC, 256, 0, stream>>>(h3, Wslot, C_, C_, vBuf, nullptr, nullptr); // v f32
  // WKV fused with sigmoid(r)*y: reads k,v,r; writes sry bf16 -> h2 (xk dead)
  k_wkv_blk<<<dim3(BC_ / CHB), 256, 0, stream>>>(kBuf, vBuf, h1, time_decay, time_first,
                                                 wkv_state, h2, wkv_out);
  k_transpose_cast<<<gCC, 256, 0, stream>>>(Wo, Wslot, C_, C_);
  k_gemm<2,0><<<gC, 256, 0, stream>>>(h2, Wslot, C_, C_, yBuf, x, nullptr);       // x_att f32

  // ---- ffn path ----
  k_ln_mix2<<<M_, 256, 0, stream>>>(yBuf, ffn_shift, ln2_g, ln2_b, fmk, fmr,
                                    h2, h3, x2_last);                           // xk2,xr2 (sry,xv dead)
  k_transpose_cast<<<dim3(F_ / 32, C_ / 32), 256, 0, stream>>>(Fk, Wslot, C_, F_);
  k_gemm<1,1><<<dim3(F_ / 128, M_ / 128), 256, 0, stream>>>(h2, Wslot, C_, F_, kf,
                                                            nullptr, nullptr);    // kf bf16 (k,v dead)
  k_transpose_cast<<<dim3(C_ / 32, F_ / 32), 256, 0, stream>>>(Fv, Wslot, F_, C_);
  k_gemm<0,1><<<gC, 256, 0, stream>>>(kf, Wslot, F_, C_, kv, nullptr, nullptr);   // kv f32 (r,xk2 dead)
  k_transpose_cast<<<gCC, 256, 0, stream>>>(Fr, Wslot, C_, C_);
  k_gemm<3,0><<<gC, 256, 0, stream>>>(h3, Wslot, C_, C_, d_out, yBuf, kv);        // final f32
}

// Round 10
// 809.564 us; speedup vs baseline: 1.0696x; 1.0696x over previous
//
#include <hip/hip_runtime.h>
#include <stdint.h>

#define B_ 2
#define T_ 2048
#define C_ 2048
#define F_ 8192
#define M_ 4096   // B_*T_
#define BC_ 4096  // B_*C_
#define CHB 16    // channels per WKV block
#define TCH 16    // time chunks per WKV block
#define LC2 128   // T_/TCH

typedef __attribute__((ext_vector_type(8))) __bf16 bf16x8;
typedef __attribute__((ext_vector_type(4))) float f32x4;

__device__ __forceinline__ unsigned short f2bf(float f) {
  union { float f; unsigned u; } v; v.f = f;
  unsigned r = v.u + 0x7fffu + ((v.u >> 16) & 1u);
  return (unsigned short)(r >> 16);
}
__device__ __forceinline__ float b2f(unsigned short h) {
  union { unsigned u; float f; } v; v.u = ((unsigned)h) << 16; return v.f;
}

__device__ __forceinline__ void gload16(const void* g, void* l) {
  __builtin_amdgcn_global_load_lds((__attribute__((address_space(1))) void*)g,
                                   (__attribute__((address_space(3))) void*)l,
                                   16, 0, 0);
}

// ---------- transpose + f32->bf16: WT[n][k] = W[k][n] ----------
__global__ __launch_bounds__(256) void k_transpose_cast(
    const float* __restrict__ W, unsigned short* __restrict__ WT, int K, int N) {
  __shared__ unsigned short tile[32][33];
  const int n0 = blockIdx.x * 32, k0 = blockIdx.y * 32;
  const int tx = threadIdx.x & 31, ty = threadIdx.x >> 5;
#pragma unroll
  for (int i = 0; i < 4; ++i)
    tile[ty + 8 * i][tx] = f2bf(W[(size_t)(k0 + ty + 8 * i) * N + n0 + tx]);
  __syncthreads();
#pragma unroll
  for (int i = 0; i < 4; ++i)
    WT[(size_t)(n0 + ty + 8 * i) * K + k0 + tx] = tile[tx][ty + 8 * i];
}

// ---------- LayerNorm over C=2048 (f32 in, bf16 out + f32 last-row out) ----------
__global__ __launch_bounds__(256) void k_layernorm(
    const float* __restrict__ x, const float* __restrict__ g,
    const float* __restrict__ beta, unsigned short* __restrict__ y,
    float* __restrict__ last_out) {
  const int row = blockIdx.x;
  const int t = row & (T_ - 1);
  const int bi = row >> 11;
  const float* xr = x + (size_t)row * C_;
  const int base = threadIdx.x * 8;
  float lv[8];
  {
    float4 a = *(const float4*)(xr + base);
    float4 b = *(const float4*)(xr + base + 4);
    lv[0]=a.x; lv[1]=a.y; lv[2]=a.z; lv[3]=a.w; lv[4]=b.x; lv[5]=b.y; lv[6]=b.z; lv[7]=b.w;
  }
  float s = 0.f, q = 0.f;
#pragma unroll
  for (int j = 0; j < 8; ++j) { s += lv[j]; q += lv[j] * lv[j]; }
#pragma unroll
  for (int o = 32; o > 0; o >>= 1) { s += __shfl_down(s, o); q += __shfl_down(q, o); }
  __shared__ float rs[4], rq[4];
  if ((threadIdx.x & 63) == 0) { rs[threadIdx.x >> 6] = s; rq[threadIdx.x >> 6] = q; }
  __syncthreads();
  s = rs[0] + rs[1] + rs[2] + rs[3];
  q = rq[0] + rq[1] + rq[2] + rq[3];
  const float mean = s * (1.f / C_);
  const float var = q * (1.f / C_) - mean * mean;
  const float inv = 1.f / sqrtf(var + 1e-5f);
  float ov[8];
  unsigned short o8[8];
#pragma unroll
  for (int j = 0; j < 8; ++j) {
    ov[j] = (lv[j] - mean) * inv * g[base + j] + beta[base + j];
    o8[j] = f2bf(ov[j]);
  }
  *(uint4*)(y + (size_t)row * C_ + base) = *(uint4*)o8;
  if (last_out != nullptr && t == T_ - 1) {
    float* lp = last_out + (size_t)bi * C_ + base;
    *(float4*)lp = make_float4(ov[0], ov[1], ov[2], ov[3]);
    *(float4*)(lp + 4) = make_float4(ov[4], ov[5], ov[6], ov[7]);
  }
}

// ---------- token-shift mix (attention: 3 outputs), bf16 in/out ----------
__global__ __launch_bounds__(256) void k_mix3(
    const unsigned short* __restrict__ x1, const float* __restrict__ shift,
    const float* __restrict__ tmk, const float* __restrict__ tmv,
    const float* __restrict__ tmr,
    unsigned short* __restrict__ xk, unsigned short* __restrict__ xv,
    unsigned short* __restrict__ xr) {
  const int row = blockIdx.x;
  const int t = row & (T_ - 1);
  const int bi = row >> 11;
  const int c0 = threadIdx.x * 8;
  const size_t o = (size_t)row * C_ + c0;
  unsigned short cur8[8];
  *(uint4*)cur8 = *(const uint4*)(x1 + o);
  float pv[8];
  if (t == 0) {
    const float* sp = shift + (size_t)bi * C_ + c0;
#pragma unroll
    for (int j = 0; j < 8; ++j) pv[j] = sp[j];
  } else {
    unsigned short p8[8];
    *(uint4*)p8 = *(const uint4*)(x1 + o - C_);
#pragma unroll
    for (int j = 0; j < 8; ++j) pv[j] = b2f(p8[j]);
  }
  unsigned short ok[8], ov[8], orr[8];
#pragma unroll
  for (int j = 0; j < 8; ++j) {
    const float a = b2f(cur8[j]), p = pv[j];
    const float mk = tmk[c0 + j], mv = tmv[c0 + j], mr = tmr[c0 + j];
    ok[j]  = f2bf(a * mk + p * (1.f - mk));
    ov[j]  = f2bf(a * mv + p * (1.f - mv));
    orr[j] = f2bf(a * mr + p * (1.f - mr));
  }
  *(uint4*)(xk + o) = *(uint4*)ok;
  *(uint4*)(xv + o) = *(uint4*)ov;
  *(uint4*)(xr + o) = *(uint4*)orr;
}

// ---------- token-shift mix (ffn: 2 outputs) ----------
__global__ __launch_bounds__(256) void k_mix2(
    const unsigned short* __restrict__ x2, const float* __restrict__ shift,
    const float* __restrict__ fmk, const float* __restrict__ fmr,
    unsigned short* __restrict__ xk2, unsigned short* __restrict__ xr2) {
  const int row = blockIdx.x;
  const int t = row & (T_ - 1);
  const int bi = row >> 11;
  const int c0 = threadIdx.x * 8;
  const size_t o = (size_t)row * C_ + c0;
  unsigned short cur8[8];
  *(uint4*)cur8 = *(const uint4*)(x2 + o);
  float pv[8];
  if (t == 0) {
    const float* sp = shift + (size_t)bi * C_ + c0;
#pragma unroll
    for (int j = 0; j < 8; ++j) pv[j] = sp[j];
  } else {
    unsigned short p8[8];
    *(uint4*)p8 = *(const uint4*)(x2 + o - C_);
#pragma unroll
    for (int j = 0; j < 8; ++j) pv[j] = b2f(p8[j]);
  }
  unsigned short ok[8], orr[8];
#pragma unroll
  for (int j = 0; j < 8; ++j) {
    const float a = b2f(cur8[j]), p = pv[j];
    const float mk = fmk[c0 + j], mr = fmr[c0 + j];
    ok[j]  = f2bf(a * mk + p * (1.f - mk));
    orr[j] = f2bf(a * mr + p * (1.f - mr));
  }
  *(uint4*)(xk2 + o) = *(uint4*)ok;
  *(uint4*)(xr2 + o) = *(uint4*)orr;
}

// ---------- WKV: single-kernel block-local chunked scan (y f32 out) ----------
__global__ __launch_bounds__(256) void k_wkv_blk(
    const float* __restrict__ kk, const float* __restrict__ vv,
    const float* __restrict__ td, const float* __restrict__ tf,
    const float* __restrict__ st, float* __restrict__ y,
    float* __restrict__ out_state) {
  __shared__ float sA[TCH][CHB], sB[TCH][CHB], sP[TCH][CHB];
  const int blk = blockIdx.x;
  const int bi = blk >> 7;
  const int tx = threadIdx.x & 15;
  const int ty = threadIdx.x >> 4;
  const int c = ((blk & 127) * CHB) + tx;
  const float w = -expf(td[c]);
  const float u = tf[c];
  const size_t base = (size_t)bi * T_ * C_ + (size_t)ty * LC2 * C_ + c;
  const float* kp = kk + base;
  const float* vp = vv + base;
  float aa = 0.f, bb = 0.f, pp = -1e38f;
#pragma unroll 8
  for (int i = 0; i < LC2; ++i) {
    const float kt = kp[(size_t)i * C_], vt = vp[(size_t)i * C_];
    const float ww2 = pp + w;
    const float p2 = fmaxf(ww2, kt);
    const float e1b = expf(ww2 - p2), e2b = expf(kt - p2);
    aa = e1b * aa + e2b * vt;
    bb = e1b * bb + e2b;
    pp = p2;
  }
  sA[ty][tx] = aa; sB[ty][tx] = bb; sP[ty][tx] = pp;
  __syncthreads();
  if (ty == 0) {
    const float* s0 = st + (size_t)bi * 3 * C_;
    float ca = s0[c], cb = s0[C_ + c], cp = s0[2 * C_ + c];
    const float wL = w * (float)LC2;
#pragma unroll
    for (int j = 0; j < TCH; ++j) {
      const float a2 = sA[j][tx], b2 = sB[j][tx], p2 = sP[j][tx];
      sA[j][tx] = ca; sB[j][tx] = cb; sP[j][tx] = cp;   // exclusive start
      const float pd = cp + wL;
      const float pm = fmaxf(pd, p2);
      const float e1 = expf(pd - pm), e2 = expf(p2 - pm);
      ca = e1 * ca + e2 * a2;
      cb = e1 * cb + e2 * b2;
      cp = pm;
    }
  }
  __syncthreads();
  aa = sA[ty][tx]; bb = sB[ty][tx]; pp = sP[ty][tx];
  float* yp = y + base;
#pragma unroll 4
  for (int i = 0; i < LC2; ++i) {
    const float kt = kp[(size_t)i * C_], vt = vp[(size_t)i * C_];
    const float ww = u + kt;
    const float p = fmaxf(pp, ww);
    const float e1 = expf(pp - p), e2 = expf(ww - p);
    yp[(size_t)i * C_] = (e1 * aa + e2 * vt) / (e1 * bb + e2);
    const float ww2 = pp + w;
    const float p2 = fmaxf(ww2, kt);
    const float e1b = expf(ww2 - p2), e2b = expf(kt - p2);
    aa = e1b * aa + e2b * vt;
    bb = e1b * bb + e2b;
    pp = p2;
  }
  if (ty == TCH - 1) {
    float* ob = out_state + (size_t)bi * 3 * C_;
    ob[c] = aa; ob[C_ + c] = bb; ob[2 * C_ + c] = pp;
  }
}

// ---------- sigmoid(r)*y -> bf16 (r bf16, y f32) ----------
__global__ __launch_bounds__(256) void k_sry(
    const unsigned short* __restrict__ r, const float* __restrict__ y,
    unsigned short* __restrict__ sry) {
  const int nv = M_ * C_ / 8;
  for (int i = blockIdx.x * 256 + threadIdx.x; i < nv; i += gridDim.x * 256) {
    unsigned short r8[8];
    *(uint4*)r8 = ((const uint4*)r)[i];
    float4 ya = ((const float4*)y)[2 * i], yb = ((const float4*)y)[2 * i + 1];
    const float yv[8] = {ya.x, ya.y, ya.z, ya.w, yb.x, yb.y, yb.z, yb.w};
    unsigned short o8[8];
#pragma unroll
    for (int j = 0; j < 8; ++j) {
      const float s = 1.f / (1.f + expf(-b2f(r8[j])));
      o8[j] = f2bf(s * yv[j]);
    }
    ((uint4*)sry)[i] = *(uint4*)o8;
  }
}

// ---------- bf16 MFMA GEMM, 128x128 tile, BK=32, global_load_lds ----------
// A: [M][K] bf16 row-major; BT: [N][K] bf16 row-major. C[M][N] = A * BT^T.
// SWZ: XCD-aware bijective block swizzle (only for HBM-bound working sets).
// EPI 0: f32 store; 1: bf16(relu(acc)^2); 2: f32(aux1+acc);
// EPI 3: f32(aux1+sigmoid(acc)*aux2); 4: bf16 plain
template <int EPI, int SWZ>
__global__ __launch_bounds__(256, 2) void k_gemm(
    const unsigned short* __restrict__ A, const unsigned short* __restrict__ BT,
    int K, int Nn, void* __restrict__ out,
    const float* __restrict__ aux1, const float* __restrict__ aux2) {
  __shared__ unsigned short lds_a[128 * 32];
  __shared__ unsigned short lds_b[128 * 32];
  const int tid = threadIdx.x;
  const int lane = tid & 63;
  const int wv = tid >> 6;
  int mBase, nBase;
  if (SWZ) {
    const int gx = gridDim.x;
    int wg = blockIdx.y * gx + blockIdx.x;
    const int nwg = gx * gridDim.y;
    wg = (wg & 7) * (nwg >> 3) + (wg >> 3);   // grids here are multiples of 8
    mBase = (wg / gx) * 128;
    nBase = (wg % gx) * 128;
  } else {
    mBase = blockIdx.y * 128;
    nBase = blockIdx.x * 128;
  }
  const int wr = (wv >> 1) * 64;
  const int wc = (wv & 1) * 64;
  const int r16 = lane & 15, kq = lane >> 4;
  const int srow = lane >> 2;          // row within 16-row chunk
  const int scol = (lane & 3) * 16;    // byte offset within 64B row
  const size_t strideA = (size_t)K * 2;
  f32x4 acc[4][4] = {};

  const int nk = K >> 5;
  for (int kt = 0; kt < nk; ++kt) {
    const size_t kb = (size_t)kt * 64;
#pragma unroll
    for (int i = 0; i < 2; ++i) {
      const int chunk = i * 4 + wv;
      const int row = chunk * 16 + srow;
      gload16((const char*)A + (size_t)(mBase + row) * strideA + kb + scol,
              &lds_a[chunk * 512]);
      gload16((const char*)BT + (size_t)(nBase + row) * strideA + kb + scol,
              &lds_b[chunk * 512]);
    }
    __syncthreads();
    bf16x8 af[4], bfr[4];
#pragma unroll
    for (int m = 0; m < 4; ++m)
      af[m] = *(const bf16x8*)&lds_a[(wr + m * 16 + r16) * 32 + kq * 8];
#pragma unroll
    for (int n = 0; n < 4; ++n)
      bfr[n] = *(const bf16x8*)&lds_b[(wc + n * 16 + r16) * 32 + kq * 8];
#pragma unroll
    for (int m = 0; m < 4; ++m)
#pragma unroll
      for (int n = 0; n < 4; ++n)
        acc[m][n] = __builtin_amdgcn_mfma_f32_16x16x32_bf16(af[m], bfr[n], acc[m][n], 0, 0, 0);
    __syncthreads();
  }

  const int c0 = kq * 4;
#pragma unroll
  for (int m = 0; m < 4; ++m) {
#pragma unroll
    for (int n = 0; n < 4; ++n) {
      const int col = nBase + wc + n * 16 + r16;
#pragma unroll
      for (int e = 0; e < 4; ++e) {
        const int rowg = mBase + wr + m * 16 + c0 + e;
        const size_t idx = (size_t)rowg * Nn + col;
        const float va = acc[m][n][e];
        if (EPI == 0) {
          ((float*)out)[idx] = va;
        } else if (EPI == 1) {
          const float t = va > 0.f ? va : 0.f;
          ((unsigned short*)out)[idx] = f2bf(t * t);
        } else if (EPI == 2) {
          ((float*)out)[idx] = aux1[idx] + va;
        } else if (EPI == 3) {
          const float s = 1.f / (1.f + expf(-va));
          ((float*)out)[idx] = aux1[idx] + s * aux2[idx];
        } else {
          ((unsigned short*)out)[idx] = f2bf(va);
        }
      }
    }
  }
}

extern "C" void kernel_launch(void* const* d_in, const int* in_sizes, int n_in,
                              void* d_out, int out_size, void* d_ws, size_t ws_size,
                              hipStream_t stream) {
  const float* x          = (const float*)d_in[0];
  const float* att_shift  = (const float*)d_in[1];
  const float* wkv_state  = (const float*)d_in[2];
  const float* ffn_shift  = (const float*)d_in[3];
  const float* ln1_g = (const float*)d_in[4];
  const float* ln1_b = (const float*)d_in[5];
  const float* ln2_g = (const float*)d_in[6];
  const float* ln2_b = (const float*)d_in[7];
  const float* tmk = (const float*)d_in[8];
  const float* tmv = (const float*)d_in[9];
  const float* tmr = (const float*)d_in[10];
  const float* time_decay = (const float*)d_in[11];
  const float* time_first = (const float*)d_in[12];
  const float* Wk = (const float*)d_in[13];
  const float* Wv = (const float*)d_in[14];
  const float* Wr = (const float*)d_in[15];
  const float* Wo = (const float*)d_in[16];
  const float* fmk = (const float*)d_in[17];
  const float* fmr = (const float*)d_in[18];
  const float* Fk = (const float*)d_in[19];
  const float* Fr = (const float*)d_in[20];
  const float* Fv = (const float*)d_in[21];

  // ---- 176 MiB workspace, strictly sequential reuse, zero in-flight overlap ----
  const size_t MB = 1ull << 20;
  char* ws = (char*)d_ws;
  if (ws_size < 176 * MB) return;

  unsigned short* Wslot = (unsigned short*)(ws);             //   0.. 32 weight slot
  float*          kBuf  = (float*)(ws + 32 * MB);            //  32.. 64 k f32
  float*          vBuf  = (float*)(ws + 64 * MB);            //  64.. 96 v f32
  float*          yBuf  = (float*)(ws + 96 * MB);            //  96..128 y f32 -> x_att f32
  unsigned short* h1    = (unsigned short*)(ws + 128 * MB);  // 128..144 x1 -> r -> x2
  unsigned short* h2    = (unsigned short*)(ws + 144 * MB);  // 144..160 xk -> sry -> xk2
  unsigned short* h3    = (unsigned short*)(ws + 160 * MB);  // 160..176 xv -> xr2
  unsigned short* xrT   = (unsigned short*)kBuf;             // xr bf16, before k exists
  unsigned short* kf    = (unsigned short*)kBuf;             // 64 MiB: 32..96 (k,v dead)
  float*          kv    = (float*)h1;                        // 32 MiB: 128..160 (x2,xk2 dead)

  // ---- f32 outputs, concatenated in reference return order ----
  float* outb    = (float*)d_out;
  float* x1_last = outb + (size_t)M_ * C_;        // [B,C]
  float* wkv_out = x1_last + (size_t)B_ * C_;     // [B,3,C]
  float* x2_last = wkv_out + (size_t)B_ * 3 * C_; // [B,C]

  const dim3 gCC(C_ / 32, C_ / 32);
  const dim3 gC(C_ / 128, M_ / 128);

  // ---- attention path ----
  k_layernorm<<<M_, 256, 0, stream>>>(x, ln1_g, ln1_b, h1, x1_last);           // x1 -> h1
  k_mix3<<<M_, 256, 0, stream>>>(h1, att_shift, tmk, tmv, tmr, h2, h3, xrT);   // xk,xv,xr
  k_transpose_cast<<<gCC, 256, 0, stream>>>(Wr, Wslot, C_, C_);
  k_gemm<4,0><<<gC, 256, 0, stream>>>(xrT, Wslot, C_, C_, h1, nullptr, nullptr); // r bf16 -> h1
  k_transpose_cast<<<gCC, 256, 0, stream>>>(Wk, Wslot, C_, C_);
  k_gemm<0,0><<<gC, 256, 0, stream>>>(h2, Wslot, C_, C_, kBuf, nullptr, nullptr); // k f32 (over xr, dead)
  k_transpose_cast<<<gCC, 256, 0, stream>>>(Wv, Wslot, C_, C_);
  k_gemm<0,0><<<gC, 256, 0, stream>>>(h3, Wslot, C_, C_, vBuf, nullptr, nullptr); // v f32
  // WKV: single kernel, block-local scan (no cross-kernel scratch)
  k_wkv_blk<<<dim3(BC_ / CHB), 256, 0, stream>>>(kBuf, vBuf, time_decay, time_first,
                                                 wkv_state, yBuf, wkv_out);
  k_sry<<<1024, 256, 0, stream>>>(h1, yBuf, h2);                                // sry -> h2 (xk dead)
  k_transpose_cast<<<gCC, 256, 0, stream>>>(Wo, Wslot, C_, C_);
  k_gemm<2,0><<<gC, 256, 0, stream>>>(h2, Wslot, C_, C_, yBuf, x, nullptr);     // x_att f32 (over y, dead)

  // ---- ffn path ----
  k_layernorm<<<M_, 256, 0, stream>>>(yBuf, ln2_g, ln2_b, h1, x2_last);         // x2 -> h1 (r dead)
  k_mix2<<<M_, 256, 0, stream>>>(h1, ffn_shift, fmk, fmr, h2, h3);              // xk2,xr2 (sry,xv dead)
  k_transpose_cast<<<dim3(F_ / 32, C_ / 32), 256, 0, stream>>>(Fk, Wslot, C_, F_);
  k_gemm<1,1><<<dim3(F_ / 128, M_ / 128), 256, 0, stream>>>(h2, Wslot, C_, F_, kf,
                                                            nullptr, nullptr);  // kf bf16 (k,v dead)
  k_transpose_cast<<<dim3(C_ / 32, F_ / 32), 256, 0, stream>>>(Fv, Wslot, F_, C_);
  k_gemm<0,1><<<gC, 256, 0, stream>>>(kf, Wslot, F_, C_, kv, nullptr, nullptr); // kv f32 (x2,xk2 dead)
  k_transpose_cast<<<gCC, 256, 0, stream>>>(Fr, Wslot, C_, C_);
  k_gemm<3,0><<<gC, 256, 0, stream>>>(h3, Wslot, C_, C_, d_out, yBuf, kv);      // final f32
}

// Round 11
// 758.450 us; speedup vs baseline: 1.1417x; 1.0674x over previous
//
#include <hip/hip_runtime.h>
#include <stdint.h>

#define B_ 2
#define T_ 2048
#define C_ 2048
#define F_ 8192
#define M_ 4096   // B_*T_
#define BC_ 4096  // B_*C_
#define CHB 16    // channels per WKV block
#define TCH 16    // time chunks per WKV block
#define LC2 128   // T_/TCH

typedef __attribute__((ext_vector_type(8))) __bf16 bf16x8;
typedef __attribute__((ext_vector_type(4))) float f32x4;

__device__ __forceinline__ unsigned short f2bf(float f) {
  union { float f; unsigned u; } v; v.f = f;
  unsigned r = v.u + 0x7fffu + ((v.u >> 16) & 1u);
  return (unsigned short)(r >> 16);
}
__device__ __forceinline__ float b2f(unsigned short h) {
  union { unsigned u; float f; } v; v.u = ((unsigned)h) << 16; return v.f;
}

__device__ __forceinline__ void gload16(const void* g, void* l) {
  __builtin_amdgcn_global_load_lds((__attribute__((address_space(1))) void*)g,
                                   (__attribute__((address_space(3))) void*)l,
                                   16, 0, 0);
}

// ---------- transpose + f32->bf16: WT[n][k] = W[k][n] ----------
__global__ __launch_bounds__(256) void k_transpose_cast(
    const float* __restrict__ W, unsigned short* __restrict__ WT, int K, int N) {
  __shared__ unsigned short tile[32][33];
  const int n0 = blockIdx.x * 32, k0 = blockIdx.y * 32;
  const int tx = threadIdx.x & 31, ty = threadIdx.x >> 5;
#pragma unroll
  for (int i = 0; i < 4; ++i)
    tile[ty + 8 * i][tx] = f2bf(W[(size_t)(k0 + ty + 8 * i) * N + n0 + tx]);
  __syncthreads();
#pragma unroll
  for (int i = 0; i < 4; ++i)
    WT[(size_t)(n0 + ty + 8 * i) * K + k0 + tx] = tile[tx][ty + 8 * i];
}

// ---------- LayerNorm over C=2048 (f32 in, bf16 out + f32 last-row out) ----------
__global__ __launch_bounds__(256) void k_layernorm(
    const float* __restrict__ x, const float* __restrict__ g,
    const float* __restrict__ beta, unsigned short* __restrict__ y,
    float* __restrict__ last_out) {
  const int row = blockIdx.x;
  const int t = row & (T_ - 1);
  const int bi = row >> 11;
  const float* xr = x + (size_t)row * C_;
  const int base = threadIdx.x * 8;
  float lv[8];
  {
    float4 a = *(const float4*)(xr + base);
    float4 b = *(const float4*)(xr + base + 4);
    lv[0]=a.x; lv[1]=a.y; lv[2]=a.z; lv[3]=a.w; lv[4]=b.x; lv[5]=b.y; lv[6]=b.z; lv[7]=b.w;
  }
  float s = 0.f, q = 0.f;
#pragma unroll
  for (int j = 0; j < 8; ++j) { s += lv[j]; q += lv[j] * lv[j]; }
#pragma unroll
  for (int o = 32; o > 0; o >>= 1) { s += __shfl_down(s, o); q += __shfl_down(q, o); }
  __shared__ float rs[4], rq[4];
  if ((threadIdx.x & 63) == 0) { rs[threadIdx.x >> 6] = s; rq[threadIdx.x >> 6] = q; }
  __syncthreads();
  s = rs[0] + rs[1] + rs[2] + rs[3];
  q = rq[0] + rq[1] + rq[2] + rq[3];
  const float mean = s * (1.f / C_);
  const float var = q * (1.f / C_) - mean * mean;
  const float inv = 1.f / sqrtf(var + 1e-5f);
  float ov[8];
  unsigned short o8[8];
#pragma unroll
  for (int j = 0; j < 8; ++j) {
    ov[j] = (lv[j] - mean) * inv * g[base + j] + beta[base + j];
    o8[j] = f2bf(ov[j]);
  }
  *(uint4*)(y + (size_t)row * C_ + base) = *(uint4*)o8;
  if (last_out != nullptr && t == T_ - 1) {
    float* lp = last_out + (size_t)bi * C_ + base;
    *(float4*)lp = make_float4(ov[0], ov[1], ov[2], ov[3]);
    *(float4*)(lp + 4) = make_float4(ov[4], ov[5], ov[6], ov[7]);
  }
}

// ---------- token-shift mix (attention: 3 outputs), bf16 in/out ----------
__global__ __launch_bounds__(256) void k_mix3(
    const unsigned short* __restrict__ x1, const float* __restrict__ shift,
    const float* __restrict__ tmk, const float* __restrict__ tmv,
    const float* __restrict__ tmr,
    unsigned short* __restrict__ xk, unsigned short* __restrict__ xv,
    unsigned short* __restrict__ xr) {
  const int row = blockIdx.x;
  const int t = row & (T_ - 1);
  const int bi = row >> 11;
  const int c0 = threadIdx.x * 8;
  const size_t o = (size_t)row * C_ + c0;
  unsigned short cur8[8];
  *(uint4*)cur8 = *(const uint4*)(x1 + o);
  float pv[8];
  if (t == 0) {
    const float* sp = shift + (size_t)bi * C_ + c0;
#pragma unroll
    for (int j = 0; j < 8; ++j) pv[j] = sp[j];
  } else {
    unsigned short p8[8];
    *(uint4*)p8 = *(const uint4*)(x1 + o - C_);
#pragma unroll
    for (int j = 0; j < 8; ++j) pv[j] = b2f(p8[j]);
  }
  unsigned short ok[8], ov[8], orr[8];
#pragma unroll
  for (int j = 0; j < 8; ++j) {
    const float a = b2f(cur8[j]), p = pv[j];
    const float mk = tmk[c0 + j], mv = tmv[c0 + j], mr = tmr[c0 + j];
    ok[j]  = f2bf(a * mk + p * (1.f - mk));
    ov[j]  = f2bf(a * mv + p * (1.f - mv));
    orr[j] = f2bf(a * mr + p * (1.f - mr));
  }
  *(uint4*)(xk + o) = *(uint4*)ok;
  *(uint4*)(xv + o) = *(uint4*)ov;
  *(uint4*)(xr + o) = *(uint4*)orr;
}

// ---------- token-shift mix (ffn: 2 outputs) ----------
__global__ __launch_bounds__(256) void k_mix2(
    const unsigned short* __restrict__ x2, const float* __restrict__ shift,
    const float* __restrict__ fmk, const float* __restrict__ fmr,
    unsigned short* __restrict__ xk2, unsigned short* __restrict__ xr2) {
  const int row = blockIdx.x;
  const int t = row & (T_ - 1);
  const int bi = row >> 11;
  const int c0 = threadIdx.x * 8;
  const size_t o = (size_t)row * C_ + c0;
  unsigned short cur8[8];
  *(uint4*)cur8 = *(const uint4*)(x2 + o);
  float pv[8];
  if (t == 0) {
    const float* sp = shift + (size_t)bi * C_ + c0;
#pragma unroll
    for (int j = 0; j < 8; ++j) pv[j] = sp[j];
  } else {
    unsigned short p8[8];
    *(uint4*)p8 = *(const uint4*)(x2 + o - C_);
#pragma unroll
    for (int j = 0; j < 8; ++j) pv[j] = b2f(p8[j]);
  }
  unsigned short ok[8], orr[8];
#pragma unroll
  for (int j = 0; j < 8; ++j) {
    const float a = b2f(cur8[j]), p = pv[j];
    const float mk = fmk[c0 + j], mr = fmr[c0 + j];
    ok[j]  = f2bf(a * mk + p * (1.f - mk));
    orr[j] = f2bf(a * mr + p * (1.f - mr));
  }
  *(uint4*)(xk2 + o) = *(uint4*)ok;
  *(uint4*)(xr2 + o) = *(uint4*)orr;
}

// ---------- WKV: single-kernel block-local chunked scan (y f32 out) ----------
__global__ __launch_bounds__(256) void k_wkv_blk(
    const float* __restrict__ kk, const float* __restrict__ vv,
    const float* __restrict__ td, const float* __restrict__ tf,
    const float* __restrict__ st, float* __restrict__ y,
    float* __restrict__ out_state) {
  __shared__ float sA[TCH][CHB], sB[TCH][CHB], sP[TCH][CHB];
  const int blk = blockIdx.x;
  const int bi = blk >> 7;
  const int tx = threadIdx.x & 15;
  const int ty = threadIdx.x >> 4;
  const int c = ((blk & 127) * CHB) + tx;
  const float w = -expf(td[c]);
  const float u = tf[c];
  const size_t base = (size_t)bi * T_ * C_ + (size_t)ty * LC2 * C_ + c;
  const float* kp = kk + base;
  const float* vp = vv + base;
  float aa = 0.f, bb = 0.f, pp = -1e38f;
#pragma unroll 8
  for (int i = 0; i < LC2; ++i) {
    const float kt = kp[(size_t)i * C_], vt = vp[(size_t)i * C_];
    const float ww2 = pp + w;
    const float p2 = fmaxf(ww2, kt);
    const float e1b = expf(ww2 - p2), e2b = expf(kt - p2);
    aa = e1b * aa + e2b * vt;
    bb = e1b * bb + e2b;
    pp = p2;
  }
  sA[ty][tx] = aa; sB[ty][tx] = bb; sP[ty][tx] = pp;
  __syncthreads();
  if (ty == 0) {
    const float* s0 = st + (size_t)bi * 3 * C_;
    float ca = s0[c], cb = s0[C_ + c], cp = s0[2 * C_ + c];
    const float wL = w * (float)LC2;
#pragma unroll
    for (int j = 0; j < TCH; ++j) {
      const float a2 = sA[j][tx], b2 = sB[j][tx], p2 = sP[j][tx];
      sA[j][tx] = ca; sB[j][tx] = cb; sP[j][tx] = cp;   // exclusive start
      const float pd = cp + wL;
      const float pm = fmaxf(pd, p2);
      const float e1 = expf(pd - pm), e2 = expf(p2 - pm);
      ca = e1 * ca + e2 * a2;
      cb = e1 * cb + e2 * b2;
      cp = pm;
    }
  }
  __syncthreads();
  aa = sA[ty][tx]; bb = sB[ty][tx]; pp = sP[ty][tx];
  float* yp = y + base;
#pragma unroll 4
  for (int i = 0; i < LC2; ++i) {
    const float kt = kp[(size_t)i * C_], vt = vp[(size_t)i * C_];
    const float ww = u + kt;
    const float p = fmaxf(pp, ww);
    const float e1 = expf(pp - p), e2 = expf(ww - p);
    yp[(size_t)i * C_] = (e1 * aa + e2 * vt) / (e1 * bb + e2);
    const float ww2 = pp + w;
    const float p2 = fmaxf(ww2, kt);
    const float e1b = expf(ww2 - p2), e2b = expf(kt - p2);
    aa = e1b * aa + e2b * vt;
    bb = e1b * bb + e2b;
    pp = p2;
  }
  if (ty == TCH - 1) {
    float* ob = out_state + (size_t)bi * 3 * C_;
    ob[c] = aa; ob[C_ + c] = bb; ob[2 * C_ + c] = pp;
  }
}

// ---------- sigmoid(r)*y -> bf16 (r bf16, y f32) ----------
__global__ __launch_bounds__(256) void k_sry(
    const unsigned short* __restrict__ r, const float* __restrict__ y,
    unsigned short* __restrict__ sry) {
  const int nv = M_ * C_ / 8;
  for (int i = blockIdx.x * 256 + threadIdx.x; i < nv; i += gridDim.x * 256) {
    unsigned short r8[8];
    *(uint4*)r8 = ((const uint4*)r)[i];
    float4 ya = ((const float4*)y)[2 * i], yb = ((const float4*)y)[2 * i + 1];
    const float yv[8] = {ya.x, ya.y, ya.z, ya.w, yb.x, yb.y, yb.z, yb.w};
    unsigned short o8[8];
#pragma unroll
    for (int j = 0; j < 8; ++j) {
      const float s = 1.f / (1.f + expf(-b2f(r8[j])));
      o8[j] = f2bf(s * yv[j]);
    }
    ((uint4*)sry)[i] = *(uint4*)o8;
  }
}

// ---------- 8-phase bf16 MFMA GEMM: 128x256 tile, BK=64, 8 waves ----------
// A: [M][K] bf16 row-major; BT: [N][K] bf16 row-major. C[M][N] = A * BT^T.
// Double-buffered 96KiB LDS staged via global_load_lds with XOR-swizzled
// SOURCE addresses (linear LDS dest) + matching swizzled ds_read (rule 21).
// Raw s_barrier (no vmcnt auto-drain); vmcnt(0) once per K-tile at phase 4.
// EPI 0: f32; 1: bf16(relu^2); 2: f32(aux1+acc); 3: f32(aux1+sig(acc)*aux2); 4: bf16
template <int EPI, int SWZ>
__global__ __launch_bounds__(512, 1) void k_gemm8(
    const unsigned short* __restrict__ A, const unsigned short* __restrict__ BT,
    int K, int Nn, void* __restrict__ out,
    const float* __restrict__ aux1, const float* __restrict__ aux2) {
  // layout (ushort): A0 [0,8192) A1 [8192,16384) B0 [16384,32768) B1 [32768,49152)
  __shared__ unsigned short lds[49152];
  const int tid = threadIdx.x;
  const int lane = tid & 63;
  const int wid = tid >> 6;
  int mBase, nBase;
  if (SWZ) {
    const int gx = gridDim.x;
    int wg = blockIdx.y * gx + blockIdx.x;
    const int nwg = gx * gridDim.y;
    wg = (wg & 7) * (nwg >> 3) + (wg >> 3);   // grids are multiples of 8
    mBase = (wg / gx) * 128;
    nBase = (wg % gx) * 256;
  } else {
    mBase = blockIdx.y * 128;
    nBase = blockIdx.x * 256;
  }
  const int wr = (wid >> 2) * 64;       // wave M offset (2 waves in M)
  const int wc = (wid & 3) * 64;        // wave N offset (4 waves in N)
  const int r16 = lane & 15, kq = lane >> 4;
  const int lrow = lane >> 3;           // staging row within 8-row wave chunk
  const int lslot = (lane & 7) ^ lrow;  // inverse-swizzled SOURCE slot
  const int xsw = r16 & 7;              // read-side xor
  f32x4 acc[4][4] = {};

  const int nt = K >> 6;
  // prologue: stage K-tile 0 into buffer 0
#pragma unroll
  for (int j = 0; j < 2; ++j)
    gload16(A + (size_t)(mBase + j * 64 + wid * 8 + lrow) * K + lslot * 8,
            &lds[j * 4096 + wid * 512]);
#pragma unroll
  for (int j = 0; j < 4; ++j)
    gload16(BT + (size_t)(nBase + j * 64 + wid * 8 + lrow) * K + lslot * 8,
            &lds[16384 + j * 4096 + wid * 512]);
  asm volatile("s_waitcnt vmcnt(0)" ::: "memory");
  asm volatile("s_barrier" ::: "memory");

  int cur = 0;
  for (int t = 0; t < nt; ++t) {
    const int kb2 = (t + 1) << 6;
    const bool pf = (t + 1 < nt);
    const int ca = cur * 8192, cbo = 16384 + cur * 16384;
    const int na = (cur ^ 1) * 8192, nb = 16384 + (cur ^ 1) * 16384;
    bf16x8 af[2][2], bq[2][2];
#pragma unroll
    for (int qm = 0; qm < 2; ++qm) {
#pragma unroll
      for (int qn = 0; qn < 2; ++qn) {
        // ds-read this phase's operand fragments (buffer cur)
        if (qn == 0) {
#pragma unroll
          for (int dm = 0; dm < 2; ++dm)
#pragma unroll
            for (int s = 0; s < 2; ++s)
              af[dm][s] = *(const bf16x8*)&lds[ca + (wr + (qm * 2 + dm) * 16 + r16) * 64 +
                                               (((s * 4 + kq) ^ xsw) * 8)];
        }
#pragma unroll
        for (int dn = 0; dn < 2; ++dn)
#pragma unroll
          for (int s = 0; s < 2; ++s)
            bq[dn][s] = *(const bf16x8*)&lds[cbo + (wc + (qn * 2 + dn) * 16 + r16) * 64 +
                                             (((s * 4 + kq) ^ xsw) * 8)];
        // prefetch next K-tile into buffer cur^1 (phases 0-2: 2 units each)
        const int ph = qm * 2 + qn;
        if (pf) {
          if (ph == 0) {
            gload16(A + (size_t)(mBase + 0 + wid * 8 + lrow) * K + kb2 + lslot * 8,
                    &lds[na + 0 + wid * 512]);
            gload16(A + (size_t)(mBase + 64 + wid * 8 + lrow) * K + kb2 + lslot * 8,
                    &lds[na + 4096 + wid * 512]);
          } else if (ph == 1) {
            gload16(BT + (size_t)(nBase + 0 + wid * 8 + lrow) * K + kb2 + lslot * 8,
                    &lds[nb + 0 + wid * 512]);
            gload16(BT + (size_t)(nBase + 64 + wid * 8 + lrow) * K + kb2 + lslot * 8,
                    &lds[nb + 4096 + wid * 512]);
          } else if (ph == 2) {
            gload16(BT + (size_t)(nBase + 128 + wid * 8 + lrow) * K + kb2 + lslot * 8,
                    &lds[nb + 8192 + wid * 512]);
            gload16(BT + (size_t)(nBase + 192 + wid * 8 + lrow) * K + kb2 + lslot * 8,
                    &lds[nb + 12288 + wid * 512]);
          }
        }
        asm volatile("s_barrier" ::: "memory");
        __builtin_amdgcn_s_setprio(1);
#pragma unroll
        for (int dm = 0; dm < 2; ++dm)
#pragma unroll
          for (int dn = 0; dn < 2; ++dn)
#pragma unroll
            for (int s = 0; s < 2; ++s)
              acc[qm * 2 + dm][qn * 2 + dn] = __builtin_amdgcn_mfma_f32_16x16x32_bf16(
                  af[dm][s], bq[dn][s], acc[qm * 2 + dm][qn * 2 + dn], 0, 0, 0);
        __builtin_amdgcn_s_setprio(0);
        if (ph == 3) asm volatile("s_waitcnt vmcnt(0)" ::: "memory");
        asm volatile("s_barrier" ::: "memory");
      }
    }
    cur ^= 1;
  }

  const int c0 = kq * 4;
#pragma unroll
  for (int m = 0; m < 4; ++m) {
#pragma unroll
    for (int n = 0; n < 4; ++n) {
      const int col = nBase + wc + n * 16 + r16;
#pragma unroll
      for (int e = 0; e < 4; ++e) {
        const int rowg = mBase + wr + m * 16 + c0 + e;
        const size_t idx = (size_t)rowg * Nn + col;
        const float va = acc[m][n][e];
        if (EPI == 0) {
          ((float*)out)[idx] = va;
        } else if (EPI == 1) {
          const float t = va > 0.f ? va : 0.f;
          ((unsigned short*)out)[idx] = f2bf(t * t);
        } else if (EPI == 2) {
          ((float*)out)[idx] = aux1[idx] + va;
        } else if (EPI == 3) {
          const float s = 1.f / (1.f + expf(-va));
          ((float*)out)[idx] = aux1[idx] + s * aux2[idx];
        } else {
          ((unsigned short*)out)[idx] = f2bf(va);
        }
      }
    }
  }
}

extern "C" void kernel_launch(void* const* d_in, const int* in_sizes, int n_in,
                              void* d_out, int out_size, void* d_ws, size_t ws_size,
                              hipStream_t stream) {
  const float* x          = (const float*)d_in[0];
  const float* att_shift  = (const float*)d_in[1];
  const float* wkv_state  = (const float*)d_in[2];
  const float* ffn_shift  = (const float*)d_in[3];
  const float* ln1_g = (const float*)d_in[4];
  const float* ln1_b = (const float*)d_in[5];
  const float* ln2_g = (const float*)d_in[6];
  const float* ln2_b = (const float*)d_in[7];
  const float* tmk = (const float*)d_in[8];
  const float* tmv = (const float*)d_in[9];
  const float* tmr = (const float*)d_in[10];
  const float* time_decay = (const float*)d_in[11];
  const float* time_first = (const float*)d_in[12];
  const float* Wk = (const float*)d_in[13];
  const float* Wv = (const float*)d_in[14];
  const float* Wr = (const float*)d_in[15];
  const float* Wo = (const float*)d_in[16];
  const float* fmk = (const float*)d_in[17];
  const float* fmr = (const float*)d_in[18];
  const float* Fk = (const float*)d_in[19];
  const float* Fr = (const float*)d_in[20];
  const float* Fv = (const float*)d_in[21];

  // ---- 176 MiB workspace, strictly sequential reuse, zero in-flight overlap ----
  const size_t MB = 1ull << 20;
  char* ws = (char*)d_ws;
  if (ws_size < 176 * MB) return;

  unsigned short* Wslot = (unsigned short*)(ws);             //   0.. 32 weight slot
  float*          kBuf  = (float*)(ws + 32 * MB);            //  32.. 64 k f32
  float*          vBuf  = (float*)(ws + 64 * MB);            //  64.. 96 v f32
  float*          yBuf  = (float*)(ws + 96 * MB);            //  96..128 y f32 -> x_att f32
  unsigned short* h1    = (unsigned short*)(ws + 128 * MB);  // 128..144 x1 -> r -> x2
  unsigned short* h2    = (unsigned short*)(ws + 144 * MB);  // 144..160 xk -> sry -> xk2
  unsigned short* h3    = (unsigned short*)(ws + 160 * MB);  // 160..176 xv -> xr2
  unsigned short* xrT   = (unsigned short*)kBuf;             // xr bf16, before k exists
  unsigned short* kf    = (unsigned short*)kBuf;             // 64 MiB: 32..96 (k,v dead)
  float*          kv    = (float*)h1;                        // 32 MiB: 128..160 (x2,xk2 dead)

  // ---- f32 outputs, concatenated in reference return order ----
  float* outb    = (float*)d_out;
  float* x1_last = outb + (size_t)M_ * C_;        // [B,C]
  float* wkv_out = x1_last + (size_t)B_ * C_;     // [B,3,C]
  float* x2_last = wkv_out + (size_t)B_ * 3 * C_; // [B,C]

  const dim3 gCC(C_ / 32, C_ / 32);
  const dim3 gC8(C_ / 256, M_ / 128);      // 8 x 32 = 256 WGs
  const dim3 gF8(F_ / 256, M_ / 128);      // 32 x 32 = 1024 WGs

  // ---- attention path ----
  k_layernorm<<<M_, 256, 0, stream>>>(x, ln1_g, ln1_b, h1, x1_last);           // x1 -> h1
  k_mix3<<<M_, 256, 0, stream>>>(h1, att_shift, tmk, tmv, tmr, h2, h3, xrT);   // xk,xv,xr
  k_transpose_cast<<<gCC, 256, 0, stream>>>(Wr, Wslot, C_, C_);
  k_gemm8<4,0><<<gC8, 512, 0, stream>>>(xrT, Wslot, C_, C_, h1, nullptr, nullptr); // r bf16 -> h1
  k_transpose_cast<<<gCC, 256, 0, stream>>>(Wk, Wslot, C_, C_);
  k_gemm8<0,0><<<gC8, 512, 0, stream>>>(h2, Wslot, C_, C_, kBuf, nullptr, nullptr); // k f32 (over xr, dead)
  k_transpose_cast<<<gCC, 256, 0, stream>>>(Wv, Wslot, C_, C_);
  k_gemm8<0,0><<<gC8, 512, 0, stream>>>(h3, Wslot, C_, C_, vBuf, nullptr, nullptr); // v f32
  // WKV: single kernel, block-local scan (no cross-kernel scratch)
  k_wkv_blk<<<dim3(BC_ / CHB), 256, 0, stream>>>(kBuf, vBuf, time_decay, time_first,
                                                 wkv_state, yBuf, wkv_out);
  k_sry<<<1024, 256, 0, stream>>>(h1, yBuf, h2);                                // sry -> h2 (xk dead)
  k_transpose_cast<<<gCC, 256, 0, stream>>>(Wo, Wslot, C_, C_);
  k_gemm8<2,0><<<gC8, 512, 0, stream>>>(h2, Wslot, C_, C_, yBuf, x, nullptr);   // x_att f32 (over y, dead)

  // ---- ffn path ----
  k_layernorm<<<M_, 256, 0, stream>>>(yBuf, ln2_g, ln2_b, h1, x2_last);         // x2 -> h1 (r dead)
  k_mix2<<<M_, 256, 0, stream>>>(h1, ffn_shift, fmk, fmr, h2, h3);              // xk2,xr2 (sry,xv dead)
  k_transpose_cast<<<dim3(F_ / 32, C_ / 32), 256, 0, stream>>>(Fk, Wslot, C_, F_);
  k_gemm8<1,1><<<gF8, 512, 0, stream>>>(h2, Wslot, C_, F_, kf, nullptr, nullptr); // kf bf16 (k,v dead)
  k_transpose_cast<<<dim3(C_ / 32, F_ / 32), 256, 0, stream>>>(Fv, Wslot, F_, C_);
  k_gemm8<0,1><<<gC8, 512, 0, stream>>>(kf, Wslot, F_, C_, kv, nullptr, nullptr); // kv f32 (x2,xk2 dead)
  k_transpose_cast<<<gCC, 256, 0, stream>>>(Fr, Wslot, C_, C_);
  k_gemm8<3,0><<<gC8, 512, 0, stream>>>(h3, Wslot, C_, C_, d_out, yBuf, kv);    // final f32
}

// Round 12
// 740.841 us; speedup vs baseline: 1.1688x; 1.0238x over previous
//
#include <hip/hip_runtime.h>
#include <stdint.h>

#define B_ 2
#define T_ 2048
#define C_ 2048
#define F_ 8192
#define M_ 4096   // B_*T_
#define BC_ 4096  // B_*C_
#define CHB 16    // channels per WKV block
#define TCH 16    // time chunks per WKV block
#define LC2 128   // T_/TCH

typedef __attribute__((ext_vector_type(8))) __bf16 bf16x8;
typedef __attribute__((ext_vector_type(4))) float f32x4;

__device__ __forceinline__ unsigned short f2bf(float f) {
  union { float f; unsigned u; } v; v.f = f;
  unsigned r = v.u + 0x7fffu + ((v.u >> 16) & 1u);
  return (unsigned short)(r >> 16);
}
__device__ __forceinline__ float b2f(unsigned short h) {
  union { unsigned u; float f; } v; v.u = ((unsigned)h) << 16; return v.f;
}

__device__ __forceinline__ void gload16(const void* g, void* l) {
  __builtin_amdgcn_global_load_lds((__attribute__((address_space(1))) void*)g,
                                   (__attribute__((address_space(3))) void*)l,
                                   16, 0, 0);
}

// ---------- transpose + f32->bf16: WT[n][k] = W[k][n] ----------
__global__ __launch_bounds__(256) void k_transpose_cast(
    const float* __restrict__ W, unsigned short* __restrict__ WT, int K, int N) {
  __shared__ unsigned short tile[32][33];
  const int n0 = blockIdx.x * 32, k0 = blockIdx.y * 32;
  const int tx = threadIdx.x & 31, ty = threadIdx.x >> 5;
#pragma unroll
  for (int i = 0; i < 4; ++i)
    tile[ty + 8 * i][tx] = f2bf(W[(size_t)(k0 + ty + 8 * i) * N + n0 + tx]);
  __syncthreads();
#pragma unroll
  for (int i = 0; i < 4; ++i)
    WT[(size_t)(n0 + ty + 8 * i) * K + k0 + tx] = tile[tx][ty + 8 * i];
}

// ---------- LayerNorm over C=2048 (f32 in, bf16 out + f32 last-row out) ----------
__global__ __launch_bounds__(256) void k_layernorm(
    const float* __restrict__ x, const float* __restrict__ g,
    const float* __restrict__ beta, unsigned short* __restrict__ y,
    float* __restrict__ last_out) {
  const int row = blockIdx.x;
  const int t = row & (T_ - 1);
  const int bi = row >> 11;
  const float* xr = x + (size_t)row * C_;
  const int base = threadIdx.x * 8;
  float lv[8];
  {
    float4 a = *(const float4*)(xr + base);
    float4 b = *(const float4*)(xr + base + 4);
    lv[0]=a.x; lv[1]=a.y; lv[2]=a.z; lv[3]=a.w; lv[4]=b.x; lv[5]=b.y; lv[6]=b.z; lv[7]=b.w;
  }
  float s = 0.f, q = 0.f;
#pragma unroll
  for (int j = 0; j < 8; ++j) { s += lv[j]; q += lv[j] * lv[j]; }
#pragma unroll
  for (int o = 32; o > 0; o >>= 1) { s += __shfl_down(s, o); q += __shfl_down(q, o); }
  __shared__ float rs[4], rq[4];
  if ((threadIdx.x & 63) == 0) { rs[threadIdx.x >> 6] = s; rq[threadIdx.x >> 6] = q; }
  __syncthreads();
  s = rs[0] + rs[1] + rs[2] + rs[3];
  q = rq[0] + rq[1] + rq[2] + rq[3];
  const float mean = s * (1.f / C_);
  const float var = q * (1.f / C_) - mean * mean;
  const float inv = 1.f / sqrtf(var + 1e-5f);
  float ov[8];
  unsigned short o8[8];
#pragma unroll
  for (int j = 0; j < 8; ++j) {
    ov[j] = (lv[j] - mean) * inv * g[base + j] + beta[base + j];
    o8[j] = f2bf(ov[j]);
  }
  *(uint4*)(y + (size_t)row * C_ + base) = *(uint4*)o8;
  if (last_out != nullptr && t == T_ - 1) {
    float* lp = last_out + (size_t)bi * C_ + base;
    *(float4*)lp = make_float4(ov[0], ov[1], ov[2], ov[3]);
    *(float4*)(lp + 4) = make_float4(ov[4], ov[5], ov[6], ov[7]);
  }
}

// ---------- token-shift mix (attention: 3 outputs), bf16 in/out ----------
__global__ __launch_bounds__(256) void k_mix3(
    const unsigned short* __restrict__ x1, const float* __restrict__ shift,
    const float* __restrict__ tmk, const float* __restrict__ tmv,
    const float* __restrict__ tmr,
    unsigned short* __restrict__ xk, unsigned short* __restrict__ xv,
    unsigned short* __restrict__ xr) {
  const int row = blockIdx.x;
  const int t = row & (T_ - 1);
  const int bi = row >> 11;
  const int c0 = threadIdx.x * 8;
  const size_t o = (size_t)row * C_ + c0;
  unsigned short cur8[8];
  *(uint4*)cur8 = *(const uint4*)(x1 + o);
  float pv[8];
  if (t == 0) {
    const float* sp = shift + (size_t)bi * C_ + c0;
#pragma unroll
    for (int j = 0; j < 8; ++j) pv[j] = sp[j];
  } else {
    unsigned short p8[8];
    *(uint4*)p8 = *(const uint4*)(x1 + o - C_);
#pragma unroll
    for (int j = 0; j < 8; ++j) pv[j] = b2f(p8[j]);
  }
  unsigned short ok[8], ov[8], orr[8];
#pragma unroll
  for (int j = 0; j < 8; ++j) {
    const float a = b2f(cur8[j]), p = pv[j];
    const float mk = tmk[c0 + j], mv = tmv[c0 + j], mr = tmr[c0 + j];
    ok[j]  = f2bf(a * mk + p * (1.f - mk));
    ov[j]  = f2bf(a * mv + p * (1.f - mv));
    orr[j] = f2bf(a * mr + p * (1.f - mr));
  }
  *(uint4*)(xk + o) = *(uint4*)ok;
  *(uint4*)(xv + o) = *(uint4*)ov;
  *(uint4*)(xr + o) = *(uint4*)orr;
}

// ---------- token-shift mix (ffn: 2 outputs) ----------
__global__ __launch_bounds__(256) void k_mix2(
    const unsigned short* __restrict__ x2, const float* __restrict__ shift,
    const float* __restrict__ fmk, const float* __restrict__ fmr,
    unsigned short* __restrict__ xk2, unsigned short* __restrict__ xr2) {
  const int row = blockIdx.x;
  const int t = row & (T_ - 1);
  const int bi = row >> 11;
  const int c0 = threadIdx.x * 8;
  const size_t o = (size_t)row * C_ + c0;
  unsigned short cur8[8];
  *(uint4*)cur8 = *(const uint4*)(x2 + o);
  float pv[8];
  if (t == 0) {
    const float* sp = shift + (size_t)bi * C_ + c0;
#pragma unroll
    for (int j = 0; j < 8; ++j) pv[j] = sp[j];
  } else {
    unsigned short p8[8];
    *(uint4*)p8 = *(const uint4*)(x2 + o - C_);
#pragma unroll
    for (int j = 0; j < 8; ++j) pv[j] = b2f(p8[j]);
  }
  unsigned short ok[8], orr[8];
#pragma unroll
  for (int j = 0; j < 8; ++j) {
    const float a = b2f(cur8[j]), p = pv[j];
    const float mk = fmk[c0 + j], mr = fmr[c0 + j];
    ok[j]  = f2bf(a * mk + p * (1.f - mk));
    orr[j] = f2bf(a * mr + p * (1.f - mr));
  }
  *(uint4*)(xk2 + o) = *(uint4*)ok;
  *(uint4*)(xr2 + o) = *(uint4*)orr;
}

// ---------- WKV: single-kernel block-local chunked scan (y f32 out) ----------
__global__ __launch_bounds__(256) void k_wkv_blk(
    const float* __restrict__ kk, const float* __restrict__ vv,
    const float* __restrict__ td, const float* __restrict__ tf,
    const float* __restrict__ st, float* __restrict__ y,
    float* __restrict__ out_state) {
  __shared__ float sA[TCH][CHB], sB[TCH][CHB], sP[TCH][CHB];
  const int blk = blockIdx.x;
  const int bi = blk >> 7;
  const int tx = threadIdx.x & 15;
  const int ty = threadIdx.x >> 4;
  const int c = ((blk & 127) * CHB) + tx;
  const float w = -expf(td[c]);
  const float u = tf[c];
  const size_t base = (size_t)bi * T_ * C_ + (size_t)ty * LC2 * C_ + c;
  const float* kp = kk + base;
  const float* vp = vv + base;
  float aa = 0.f, bb = 0.f, pp = -1e38f;
#pragma unroll 8
  for (int i = 0; i < LC2; ++i) {
    const float kt = kp[(size_t)i * C_], vt = vp[(size_t)i * C_];
    const float ww2 = pp + w;
    const float p2 = fmaxf(ww2, kt);
    const float e1b = expf(ww2 - p2), e2b = expf(kt - p2);
    aa = e1b * aa + e2b * vt;
    bb = e1b * bb + e2b;
    pp = p2;
  }
  sA[ty][tx] = aa; sB[ty][tx] = bb; sP[ty][tx] = pp;
  __syncthreads();
  if (ty == 0) {
    const float* s0 = st + (size_t)bi * 3 * C_;
    float ca = s0[c], cb = s0[C_ + c], cp = s0[2 * C_ + c];
    const float wL = w * (float)LC2;
#pragma unroll
    for (int j = 0; j < TCH; ++j) {
      const float a2 = sA[j][tx], b2 = sB[j][tx], p2 = sP[j][tx];
      sA[j][tx] = ca; sB[j][tx] = cb; sP[j][tx] = cp;   // exclusive start
      const float pd = cp + wL;
      const float pm = fmaxf(pd, p2);
      const float e1 = expf(pd - pm), e2 = expf(p2 - pm);
      ca = e1 * ca + e2 * a2;
      cb = e1 * cb + e2 * b2;
      cp = pm;
    }
  }
  __syncthreads();
  aa = sA[ty][tx]; bb = sB[ty][tx]; pp = sP[ty][tx];
  float* yp = y + base;
#pragma unroll 4
  for (int i = 0; i < LC2; ++i) {
    const float kt = kp[(size_t)i * C_], vt = vp[(size_t)i * C_];
    const float ww = u + kt;
    const float p = fmaxf(pp, ww);
    const float e1 = expf(pp - p), e2 = expf(ww - p);
    yp[(size_t)i * C_] = (e1 * aa + e2 * vt) / (e1 * bb + e2);
    const float ww2 = pp + w;
    const float p2 = fmaxf(ww2, kt);
    const float e1b = expf(ww2 - p2), e2b = expf(kt - p2);
    aa = e1b * aa + e2b * vt;
    bb = e1b * bb + e2b;
    pp = p2;
  }
  if (ty == TCH - 1) {
    float* ob = out_state + (size_t)bi * 3 * C_;
    ob[c] = aa; ob[C_ + c] = bb; ob[2 * C_ + c] = pp;
  }
}

// ---------- sigmoid(r)*y -> bf16 (r bf16, y f32) ----------
__global__ __launch_bounds__(256) void k_sry(
    const unsigned short* __restrict__ r, const float* __restrict__ y,
    unsigned short* __restrict__ sry) {
  const int nv = M_ * C_ / 8;
  for (int i = blockIdx.x * 256 + threadIdx.x; i < nv; i += gridDim.x * 256) {
    unsigned short r8[8];
    *(uint4*)r8 = ((const uint4*)r)[i];
    float4 ya = ((const float4*)y)[2 * i], yb = ((const float4*)y)[2 * i + 1];
    const float yv[8] = {ya.x, ya.y, ya.z, ya.w, yb.x, yb.y, yb.z, yb.w};
    unsigned short o8[8];
#pragma unroll
    for (int j = 0; j < 8; ++j) {
      const float s = 1.f / (1.f + expf(-b2f(r8[j])));
      o8[j] = f2bf(s * yv[j]);
    }
    ((uint4*)sry)[i] = *(uint4*)o8;
  }
}

// ---------- 8-phase bf16 MFMA GEMM: 128x256 tile, BK=64, 8 waves ----------
// TRIPLE-buffered 144KiB LDS, prefetch distance 2, counted vmcnt(6) in steady
// state (never drains to 0 mid-loop). Staged via global_load_lds with
// XOR-swizzled SOURCE addresses (linear LDS dest) + matching swizzled ds_read.
// EPI 0: f32; 1: bf16(relu^2); 2: f32(aux1+acc); 3: f32(aux1+sig(acc)*aux2); 4: bf16
template <int EPI, int SWZ>
__global__ __launch_bounds__(512, 1) void k_gemm8(
    const unsigned short* __restrict__ A, const unsigned short* __restrict__ BT,
    int K, int Nn, void* __restrict__ out,
    const float* __restrict__ aux1, const float* __restrict__ aux2) {
  // 3 buffers x (A 8192 + B 16384) ushorts = 73728 ushorts = 144 KiB
  __shared__ unsigned short lds[73728];
  const int tid = threadIdx.x;
  const int lane = tid & 63;
  const int wid = tid >> 6;
  int mBase, nBase;
  if (SWZ) {
    const int gx = gridDim.x;
    int wg = blockIdx.y * gx + blockIdx.x;
    const int nwg = gx * gridDim.y;
    wg = (wg & 7) * (nwg >> 3) + (wg >> 3);   // grids are multiples of 8
    mBase = (wg / gx) * 128;
    nBase = (wg % gx) * 256;
  } else {
    mBase = blockIdx.y * 128;
    nBase = blockIdx.x * 256;
  }
  const int wr = (wid >> 2) * 64;       // wave M offset (2 waves in M)
  const int wc = (wid & 3) * 64;        // wave N offset (4 waves in N)
  const int r16 = lane & 15, kq = lane >> 4;
  const int lrow = lane >> 3;           // staging row within 8-row wave chunk
  const int lslot = (lane & 7) ^ lrow;  // inverse-swizzled SOURCE slot
  const int xsw = r16 & 7;              // read-side xor
  f32x4 acc[4][4] = {};

  const unsigned short* gA0 = A  + (size_t)(mBase + 0   + wid * 8 + lrow) * K + lslot * 8;
  const unsigned short* gA1 = A  + (size_t)(mBase + 64  + wid * 8 + lrow) * K + lslot * 8;
  const unsigned short* gB0 = BT + (size_t)(nBase + 0   + wid * 8 + lrow) * K + lslot * 8;
  const unsigned short* gB1 = BT + (size_t)(nBase + 64  + wid * 8 + lrow) * K + lslot * 8;
  const unsigned short* gB2 = BT + (size_t)(nBase + 128 + wid * 8 + lrow) * K + lslot * 8;
  const unsigned short* gB3 = BT + (size_t)(nBase + 192 + wid * 8 + lrow) * K + lslot * 8;
  const int wof = wid * 512;

  const int nt = K >> 6;
  // prologue: stage tile 0 -> buf0, tile 1 -> buf1 (12 loads/wave in flight)
  gload16(gA0, &lds[0 + wof]);
  gload16(gA1, &lds[4096 + wof]);
  gload16(gB0, &lds[8192 + wof]);
  gload16(gB1, &lds[12288 + wof]);
  gload16(gB2, &lds[16384 + wof]);
  gload16(gB3, &lds[20480 + wof]);
  gload16(gA0 + 64, &lds[24576 + 0 + wof]);
  gload16(gA1 + 64, &lds[24576 + 4096 + wof]);
  gload16(gB0 + 64, &lds[24576 + 8192 + wof]);
  gload16(gB1 + 64, &lds[24576 + 12288 + wof]);
  gload16(gB2 + 64, &lds[24576 + 16384 + wof]);
  gload16(gB3 + 64, &lds[24576 + 20480 + wof]);
  asm volatile("s_waitcnt vmcnt(6)" ::: "memory");   // tile 0 ready, tile 1 flying
  asm volatile("s_barrier" ::: "memory");

  int cb = 0;                           // current buffer = t % 3
  for (int t = 0; t < nt; ++t) {
    const int nb = (cb >= 1) ? cb - 1 : 2;           // (t+2) % 3
    const int ca = cb * 24576;
    const int cbo = cb * 24576 + 8192;
    const int nba = nb * 24576;
    const int kb2 = (t + 2) << 6;
    const bool pf = (t + 2) < nt;
    bf16x8 af[2][2], bq[2][2];
#pragma unroll
    for (int qm = 0; qm < 2; ++qm) {
#pragma unroll
      for (int qn = 0; qn < 2; ++qn) {
        // ds-read this phase's operand fragments (buffer cb)
        if (qn == 0) {
#pragma unroll
          for (int dm = 0; dm < 2; ++dm)
#pragma unroll
            for (int s = 0; s < 2; ++s)
              af[dm][s] = *(const bf16x8*)&lds[ca + (wr + (qm * 2 + dm) * 16 + r16) * 64 +
                                               (((s * 4 + kq) ^ xsw) * 8)];
        }
#pragma unroll
        for (int dn = 0; dn < 2; ++dn)
#pragma unroll
          for (int s = 0; s < 2; ++s)
            bq[dn][s] = *(const bf16x8*)&lds[cbo + (wc + (qn * 2 + dn) * 16 + r16) * 64 +
                                             (((s * 4 + kq) ^ xsw) * 8)];
        // prefetch tile t+2 into buffer nb (phases 0-2: 2 loads each)
        const int ph = qm * 2 + qn;
        if (pf) {
          if (ph == 0) {
            gload16(gA0 + kb2, &lds[nba + 0 + wof]);
            gload16(gA1 + kb2, &lds[nba + 4096 + wof]);
          } else if (ph == 1) {
            gload16(gB0 + kb2, &lds[nba + 8192 + wof]);
            gload16(gB1 + kb2, &lds[nba + 12288 + wof]);
          } else if (ph == 2) {
            gload16(gB2 + kb2, &lds[nba + 16384 + wof]);
            gload16(gB3 + kb2, &lds[nba + 20480 + wof]);
          }
        }
        asm volatile("s_barrier" ::: "memory");
        __builtin_amdgcn_s_setprio(1);
#pragma unroll
        for (int dm = 0; dm < 2; ++dm)
#pragma unroll
          for (int dn = 0; dn < 2; ++dn)
#pragma unroll
            for (int s = 0; s < 2; ++s)
              acc[qm * 2 + dm][qn * 2 + dn] = __builtin_amdgcn_mfma_f32_16x16x32_bf16(
                  af[dm][s], bq[dn][s], acc[qm * 2 + dm][qn * 2 + dn], 0, 0, 0);
        __builtin_amdgcn_s_setprio(0);
        if (ph == 3) {
          if (pf) {
            asm volatile("s_waitcnt vmcnt(6)" ::: "memory");   // t+1 ready, t+2 flying
          } else if (t + 1 < nt) {
            asm volatile("s_waitcnt vmcnt(0)" ::: "memory");   // final drain
          }
        }
        asm volatile("s_barrier" ::: "memory");
      }
    }
    cb = (cb == 2) ? 0 : cb + 1;
  }

  const int c0 = kq * 4;
#pragma unroll
  for (int m = 0; m < 4; ++m) {
#pragma unroll
    for (int n = 0; n < 4; ++n) {
      const int col = nBase + wc + n * 16 + r16;
#pragma unroll
      for (int e = 0; e < 4; ++e) {
        const int rowg = mBase + wr + m * 16 + c0 + e;
        const size_t idx = (size_t)rowg * Nn + col;
        const float va = acc[m][n][e];
        if (EPI == 0) {
          ((float*)out)[idx] = va;
        } else if (EPI == 1) {
          const float t = va > 0.f ? va : 0.f;
          ((unsigned short*)out)[idx] = f2bf(t * t);
        } else if (EPI == 2) {
          ((float*)out)[idx] = aux1[idx] + va;
        } else if (EPI == 3) {
          const float s = 1.f / (1.f + expf(-va));
          ((float*)out)[idx] = aux1[idx] + s * aux2[idx];
        } else {
          ((unsigned short*)out)[idx] = f2bf(va);
        }
      }
    }
  }
}

extern "C" void kernel_launch(void* const* d_in, const int* in_sizes, int n_in,
                              void* d_out, int out_size, void* d_ws, size_t ws_size,
                              hipStream_t stream) {
  const float* x          = (const float*)d_in[0];
  const float* att_shift  = (const float*)d_in[1];
  const float* wkv_state  = (const float*)d_in[2];
  const float* ffn_shift  = (const float*)d_in[3];
  const float* ln1_g = (const float*)d_in[4];
  const float* ln1_b = (const float*)d_in[5];
  const float* ln2_g = (const float*)d_in[6];
  const float* ln2_b = (const float*)d_in[7];
  const float* tmk = (const float*)d_in[8];
  const float* tmv = (const float*)d_in[9];
  const float* tmr = (const float*)d_in[10];
  const float* time_decay = (const float*)d_in[11];
  const float* time_first = (const float*)d_in[12];
  const float* Wk = (const float*)d_in[13];
  const float* Wv = (const float*)d_in[14];
  const float* Wr = (const float*)d_in[15];
  const float* Wo = (const float*)d_in[16];
  const float* fmk = (const float*)d_in[17];
  const float* fmr = (const float*)d_in[18];
  const float* Fk = (const float*)d_in[19];
  const float* Fr = (const float*)d_in[20];
  const float* Fv = (const float*)d_in[21];

  // ---- 176 MiB workspace, strictly sequential reuse, zero in-flight overlap ----
  const size_t MB = 1ull << 20;
  char* ws = (char*)d_ws;
  if (ws_size < 176 * MB) return;

  unsigned short* Wslot = (unsigned short*)(ws);             //   0.. 32 weight slot
  float*          kBuf  = (float*)(ws + 32 * MB);            //  32.. 64 k f32
  float*          vBuf  = (float*)(ws + 64 * MB);            //  64.. 96 v f32
  float*          yBuf  = (float*)(ws + 96 * MB);            //  96..128 y f32 -> x_att f32
  unsigned short* h1    = (unsigned short*)(ws + 128 * MB);  // 128..144 x1 -> r -> x2
  unsigned short* h2    = (unsigned short*)(ws + 144 * MB);  // 144..160 xk -> sry -> xk2
  unsigned short* h3    = (unsigned short*)(ws + 160 * MB);  // 160..176 xv -> xr2
  unsigned short* xrT   = (unsigned short*)kBuf;             // xr bf16, before k exists
  unsigned short* kf    = (unsigned short*)kBuf;             // 64 MiB: 32..96 (k,v dead)
  float*          kv    = (float*)h1;                        // 32 MiB: 128..160 (x2,xk2 dead)

  // ---- f32 outputs, concatenated in reference return order ----
  float* outb    = (float*)d_out;
  float* x1_last = outb + (size_t)M_ * C_;        // [B,C]
  float* wkv_out = x1_last + (size_t)B_ * C_;     // [B,3,C]
  float* x2_last = wkv_out + (size_t)B_ * 3 * C_; // [B,C]

  const dim3 gCC(C_ / 32, C_ / 32);
  const dim3 gC8(C_ / 256, M_ / 128);      // 8 x 32 = 256 WGs
  const dim3 gF8(F_ / 256, M_ / 128);      // 32 x 32 = 1024 WGs

  // ---- attention path ----
  k_layernorm<<<M_, 256, 0, stream>>>(x, ln1_g, ln1_b, h1, x1_last);           // x1 -> h1
  k_mix3<<<M_, 256, 0, stream>>>(h1, att_shift, tmk, tmv, tmr, h2, h3, xrT);   // xk,xv,xr
  k_transpose_cast<<<gCC, 256, 0, stream>>>(Wr, Wslot, C_, C_);
  k_gemm8<4,0><<<gC8, 512, 0, stream>>>(xrT, Wslot, C_, C_, h1, nullptr, nullptr); // r bf16 -> h1
  k_transpose_cast<<<gCC, 256, 0, stream>>>(Wk, Wslot, C_, C_);
  k_gemm8<0,0><<<gC8, 512, 0, stream>>>(h2, Wslot, C_, C_, kBuf, nullptr, nullptr); // k f32 (over xr, dead)
  k_transpose_cast<<<gCC, 256, 0, stream>>>(Wv, Wslot, C_, C_);
  k_gemm8<0,0><<<gC8, 512, 0, stream>>>(h3, Wslot, C_, C_, vBuf, nullptr, nullptr); // v f32
  // WKV: single kernel, block-local scan (no cross-kernel scratch)
  k_wkv_blk<<<dim3(BC_ / CHB), 256, 0, stream>>>(kBuf, vBuf, time_decay, time_first,
                                                 wkv_state, yBuf, wkv_out);
  k_sry<<<1024, 256, 0, stream>>>(h1, yBuf, h2);                                // sry -> h2 (xk dead)
  k_transpose_cast<<<gCC, 256, 0, stream>>>(Wo, Wslot, C_, C_);
  k_gemm8<2,0><<<gC8, 512, 0, stream>>>(h2, Wslot, C_, C_, yBuf, x, nullptr);   // x_att f32 (over y, dead)

  // ---- ffn path ----
  k_layernorm<<<M_, 256, 0, stream>>>(yBuf, ln2_g, ln2_b, h1, x2_last);         // x2 -> h1 (r dead)
  k_mix2<<<M_, 256, 0, stream>>>(h1, ffn_shift, fmk, fmr, h2, h3);              // xk2,xr2 (sry,xv dead)
  k_transpose_cast<<<dim3(F_ / 32, C_ / 32), 256, 0, stream>>>(Fk, Wslot, C_, F_);
  k_gemm8<1,1><<<gF8, 512, 0, stream>>>(h2, Wslot, C_, F_, kf, nullptr, nullptr); // kf bf16 (k,v dead)
  k_transpose_cast<<<dim3(C_ / 32, F_ / 32), 256, 0, stream>>>(Fv, Wslot, F_, C_);
  k_gemm8<0,1><<<gC8, 512, 0, stream>>>(kf, Wslot, F_, C_, kv, nullptr, nullptr); // kv f32 (x2,xk2 dead)
  k_transpose_cast<<<gCC, 256, 0, stream>>>(Fr, Wslot, C_, C_);
  k_gemm8<3,0><<<gC8, 512, 0, stream>>>(h3, Wslot, C_, C_, d_out, yBuf, kv);    // final f32
}

// Round 13
// 695.530 us; speedup vs baseline: 1.2450x; 1.0651x over previous
//
#include <hip/hip_runtime.h>
#include <stdint.h>

#define B_ 2
#define T_ 2048
#define C_ 2048
#define F_ 8192
#define M_ 4096   // B_*T_
#define BC_ 4096  // B_*C_
#define CHB 16    // channels per WKV block
#define TCH 16    // time chunks per WKV block
#define LC2 128   // T_/TCH

typedef __attribute__((ext_vector_type(8))) __bf16 bf16x8;
typedef __attribute__((ext_vector_type(4))) float f32x4;

__device__ __forceinline__ unsigned short f2bf(float f) {
  union { float f; unsigned u; } v; v.f = f;
  unsigned r = v.u + 0x7fffu + ((v.u >> 16) & 1u);
  return (unsigned short)(r >> 16);
}
__device__ __forceinline__ float b2f(unsigned short h) {
  union { unsigned u; float f; } v; v.u = ((unsigned)h) << 16; return v.f;
}

__device__ __forceinline__ void gload16(const void* g, void* l) {
  __builtin_amdgcn_global_load_lds((__attribute__((address_space(1))) void*)g,
                                   (__attribute__((address_space(3))) void*)l,
                                   16, 0, 0);
}

// ---------- transpose + f32->bf16: WT[n][k] = W[k][n] ----------
__global__ __launch_bounds__(256) void k_transpose_cast(
    const float* __restrict__ W, unsigned short* __restrict__ WT, int K, int N) {
  __shared__ unsigned short tile[32][33];
  const int n0 = blockIdx.x * 32, k0 = blockIdx.y * 32;
  const int tx = threadIdx.x & 31, ty = threadIdx.x >> 5;
#pragma unroll
  for (int i = 0; i < 4; ++i)
    tile[ty + 8 * i][tx] = f2bf(W[(size_t)(k0 + ty + 8 * i) * N + n0 + tx]);
  __syncthreads();
#pragma unroll
  for (int i = 0; i < 4; ++i)
    WT[(size_t)(n0 + ty + 8 * i) * K + k0 + tx] = tile[tx][ty + 8 * i];
}

// ---------- LayerNorm over C=2048 (f32 in, bf16 out + f32 last-row out) ----------
__global__ __launch_bounds__(256) void k_layernorm(
    const float* __restrict__ x, const float* __restrict__ g,
    const float* __restrict__ beta, unsigned short* __restrict__ y,
    float* __restrict__ last_out) {
  const int row = blockIdx.x;
  const int t = row & (T_ - 1);
  const int bi = row >> 11;
  const float* xr = x + (size_t)row * C_;
  const int base = threadIdx.x * 8;
  float lv[8];
  {
    float4 a = *(const float4*)(xr + base);
    float4 b = *(const float4*)(xr + base + 4);
    lv[0]=a.x; lv[1]=a.y; lv[2]=a.z; lv[3]=a.w; lv[4]=b.x; lv[5]=b.y; lv[6]=b.z; lv[7]=b.w;
  }
  float s = 0.f, q = 0.f;
#pragma unroll
  for (int j = 0; j < 8; ++j) { s += lv[j]; q += lv[j] * lv[j]; }
#pragma unroll
  for (int o = 32; o > 0; o >>= 1) { s += __shfl_down(s, o); q += __shfl_down(q, o); }
  __shared__ float rs[4], rq[4];
  if ((threadIdx.x & 63) == 0) { rs[threadIdx.x >> 6] = s; rq[threadIdx.x >> 6] = q; }
  __syncthreads();
  s = rs[0] + rs[1] + rs[2] + rs[3];
  q = rq[0] + rq[1] + rq[2] + rq[3];
  const float mean = s * (1.f / C_);
  const float var = q * (1.f / C_) - mean * mean;
  const float inv = 1.f / sqrtf(var + 1e-5f);
  float ov[8];
  unsigned short o8[8];
#pragma unroll
  for (int j = 0; j < 8; ++j) {
    ov[j] = (lv[j] - mean) * inv * g[base + j] + beta[base + j];
    o8[j] = f2bf(ov[j]);
  }
  *(uint4*)(y + (size_t)row * C_ + base) = *(uint4*)o8;
  if (last_out != nullptr && t == T_ - 1) {
    float* lp = last_out + (size_t)bi * C_ + base;
    *(float4*)lp = make_float4(ov[0], ov[1], ov[2], ov[3]);
    *(float4*)(lp + 4) = make_float4(ov[4], ov[5], ov[6], ov[7]);
  }
}

// ---------- token-shift mix (attention: 3 outputs), bf16 in/out ----------
__global__ __launch_bounds__(256) void k_mix3(
    const unsigned short* __restrict__ x1, const float* __restrict__ shift,
    const float* __restrict__ tmk, const float* __restrict__ tmv,
    const float* __restrict__ tmr,
    unsigned short* __restrict__ xk, unsigned short* __restrict__ xv,
    unsigned short* __restrict__ xr) {
  const int row = blockIdx.x;
  const int t = row & (T_ - 1);
  const int bi = row >> 11;
  const int c0 = threadIdx.x * 8;
  const size_t o = (size_t)row * C_ + c0;
  unsigned short cur8[8];
  *(uint4*)cur8 = *(const uint4*)(x1 + o);
  float pv[8];
  if (t == 0) {
    const float* sp = shift + (size_t)bi * C_ + c0;
#pragma unroll
    for (int j = 0; j < 8; ++j) pv[j] = sp[j];
  } else {
    unsigned short p8[8];
    *(uint4*)p8 = *(const uint4*)(x1 + o - C_);
#pragma unroll
    for (int j = 0; j < 8; ++j) pv[j] = b2f(p8[j]);
  }
  unsigned short ok[8], ov[8], orr[8];
#pragma unroll
  for (int j = 0; j < 8; ++j) {
    const float a = b2f(cur8[j]), p = pv[j];
    const float mk = tmk[c0 + j], mv = tmv[c0 + j], mr = tmr[c0 + j];
    ok[j]  = f2bf(a * mk + p * (1.f - mk));
    ov[j]  = f2bf(a * mv + p * (1.f - mv));
    orr[j] = f2bf(a * mr + p * (1.f - mr));
  }
  *(uint4*)(xk + o) = *(uint4*)ok;
  *(uint4*)(xv + o) = *(uint4*)ov;
  *(uint4*)(xr + o) = *(uint4*)orr;
}

// ---------- token-shift mix (ffn: 2 outputs) ----------
__global__ __launch_bounds__(256) void k_mix2(
    const unsigned short* __restrict__ x2, const float* __restrict__ shift,
    const float* __restrict__ fmk, const float* __restrict__ fmr,
    unsigned short* __restrict__ xk2, unsigned short* __restrict__ xr2) {
  const int row = blockIdx.x;
  const int t = row & (T_ - 1);
  const int bi = row >> 11;
  const int c0 = threadIdx.x * 8;
  const size_t o = (size_t)row * C_ + c0;
  unsigned short cur8[8];
  *(uint4*)cur8 = *(const uint4*)(x2 + o);
  float pv[8];
  if (t == 0) {
    const float* sp = shift + (size_t)bi * C_ + c0;
#pragma unroll
    for (int j = 0; j < 8; ++j) pv[j] = sp[j];
  } else {
    unsigned short p8[8];
    *(uint4*)p8 = *(const uint4*)(x2 + o - C_);
#pragma unroll
    for (int j = 0; j < 8; ++j) pv[j] = b2f(p8[j]);
  }
  unsigned short ok[8], orr[8];
#pragma unroll
  for (int j = 0; j < 8; ++j) {
    const float a = b2f(cur8[j]), p = pv[j];
    const float mk = fmk[c0 + j], mr = fmr[c0 + j];
    ok[j]  = f2bf(a * mk + p * (1.f - mk));
    orr[j] = f2bf(a * mr + p * (1.f - mr));
  }
  *(uint4*)(xk2 + o) = *(uint4*)ok;
  *(uint4*)(xr2 + o) = *(uint4*)orr;
}

// ---------- WKV: single-kernel block-local chunked scan (y f32 out) ----------
__global__ __launch_bounds__(256) void k_wkv_blk(
    const float* __restrict__ kk, const float* __restrict__ vv,
    const float* __restrict__ td, const float* __restrict__ tf,
    const float* __restrict__ st, float* __restrict__ y,
    float* __restrict__ out_state) {
  __shared__ float sA[TCH][CHB], sB[TCH][CHB], sP[TCH][CHB];
  const int blk = blockIdx.x;
  const int bi = blk >> 7;
  const int tx = threadIdx.x & 15;
  const int ty = threadIdx.x >> 4;
  const int c = ((blk & 127) * CHB) + tx;
  const float w = -expf(td[c]);
  const float u = tf[c];
  const size_t base = (size_t)bi * T_ * C_ + (size_t)ty * LC2 * C_ + c;
  const float* kp = kk + base;
  const float* vp = vv + base;
  float aa = 0.f, bb = 0.f, pp = -1e38f;
#pragma unroll 8
  for (int i = 0; i < LC2; ++i) {
    const float kt = kp[(size_t)i * C_], vt = vp[(size_t)i * C_];
    const float ww2 = pp + w;
    const float p2 = fmaxf(ww2, kt);
    const float e1b = expf(ww2 - p2), e2b = expf(kt - p2);
    aa = e1b * aa + e2b * vt;
    bb = e1b * bb + e2b;
    pp = p2;
  }
  sA[ty][tx] = aa; sB[ty][tx] = bb; sP[ty][tx] = pp;
  __syncthreads();
  if (ty == 0) {
    const float* s0 = st + (size_t)bi * 3 * C_;
    float ca = s0[c], cb = s0[C_ + c], cp = s0[2 * C_ + c];
    const float wL = w * (float)LC2;
#pragma unroll
    for (int j = 0; j < TCH; ++j) {
      const float a2 = sA[j][tx], b2 = sB[j][tx], p2 = sP[j][tx];
      sA[j][tx] = ca; sB[j][tx] = cb; sP[j][tx] = cp;   // exclusive start
      const float pd = cp + wL;
      const float pm = fmaxf(pd, p2);
      const float e1 = expf(pd - pm), e2 = expf(p2 - pm);
      ca = e1 * ca + e2 * a2;
      cb = e1 * cb + e2 * b2;
      cp = pm;
    }
  }
  __syncthreads();
  aa = sA[ty][tx]; bb = sB[ty][tx]; pp = sP[ty][tx];
  float* yp = y + base;
#pragma unroll 4
  for (int i = 0; i < LC2; ++i) {
    const float kt = kp[(size_t)i * C_], vt = vp[(size_t)i * C_];
    const float ww = u + kt;
    const float p = fmaxf(pp, ww);
    const float e1 = expf(pp - p), e2 = expf(ww - p);
    yp[(size_t)i * C_] = (e1 * aa + e2 * vt) / (e1 * bb + e2);
    const float ww2 = pp + w;
    const float p2 = fmaxf(ww2, kt);
    const float e1b = expf(ww2 - p2), e2b = expf(kt - p2);
    aa = e1b * aa + e2b * vt;
    bb = e1b * bb + e2b;
    pp = p2;
  }
  if (ty == TCH - 1) {
    float* ob = out_state + (size_t)bi * 3 * C_;
    ob[c] = aa; ob[C_ + c] = bb; ob[2 * C_ + c] = pp;
  }
}

// ---------- sigmoid(r)*y -> bf16 (r bf16, y f32) ----------
__global__ __launch_bounds__(256) void k_sry(
    const unsigned short* __restrict__ r, const float* __restrict__ y,
    unsigned short* __restrict__ sry) {
  const int nv = M_ * C_ / 8;
  for (int i = blockIdx.x * 256 + threadIdx.x; i < nv; i += gridDim.x * 256) {
    unsigned short r8[8];
    *(uint4*)r8 = ((const uint4*)r)[i];
    float4 ya = ((const float4*)y)[2 * i], yb = ((const float4*)y)[2 * i + 1];
    const float yv[8] = {ya.x, ya.y, ya.z, ya.w, yb.x, yb.y, yb.z, yb.w};
    unsigned short o8[8];
#pragma unroll
    for (int j = 0; j < 8; ++j) {
      const float s = 1.f / (1.f + expf(-b2f(r8[j])));
      o8[j] = f2bf(s * yv[j]);
    }
    ((uint4*)sry)[i] = *(uint4*)o8;
  }
}

// ---------- bf16 MFMA GEMM: 128x256 tile, BK=64, 8 waves, single-barrier tiles --
// TRIPLE-buffered 144KiB LDS, prefetch distance 2, counted vmcnt(6). Because the
// written buffer (t+2) is never the read buffer (t), ONE barrier per K-tile
// suffices. All 16 fragments (8 A + 8 B) read once per tile (no B double-read);
// compiler interleaves ds_read/MFMA with fine lgkmcnt. XOR-swizzled staging
// (source-side) + matching swizzled ds_read (rule 21).
// EPI 0: f32; 1: bf16(relu^2); 2: f32(aux1+acc); 3: f32(aux1+sig(acc)*aux2); 4: bf16
template <int EPI, int SWZ>
__global__ __launch_bounds__(512, 1) void k_gemm8(
    const unsigned short* __restrict__ A, const unsigned short* __restrict__ BT,
    int K, int Nn, void* __restrict__ out,
    const float* __restrict__ aux1, const float* __restrict__ aux2) {
  // 3 buffers x (A 8192 + B 16384) ushorts = 73728 ushorts = 144 KiB
  __shared__ unsigned short lds[73728];
  const int tid = threadIdx.x;
  const int lane = tid & 63;
  const int wid = tid >> 6;
  int mBase, nBase;
  if (SWZ) {
    const int gx = gridDim.x;
    int wg = blockIdx.y * gx + blockIdx.x;
    const int nwg = gx * gridDim.y;
    wg = (wg & 7) * (nwg >> 3) + (wg >> 3);   // grids are multiples of 8
    mBase = (wg / gx) * 128;
    nBase = (wg % gx) * 256;
  } else {
    mBase = blockIdx.y * 128;
    nBase = blockIdx.x * 256;
  }
  const int wr = (wid >> 2) * 64;       // wave M offset (2 waves in M)
  const int wc = (wid & 3) * 64;        // wave N offset (4 waves in N)
  const int r16 = lane & 15, kq = lane >> 4;
  const int lrow = lane >> 3;           // staging row within 8-row wave chunk
  const int lslot = (lane & 7) ^ lrow;  // inverse-swizzled SOURCE slot
  const int xsw = r16 & 7;              // read-side xor
  f32x4 acc[4][4] = {};

  const unsigned short* gA0 = A  + (size_t)(mBase + 0   + wid * 8 + lrow) * K + lslot * 8;
  const unsigned short* gA1 = A  + (size_t)(mBase + 64  + wid * 8 + lrow) * K + lslot * 8;
  const unsigned short* gB0 = BT + (size_t)(nBase + 0   + wid * 8 + lrow) * K + lslot * 8;
  const unsigned short* gB1 = BT + (size_t)(nBase + 64  + wid * 8 + lrow) * K + lslot * 8;
  const unsigned short* gB2 = BT + (size_t)(nBase + 128 + wid * 8 + lrow) * K + lslot * 8;
  const unsigned short* gB3 = BT + (size_t)(nBase + 192 + wid * 8 + lrow) * K + lslot * 8;
  const int wof = wid * 512;
  // lane-relative LDS read offsets (ushort index), frag (m|n, s)
  int aoff[4][2], boff[4][2];
#pragma unroll
  for (int m = 0; m < 4; ++m)
#pragma unroll
    for (int s = 0; s < 2; ++s)
      aoff[m][s] = (wr + m * 16 + r16) * 64 + (((s * 4 + kq) ^ xsw) * 8);
#pragma unroll
  for (int n = 0; n < 4; ++n)
#pragma unroll
    for (int s = 0; s < 2; ++s)
      boff[n][s] = 8192 + (wc + n * 16 + r16) * 64 + (((s * 4 + kq) ^ xsw) * 8);

  const int nt = K >> 6;
  // prologue: stage tile 0 -> buf0, tile 1 -> buf1 (12 loads/wave in flight)
  gload16(gA0, &lds[0 + wof]);
  gload16(gA1, &lds[4096 + wof]);
  gload16(gB0, &lds[8192 + wof]);
  gload16(gB1, &lds[12288 + wof]);
  gload16(gB2, &lds[16384 + wof]);
  gload16(gB3, &lds[20480 + wof]);
  gload16(gA0 + 64, &lds[24576 + 0 + wof]);
  gload16(gA1 + 64, &lds[24576 + 4096 + wof]);
  gload16(gB0 + 64, &lds[24576 + 8192 + wof]);
  gload16(gB1 + 64, &lds[24576 + 12288 + wof]);
  gload16(gB2 + 64, &lds[24576 + 16384 + wof]);
  gload16(gB3 + 64, &lds[24576 + 20480 + wof]);
  asm volatile("s_waitcnt vmcnt(6)" ::: "memory");   // tile 0 ready, tile 1 flying
  asm volatile("s_barrier" ::: "memory");

  int cb = 0;                           // current buffer = t % 3
  for (int t = 0; t < nt; ++t) {
    const int nb = (cb >= 1) ? cb - 1 : 2;           // (t+2) % 3
    const int ca = cb * 24576;
    const int nba = nb * 24576;
    const int kb2 = (t + 2) << 6;
    const bool pf = (t + 2) < nt;
    // issue prefetch of tile t+2 first (longest time in flight)
    if (pf) {
      gload16(gA0 + kb2, &lds[nba + 0 + wof]);
      gload16(gA1 + kb2, &lds[nba + 4096 + wof]);
      gload16(gB0 + kb2, &lds[nba + 8192 + wof]);
      gload16(gB1 + kb2, &lds[nba + 12288 + wof]);
      gload16(gB2 + kb2, &lds[nba + 16384 + wof]);
      gload16(gB3 + kb2, &lds[nba + 20480 + wof]);
    }
    // read all 16 fragments once
    bf16x8 af[4][2], bq[4][2];
#pragma unroll
    for (int m = 0; m < 4; ++m)
#pragma unroll
      for (int s = 0; s < 2; ++s)
        af[m][s] = *(const bf16x8*)&lds[ca + aoff[m][s]];
#pragma unroll
    for (int n = 0; n < 4; ++n)
#pragma unroll
      for (int s = 0; s < 2; ++s)
        bq[n][s] = *(const bf16x8*)&lds[ca + boff[n][s]];
    __builtin_amdgcn_s_setprio(1);
#pragma unroll
    for (int m = 0; m < 4; ++m)
#pragma unroll
      for (int n = 0; n < 4; ++n)
#pragma unroll
        for (int s = 0; s < 2; ++s)
          acc[m][n] = __builtin_amdgcn_mfma_f32_16x16x32_bf16(
              af[m][s], bq[n][s], acc[m][n], 0, 0, 0);
    __builtin_amdgcn_s_setprio(0);
    if (pf) {
      asm volatile("s_waitcnt vmcnt(6)" ::: "memory");   // t+1 ready, t+2 flying
    } else if (t + 1 < nt) {
      asm volatile("s_waitcnt vmcnt(0)" ::: "memory");   // final drain
    }
    asm volatile("s_barrier" ::: "memory");
    cb = (cb == 2) ? 0 : cb + 1;
  }

  const int c0 = kq * 4;
#pragma unroll
  for (int m = 0; m < 4; ++m) {
#pragma unroll
    for (int n = 0; n < 4; ++n) {
      const int col = nBase + wc + n * 16 + r16;
#pragma unroll
      for (int e = 0; e < 4; ++e) {
        const int rowg = mBase + wr + m * 16 + c0 + e;
        const size_t idx = (size_t)rowg * Nn + col;
        const float va = acc[m][n][e];
        if (EPI == 0) {
          ((float*)out)[idx] = va;
        } else if (EPI == 1) {
          const float t = va > 0.f ? va : 0.f;
          ((unsigned short*)out)[idx] = f2bf(t * t);
        } else if (EPI == 2) {
          ((float*)out)[idx] = aux1[idx] + va;
        } else if (EPI == 3) {
          const float s = 1.f / (1.f + expf(-va));
          ((float*)out)[idx] = aux1[idx] + s * aux2[idx];
        } else {
          ((unsigned short*)out)[idx] = f2bf(va);
        }
      }
    }
  }
}

extern "C" void kernel_launch(void* const* d_in, const int* in_sizes, int n_in,
                              void* d_out, int out_size, void* d_ws, size_t ws_size,
                              hipStream_t stream) {
  const float* x          = (const float*)d_in[0];
  const float* att_shift  = (const float*)d_in[1];
  const float* wkv_state  = (const float*)d_in[2];
  const float* ffn_shift  = (const float*)d_in[3];
  const float* ln1_g = (const float*)d_in[4];
  const float* ln1_b = (const float*)d_in[5];
  const float* ln2_g = (const float*)d_in[6];
  const float* ln2_b = (const float*)d_in[7];
  const float* tmk = (const float*)d_in[8];
  const float* tmv = (const float*)d_in[9];
  const float* tmr = (const float*)d_in[10];
  const float* time_decay = (const float*)d_in[11];
  const float* time_first = (const float*)d_in[12];
  const float* Wk = (const float*)d_in[13];
  const float* Wv = (const float*)d_in[14];
  const float* Wr = (const float*)d_in[15];
  const float* Wo = (const float*)d_in[16];
  const float* fmk = (const float*)d_in[17];
  const float* fmr = (const float*)d_in[18];
  const float* Fk = (const float*)d_in[19];
  const float* Fr = (const float*)d_in[20];
  const float* Fv = (const float*)d_in[21];

  // ---- 176 MiB workspace, strictly sequential reuse, zero in-flight overlap ----
  const size_t MB = 1ull << 20;
  char* ws = (char*)d_ws;
  if (ws_size < 176 * MB) return;

  unsigned short* Wslot = (unsigned short*)(ws);             //   0.. 32 weight slot
  float*          kBuf  = (float*)(ws + 32 * MB);            //  32.. 64 k f32
  float*          vBuf  = (float*)(ws + 64 * MB);            //  64.. 96 v f32
  float*          yBuf  = (float*)(ws + 96 * MB);            //  96..128 y f32 -> x_att f32
  unsigned short* h1    = (unsigned short*)(ws + 128 * MB);  // 128..144 x1 -> r -> x2
  unsigned short* h2    = (unsigned short*)(ws + 144 * MB);  // 144..160 xk -> sry -> xk2
  unsigned short* h3    = (unsigned short*)(ws + 160 * MB);  // 160..176 xv -> xr2
  unsigned short* xrT   = (unsigned short*)kBuf;             // xr bf16, before k exists
  unsigned short* kf    = (unsigned short*)kBuf;             // 64 MiB: 32..96 (k,v dead)
  float*          kv    = (float*)h1;                        // 32 MiB: 128..160 (x2,xk2 dead)

  // ---- f32 outputs, concatenated in reference return order ----
  float* outb    = (float*)d_out;
  float* x1_last = outb + (size_t)M_ * C_;        // [B,C]
  float* wkv_out = x1_last + (size_t)B_ * C_;     // [B,3,C]
  float* x2_last = wkv_out + (size_t)B_ * 3 * C_; // [B,C]

  const dim3 gCC(C_ / 32, C_ / 32);
  const dim3 gC8(C_ / 256, M_ / 128);      // 8 x 32 = 256 WGs
  const dim3 gF8(F_ / 256, M_ / 128);      // 32 x 32 = 1024 WGs

  // ---- attention path ----
  k_layernorm<<<M_, 256, 0, stream>>>(x, ln1_g, ln1_b, h1, x1_last);           // x1 -> h1
  k_mix3<<<M_, 256, 0, stream>>>(h1, att_shift, tmk, tmv, tmr, h2, h3, xrT);   // xk,xv,xr
  k_transpose_cast<<<gCC, 256, 0, stream>>>(Wr, Wslot, C_, C_);
  k_gemm8<4,0><<<gC8, 512, 0, stream>>>(xrT, Wslot, C_, C_, h1, nullptr, nullptr); // r bf16 -> h1
  k_transpose_cast<<<gCC, 256, 0, stream>>>(Wk, Wslot, C_, C_);
  k_gemm8<0,0><<<gC8, 512, 0, stream>>>(h2, Wslot, C_, C_, kBuf, nullptr, nullptr); // k f32 (over xr, dead)
  k_transpose_cast<<<gCC, 256, 0, stream>>>(Wv, Wslot, C_, C_);
  k_gemm8<0,0><<<gC8, 512, 0, stream>>>(h3, Wslot, C_, C_, vBuf, nullptr, nullptr); // v f32
  // WKV: single kernel, block-local scan (no cross-kernel scratch)
  k_wkv_blk<<<dim3(BC_ / CHB), 256, 0, stream>>>(kBuf, vBuf, time_decay, time_first,
                                                 wkv_state, yBuf, wkv_out);
  k_sry<<<1024, 256, 0, stream>>>(h1, yBuf, h2);                                // sry -> h2 (xk dead)
  k_transpose_cast<<<gCC, 256, 0, stream>>>(Wo, Wslot, C_, C_);
  k_gemm8<2,0><<<gC8, 512, 0, stream>>>(h2, Wslot, C_, C_, yBuf, x, nullptr);   // x_att f32 (over y, dead)

  // ---- ffn path ----
  k_layernorm<<<M_, 256, 0, stream>>>(yBuf, ln2_g, ln2_b, h1, x2_last);         // x2 -> h1 (r dead)
  k_mix2<<<M_, 256, 0, stream>>>(h1, ffn_shift, fmk, fmr, h2, h3);              // xk2,xr2 (sry,xv dead)
  k_transpose_cast<<<dim3(F_ / 32, C_ / 32), 256, 0, stream>>>(Fk, Wslot, C_, F_);
  k_gemm8<1,1><<<gF8, 512, 0, stream>>>(h2, Wslot, C_, F_, kf, nullptr, nullptr); // kf bf16 (k,v dead)
  k_transpose_cast<<<dim3(C_ / 32, F_ / 32), 256, 0, stream>>>(Fv, Wslot, F_, C_);
  k_gemm8<0,1><<<gC8, 512, 0, stream>>>(kf, Wslot, F_, C_, kv, nullptr, nullptr); // kv f32 (x2,xk2 dead)
  k_transpose_cast<<<gCC, 256, 0, stream>>>(Fr, Wslot, C_, C_);
  k_gemm8<3,0><<<gC8, 512, 0, stream>>>(h3, Wslot, C_, C_, d_out, yBuf, kv);    // final f32
}

// Round 14
// 678.967 us; speedup vs baseline: 1.2754x; 1.0244x over previous
//
#include <hip/hip_runtime.h>
#include <stdint.h>

#define B_ 2
#define T_ 2048
#define C_ 2048
#define F_ 8192
#define M_ 4096   // B_*T_
#define BC_ 4096  // B_*C_
#define CHB 16    // channels per WKV block
#define TCH 16    // time chunks per WKV block
#define LC2 128   // T_/TCH

typedef __attribute__((ext_vector_type(8))) __bf16 bf16x8;
typedef __attribute__((ext_vector_type(4))) float f32x4;

__device__ __forceinline__ unsigned short f2bf(float f) {
  union { float f; unsigned u; } v; v.f = f;
  unsigned r = v.u + 0x7fffu + ((v.u >> 16) & 1u);
  return (unsigned short)(r >> 16);
}
__device__ __forceinline__ float b2f(unsigned short h) {
  union { unsigned u; float f; } v; v.u = ((unsigned)h) << 16; return v.f;
}

__device__ __forceinline__ void gload16(const void* g, void* l) {
  __builtin_amdgcn_global_load_lds((__attribute__((address_space(1))) void*)g,
                                   (__attribute__((address_space(3))) void*)l,
                                   16, 0, 0);
}

// ---------- transpose + f32->bf16: WT[n][k] = W[k][n] ----------
__global__ __launch_bounds__(256) void k_transpose_cast(
    const float* __restrict__ W, unsigned short* __restrict__ WT, int K, int N) {
  __shared__ unsigned short tile[32][33];
  const int n0 = blockIdx.x * 32, k0 = blockIdx.y * 32;
  const int tx = threadIdx.x & 31, ty = threadIdx.x >> 5;
#pragma unroll
  for (int i = 0; i < 4; ++i)
    tile[ty + 8 * i][tx] = f2bf(W[(size_t)(k0 + ty + 8 * i) * N + n0 + tx]);
  __syncthreads();
#pragma unroll
  for (int i = 0; i < 4; ++i)
    WT[(size_t)(n0 + ty + 8 * i) * K + k0 + tx] = tile[tx][ty + 8 * i];
}

// ---------- LayerNorm over C=2048 (f32 in, bf16 out + f32 last-row out) ----------
__global__ __launch_bounds__(256) void k_layernorm(
    const float* __restrict__ x, const float* __restrict__ g,
    const float* __restrict__ beta, unsigned short* __restrict__ y,
    float* __restrict__ last_out) {
  const int row = blockIdx.x;
  const int t = row & (T_ - 1);
  const int bi = row >> 11;
  const float* xr = x + (size_t)row * C_;
  const int base = threadIdx.x * 8;
  float lv[8];
  {
    float4 a = *(const float4*)(xr + base);
    float4 b = *(const float4*)(xr + base + 4);
    lv[0]=a.x; lv[1]=a.y; lv[2]=a.z; lv[3]=a.w; lv[4]=b.x; lv[5]=b.y; lv[6]=b.z; lv[7]=b.w;
  }
  float s = 0.f, q = 0.f;
#pragma unroll
  for (int j = 0; j < 8; ++j) { s += lv[j]; q += lv[j] * lv[j]; }
#pragma unroll
  for (int o = 32; o > 0; o >>= 1) { s += __shfl_down(s, o); q += __shfl_down(q, o); }
  __shared__ float rs[4], rq[4];
  if ((threadIdx.x & 63) == 0) { rs[threadIdx.x >> 6] = s; rq[threadIdx.x >> 6] = q; }
  __syncthreads();
  s = rs[0] + rs[1] + rs[2] + rs[3];
  q = rq[0] + rq[1] + rq[2] + rq[3];
  const float mean = s * (1.f / C_);
  const float var = q * (1.f / C_) - mean * mean;
  const float inv = 1.f / sqrtf(var + 1e-5f);
  float ov[8];
  unsigned short o8[8];
#pragma unroll
  for (int j = 0; j < 8; ++j) {
    ov[j] = (lv[j] - mean) * inv * g[base + j] + beta[base + j];
    o8[j] = f2bf(ov[j]);
  }
  *(uint4*)(y + (size_t)row * C_ + base) = *(uint4*)o8;
  if (last_out != nullptr && t == T_ - 1) {
    float* lp = last_out + (size_t)bi * C_ + base;
    *(float4*)lp = make_float4(ov[0], ov[1], ov[2], ov[3]);
    *(float4*)(lp + 4) = make_float4(ov[4], ov[5], ov[6], ov[7]);
  }
}

// ---------- token-shift mix (attention: 3 outputs), bf16 in/out ----------
__global__ __launch_bounds__(256) void k_mix3(
    const unsigned short* __restrict__ x1, const float* __restrict__ shift,
    const float* __restrict__ tmk, const float* __restrict__ tmv,
    const float* __restrict__ tmr,
    unsigned short* __restrict__ xk, unsigned short* __restrict__ xv,
    unsigned short* __restrict__ xr) {
  const int row = blockIdx.x;
  const int t = row & (T_ - 1);
  const int bi = row >> 11;
  const int c0 = threadIdx.x * 8;
  const size_t o = (size_t)row * C_ + c0;
  unsigned short cur8[8];
  *(uint4*)cur8 = *(const uint4*)(x1 + o);
  float pv[8];
  if (t == 0) {
    const float* sp = shift + (size_t)bi * C_ + c0;
#pragma unroll
    for (int j = 0; j < 8; ++j) pv[j] = sp[j];
  } else {
    unsigned short p8[8];
    *(uint4*)p8 = *(const uint4*)(x1 + o - C_);
#pragma unroll
    for (int j = 0; j < 8; ++j) pv[j] = b2f(p8[j]);
  }
  unsigned short ok[8], ov[8], orr[8];
#pragma unroll
  for (int j = 0; j < 8; ++j) {
    const float a = b2f(cur8[j]), p = pv[j];
    const float mk = tmk[c0 + j], mv = tmv[c0 + j], mr = tmr[c0 + j];
    ok[j]  = f2bf(a * mk + p * (1.f - mk));
    ov[j]  = f2bf(a * mv + p * (1.f - mv));
    orr[j] = f2bf(a * mr + p * (1.f - mr));
  }
  *(uint4*)(xk + o) = *(uint4*)ok;
  *(uint4*)(xv + o) = *(uint4*)ov;
  *(uint4*)(xr + o) = *(uint4*)orr;
}

// ---------- token-shift mix (ffn: 2 outputs) ----------
__global__ __launch_bounds__(256) void k_mix2(
    const unsigned short* __restrict__ x2, const float* __restrict__ shift,
    const float* __restrict__ fmk, const float* __restrict__ fmr,
    unsigned short* __restrict__ xk2, unsigned short* __restrict__ xr2) {
  const int row = blockIdx.x;
  const int t = row & (T_ - 1);
  const int bi = row >> 11;
  const int c0 = threadIdx.x * 8;
  const size_t o = (size_t)row * C_ + c0;
  unsigned short cur8[8];
  *(uint4*)cur8 = *(const uint4*)(x2 + o);
  float pv[8];
  if (t == 0) {
    const float* sp = shift + (size_t)bi * C_ + c0;
#pragma unroll
    for (int j = 0; j < 8; ++j) pv[j] = sp[j];
  } else {
    unsigned short p8[8];
    *(uint4*)p8 = *(const uint4*)(x2 + o - C_);
#pragma unroll
    for (int j = 0; j < 8; ++j) pv[j] = b2f(p8[j]);
  }
  unsigned short ok[8], orr[8];
#pragma unroll
  for (int j = 0; j < 8; ++j) {
    const float a = b2f(cur8[j]), p = pv[j];
    const float mk = fmk[c0 + j], mr = fmr[c0 + j];
    ok[j]  = f2bf(a * mk + p * (1.f - mk));
    orr[j] = f2bf(a * mr + p * (1.f - mr));
  }
  *(uint4*)(xk2 + o) = *(uint4*)ok;
  *(uint4*)(xr2 + o) = *(uint4*)orr;
}

// ---------- WKV: single-kernel block-local chunked scan (y f32 out) ----------
__global__ __launch_bounds__(256) void k_wkv_blk(
    const float* __restrict__ kk, const float* __restrict__ vv,
    const float* __restrict__ td, const float* __restrict__ tf,
    const float* __restrict__ st, float* __restrict__ y,
    float* __restrict__ out_state) {
  __shared__ float sA[TCH][CHB], sB[TCH][CHB], sP[TCH][CHB];
  const int blk = blockIdx.x;
  const int bi = blk >> 7;
  const int tx = threadIdx.x & 15;
  const int ty = threadIdx.x >> 4;
  const int c = ((blk & 127) * CHB) + tx;
  const float w = -expf(td[c]);
  const float u = tf[c];
  const size_t base = (size_t)bi * T_ * C_ + (size_t)ty * LC2 * C_ + c;
  const float* kp = kk + base;
  const float* vp = vv + base;
  float aa = 0.f, bb = 0.f, pp = -1e38f;
#pragma unroll 8
  for (int i = 0; i < LC2; ++i) {
    const float kt = kp[(size_t)i * C_], vt = vp[(size_t)i * C_];
    const float ww2 = pp + w;
    const float p2 = fmaxf(ww2, kt);
    const float e1b = expf(ww2 - p2), e2b = expf(kt - p2);
    aa = e1b * aa + e2b * vt;
    bb = e1b * bb + e2b;
    pp = p2;
  }
  sA[ty][tx] = aa; sB[ty][tx] = bb; sP[ty][tx] = pp;
  __syncthreads();
  if (ty == 0) {
    const float* s0 = st + (size_t)bi * 3 * C_;
    float ca = s0[c], cb = s0[C_ + c], cp = s0[2 * C_ + c];
    const float wL = w * (float)LC2;
#pragma unroll
    for (int j = 0; j < TCH; ++j) {
      const float a2 = sA[j][tx], b2 = sB[j][tx], p2 = sP[j][tx];
      sA[j][tx] = ca; sB[j][tx] = cb; sP[j][tx] = cp;   // exclusive start
      const float pd = cp + wL;
      const float pm = fmaxf(pd, p2);
      const float e1 = expf(pd - pm), e2 = expf(p2 - pm);
      ca = e1 * ca + e2 * a2;
      cb = e1 * cb + e2 * b2;
      cp = pm;
    }
  }
  __syncthreads();
  aa = sA[ty][tx]; bb = sB[ty][tx]; pp = sP[ty][tx];
  float* yp = y + base;
#pragma unroll 4
  for (int i = 0; i < LC2; ++i) {
    const float kt = kp[(size_t)i * C_], vt = vp[(size_t)i * C_];
    const float ww = u + kt;
    const float p = fmaxf(pp, ww);
    const float e1 = expf(pp - p), e2 = expf(ww - p);
    yp[(size_t)i * C_] = (e1 * aa + e2 * vt) / (e1 * bb + e2);
    const float ww2 = pp + w;
    const float p2 = fmaxf(ww2, kt);
    const float e1b = expf(ww2 - p2), e2b = expf(kt - p2);
    aa = e1b * aa + e2b * vt;
    bb = e1b * bb + e2b;
    pp = p2;
  }
  if (ty == TCH - 1) {
    float* ob = out_state + (size_t)bi * 3 * C_;
    ob[c] = aa; ob[C_ + c] = bb; ob[2 * C_ + c] = pp;
  }
}

// ---------- sigmoid(r)*y -> bf16 (r bf16, y f32) ----------
__global__ __launch_bounds__(256) void k_sry(
    const unsigned short* __restrict__ r, const float* __restrict__ y,
    unsigned short* __restrict__ sry) {
  const int nv = M_ * C_ / 8;
  for (int i = blockIdx.x * 256 + threadIdx.x; i < nv; i += gridDim.x * 256) {
    unsigned short r8[8];
    *(uint4*)r8 = ((const uint4*)r)[i];
    float4 ya = ((const float4*)y)[2 * i], yb = ((const float4*)y)[2 * i + 1];
    const float yv[8] = {ya.x, ya.y, ya.z, ya.w, yb.x, yb.y, yb.z, yb.w};
    unsigned short o8[8];
#pragma unroll
    for (int j = 0; j < 8; ++j) {
      const float s = 1.f / (1.f + expf(-b2f(r8[j])));
      o8[j] = f2bf(s * yv[j]);
    }
    ((uint4*)sry)[i] = *(uint4*)o8;
  }
}

// ---------- bf16 MFMA GEMM: 128x256 tile, BK=64, 8 waves, single-barrier tiles --
// TRIPLE-buffered 144KiB LDS, prefetch distance 2, counted vmcnt(6).
// SWZ=1: 2D-chunked XCD swizzle — each XCD owns an (m_r x n_r) tile region with
// m_r = 2*n_r (balances A/B panel fetch); cuts cross-XCD B re-streams ~4x.
// EPI 0: f32; 1: bf16(relu^2); 2: f32(aux1+acc); 3: f32(aux1+sig(acc)*aux2); 4: bf16
template <int EPI, int SWZ>
__global__ __launch_bounds__(512, 1) void k_gemm8(
    const unsigned short* __restrict__ A, const unsigned short* __restrict__ BT,
    int K, int Nn, void* __restrict__ out,
    const float* __restrict__ aux1, const float* __restrict__ aux2) {
  // 3 buffers x (A 8192 + B 16384) ushorts = 73728 ushorts = 144 KiB
  __shared__ unsigned short lds[73728];
  const int tid = threadIdx.x;
  const int lane = tid & 63;
  const int wid = tid >> 6;
  int mBase, nBase;
  if (SWZ) {
    const int gx = gridDim.x, gy = gridDim.y;
    const int wg = blockIdx.y * gx + blockIdx.x;
    const int per = (gx * gy) >> 3;             // tiles per XCD
    const int p = 31 - __clz(per);
    const int nr = 1 << ((p - 1) >> 1);         // n_r = sqrt(per/2)
    const int mr = per / nr;
    if ((gx % nr) == 0 && (gy % mr) == 0) {
      const int gxr = gx / nr;                  // region columns
      const int xcd = wg & 7, idx = wg >> 3;
      const int rr = xcd / gxr, rc = xcd % gxr;
      mBase = (rr * mr + idx / nr) * 128;
      nBase = (rc * nr + idx % nr) * 256;
    } else {
      int w2 = (wg & 7) * per + (wg >> 3);      // 1D fallback
      mBase = (w2 / gx) * 128;
      nBase = (w2 % gx) * 256;
    }
  } else {
    mBase = blockIdx.y * 128;
    nBase = blockIdx.x * 256;
  }
  const int wr = (wid >> 2) * 64;       // wave M offset (2 waves in M)
  const int wc = (wid & 3) * 64;        // wave N offset (4 waves in N)
  const int r16 = lane & 15, kq = lane >> 4;
  const int lrow = lane >> 3;           // staging row within 8-row wave chunk
  const int lslot = (lane & 7) ^ lrow;  // inverse-swizzled SOURCE slot
  const int xsw = r16 & 7;              // read-side xor
  f32x4 acc[4][4] = {};

  const unsigned short* gA0 = A  + (size_t)(mBase + 0   + wid * 8 + lrow) * K + lslot * 8;
  const unsigned short* gA1 = A  + (size_t)(mBase + 64  + wid * 8 + lrow) * K + lslot * 8;
  const unsigned short* gB0 = BT + (size_t)(nBase + 0   + wid * 8 + lrow) * K + lslot * 8;
  const unsigned short* gB1 = BT + (size_t)(nBase + 64  + wid * 8 + lrow) * K + lslot * 8;
  const unsigned short* gB2 = BT + (size_t)(nBase + 128 + wid * 8 + lrow) * K + lslot * 8;
  const unsigned short* gB3 = BT + (size_t)(nBase + 192 + wid * 8 + lrow) * K + lslot * 8;
  const int wof = wid * 512;
  // lane-relative LDS read offsets (ushort index), frag (m|n, s)
  int aoff[4][2], boff[4][2];
#pragma unroll
  for (int m = 0; m < 4; ++m)
#pragma unroll
    for (int s = 0; s < 2; ++s)
      aoff[m][s] = (wr + m * 16 + r16) * 64 + (((s * 4 + kq) ^ xsw) * 8);
#pragma unroll
  for (int n = 0; n < 4; ++n)
#pragma unroll
    for (int s = 0; s < 2; ++s)
      boff[n][s] = 8192 + (wc + n * 16 + r16) * 64 + (((s * 4 + kq) ^ xsw) * 8);

  const int nt = K >> 6;
  // prologue: stage tile 0 -> buf0, tile 1 -> buf1 (12 loads/wave in flight)
  gload16(gA0, &lds[0 + wof]);
  gload16(gA1, &lds[4096 + wof]);
  gload16(gB0, &lds[8192 + wof]);
  gload16(gB1, &lds[12288 + wof]);
  gload16(gB2, &lds[16384 + wof]);
  gload16(gB3, &lds[20480 + wof]);
  gload16(gA0 + 64, &lds[24576 + 0 + wof]);
  gload16(gA1 + 64, &lds[24576 + 4096 + wof]);
  gload16(gB0 + 64, &lds[24576 + 8192 + wof]);
  gload16(gB1 + 64, &lds[24576 + 12288 + wof]);
  gload16(gB2 + 64, &lds[24576 + 16384 + wof]);
  gload16(gB3 + 64, &lds[24576 + 20480 + wof]);
  asm volatile("s_waitcnt vmcnt(6)" ::: "memory");   // tile 0 ready, tile 1 flying
  asm volatile("s_barrier" ::: "memory");

  int cb = 0;                           // current buffer = t % 3
  for (int t = 0; t < nt; ++t) {
    const int nb = (cb >= 1) ? cb - 1 : 2;           // (t+2) % 3
    const int ca = cb * 24576;
    const int nba = nb * 24576;
    const int kb2 = (t + 2) << 6;
    const bool pf = (t + 2) < nt;
    // issue prefetch of tile t+2 first (longest time in flight)
    if (pf) {
      gload16(gA0 + kb2, &lds[nba + 0 + wof]);
      gload16(gA1 + kb2, &lds[nba + 4096 + wof]);
      gload16(gB0 + kb2, &lds[nba + 8192 + wof]);
      gload16(gB1 + kb2, &lds[nba + 12288 + wof]);
      gload16(gB2 + kb2, &lds[nba + 16384 + wof]);
      gload16(gB3 + kb2, &lds[nba + 20480 + wof]);
    }
    // read all 16 fragments once
    bf16x8 af[4][2], bq[4][2];
#pragma unroll
    for (int m = 0; m < 4; ++m)
#pragma unroll
      for (int s = 0; s < 2; ++s)
        af[m][s] = *(const bf16x8*)&lds[ca + aoff[m][s]];
#pragma unroll
    for (int n = 0; n < 4; ++n)
#pragma unroll
      for (int s = 0; s < 2; ++s)
        bq[n][s] = *(const bf16x8*)&lds[ca + boff[n][s]];
    __builtin_amdgcn_s_setprio(1);
#pragma unroll
    for (int m = 0; m < 4; ++m)
#pragma unroll
      for (int n = 0; n < 4; ++n)
#pragma unroll
        for (int s = 0; s < 2; ++s)
          acc[m][n] = __builtin_amdgcn_mfma_f32_16x16x32_bf16(
              af[m][s], bq[n][s], acc[m][n], 0, 0, 0);
    __builtin_amdgcn_s_setprio(0);
    if (pf) {
      asm volatile("s_waitcnt vmcnt(6)" ::: "memory");   // t+1 ready, t+2 flying
    } else if (t + 1 < nt) {
      asm volatile("s_waitcnt vmcnt(0)" ::: "memory");   // final drain
    }
    asm volatile("s_barrier" ::: "memory");
    cb = (cb == 2) ? 0 : cb + 1;
  }

  const int c0 = kq * 4;
#pragma unroll
  for (int m = 0; m < 4; ++m) {
#pragma unroll
    for (int n = 0; n < 4; ++n) {
      const int col = nBase + wc + n * 16 + r16;
#pragma unroll
      for (int e = 0; e < 4; ++e) {
        const int rowg = mBase + wr + m * 16 + c0 + e;
        const size_t idx = (size_t)rowg * Nn + col;
        const float va = acc[m][n][e];
        if (EPI == 0) {
          ((float*)out)[idx] = va;
        } else if (EPI == 1) {
          const float t = va > 0.f ? va : 0.f;
          ((unsigned short*)out)[idx] = f2bf(t * t);
        } else if (EPI == 2) {
          ((float*)out)[idx] = aux1[idx] + va;
        } else if (EPI == 3) {
          const float s = 1.f / (1.f + expf(-va));
          ((float*)out)[idx] = aux1[idx] + s * aux2[idx];
        } else {
          ((unsigned short*)out)[idx] = f2bf(va);
        }
      }
    }
  }
}

extern "C" void kernel_launch(void* const* d_in, const int* in_sizes, int n_in,
                              void* d_out, int out_size, void* d_ws, size_t ws_size,
                              hipStream_t stream) {
  const float* x          = (const float*)d_in[0];
  const float* att_shift  = (const float*)d_in[1];
  const float* wkv_state  = (const float*)d_in[2];
  const float* ffn_shift  = (const float*)d_in[3];
  const float* ln1_g = (const float*)d_in[4];
  const float* ln1_b = (const float*)d_in[5];
  const float* ln2_g = (const float*)d_in[6];
  const float* ln2_b = (const float*)d_in[7];
  const float* tmk = (const float*)d_in[8];
  const float* tmv = (const float*)d_in[9];
  const float* tmr = (const float*)d_in[10];
  const float* time_decay = (const float*)d_in[11];
  const float* time_first = (const float*)d_in[12];
  const float* Wk = (const float*)d_in[13];
  const float* Wv = (const float*)d_in[14];
  const float* Wr = (const float*)d_in[15];
  const float* Wo = (const float*)d_in[16];
  const float* fmk = (const float*)d_in[17];
  const float* fmr = (const float*)d_in[18];
  const float* Fk = (const float*)d_in[19];
  const float* Fr = (const float*)d_in[20];
  const float* Fv = (const float*)d_in[21];

  // ---- 176 MiB workspace, strictly sequential reuse, zero in-flight overlap ----
  const size_t MB = 1ull << 20;
  char* ws = (char*)d_ws;
  if (ws_size < 176 * MB) return;

  unsigned short* Wslot = (unsigned short*)(ws);             //   0.. 32 weight slot
  float*          kBuf  = (float*)(ws + 32 * MB);            //  32.. 64 k f32
  float*          vBuf  = (float*)(ws + 64 * MB);            //  64.. 96 v f32
  float*          yBuf  = (float*)(ws + 96 * MB);            //  96..128 y f32 -> x_att f32
  unsigned short* h1    = (unsigned short*)(ws + 128 * MB);  // 128..144 x1 -> r -> x2
  unsigned short* h2    = (unsigned short*)(ws + 144 * MB);  // 144..160 xk -> sry -> xk2
  unsigned short* h3    = (unsigned short*)(ws + 160 * MB);  // 160..176 xv -> xr2
  unsigned short* xrT   = (unsigned short*)kBuf;             // xr bf16, before k exists
  unsigned short* kf    = (unsigned short*)kBuf;             // 64 MiB: 32..96 (k,v dead)
  float*          kv    = (float*)h1;                        // 32 MiB: 128..160 (x2,xk2 dead)

  // ---- f32 outputs, concatenated in reference return order ----
  float* outb    = (float*)d_out;
  float* x1_last = outb + (size_t)M_ * C_;        // [B,C]
  float* wkv_out = x1_last + (size_t)B_ * C_;     // [B,3,C]
  float* x2_last = wkv_out + (size_t)B_ * 3 * C_; // [B,C]

  const dim3 gCC(C_ / 32, C_ / 32);
  const dim3 gC8(C_ / 256, M_ / 128);      // 8 x 32 = 256 WGs
  const dim3 gF8(F_ / 256, M_ / 128);      // 32 x 32 = 1024 WGs

  // ---- attention path ----
  k_layernorm<<<M_, 256, 0, stream>>>(x, ln1_g, ln1_b, h1, x1_last);           // x1 -> h1
  k_mix3<<<M_, 256, 0, stream>>>(h1, att_shift, tmk, tmv, tmr, h2, h3, xrT);   // xk,xv,xr
  k_transpose_cast<<<gCC, 256, 0, stream>>>(Wr, Wslot, C_, C_);
  k_gemm8<4,1><<<gC8, 512, 0, stream>>>(xrT, Wslot, C_, C_, h1, nullptr, nullptr); // r bf16 -> h1
  k_transpose_cast<<<gCC, 256, 0, stream>>>(Wk, Wslot, C_, C_);
  k_gemm8<0,1><<<gC8, 512, 0, stream>>>(h2, Wslot, C_, C_, kBuf, nullptr, nullptr); // k f32 (over xr, dead)
  k_transpose_cast<<<gCC, 256, 0, stream>>>(Wv, Wslot, C_, C_);
  k_gemm8<0,1><<<gC8, 512, 0, stream>>>(h3, Wslot, C_, C_, vBuf, nullptr, nullptr); // v f32
  // WKV: single kernel, block-local scan (no cross-kernel scratch)
  k_wkv_blk<<<dim3(BC_ / CHB), 256, 0, stream>>>(kBuf, vBuf, time_decay, time_first,
                                                 wkv_state, yBuf, wkv_out);
  k_sry<<<1024, 256, 0, stream>>>(h1, yBuf, h2);                                // sry -> h2 (xk dead)
  k_transpose_cast<<<gCC, 256, 0, stream>>>(Wo, Wslot, C_, C_);
  k_gemm8<2,1><<<gC8, 512, 0, stream>>>(h2, Wslot, C_, C_, yBuf, x, nullptr);   // x_att f32 (over y, dead)

  // ---- ffn path ----
  k_layernorm<<<M_, 256, 0, stream>>>(yBuf, ln2_g, ln2_b, h1, x2_last);         // x2 -> h1 (r dead)
  k_mix2<<<M_, 256, 0, stream>>>(h1, ffn_shift, fmk, fmr, h2, h3);              // xk2,xr2 (sry,xv dead)
  k_transpose_cast<<<dim3(F_ / 32, C_ / 32), 256, 0, stream>>>(Fk, Wslot, C_, F_);
  k_gemm8<1,1><<<gF8, 512, 0, stream>>>(h2, Wslot, C_, F_, kf, nullptr, nullptr); // kf bf16 (k,v dead)
  k_transpose_cast<<<dim3(C_ / 32, F_ / 32), 256, 0, stream>>>(Fv, Wslot, F_, C_);
  k_gemm8<0,1><<<gC8, 512, 0, stream>>>(kf, Wslot, F_, C_, kv, nullptr, nullptr); // kv f32 (x2,xk2 dead)
  k_transpose_cast<<<gCC, 256, 0, stream>>>(Fr, Wslot, C_, C_);
  k_gemm8<3,1><<<gC8, 512, 0, stream>>>(h3, Wslot, C_, C_, d_out, yBuf, kv);    // final f32
}

// Round 15
// 644.164 us; speedup vs baseline: 1.3443x; 1.0540x over previous
//
#include <hip/hip_runtime.h>
#include <stdint.h>

#define B_ 2
#define T_ 2048
#define C_ 2048
#define F_ 8192
#define M_ 4096   // B_*T_
#define BC_ 4096  // B_*C_
#define CHB 16    // channels per WKV block
#define TCH 16    // time chunks per WKV block
#define LC2 128   // T_/TCH

typedef __attribute__((ext_vector_type(8))) __bf16 bf16x8;
typedef __attribute__((ext_vector_type(4))) float f32x4;

__device__ __forceinline__ unsigned short f2bf(float f) {
  union { float f; unsigned u; } v; v.f = f;
  unsigned r = v.u + 0x7fffu + ((v.u >> 16) & 1u);
  return (unsigned short)(r >> 16);
}
__device__ __forceinline__ float b2f(unsigned short h) {
  union { unsigned u; float f; } v; v.u = ((unsigned)h) << 16; return v.f;
}

__device__ __forceinline__ void gload16(const void* g, void* l) {
  __builtin_amdgcn_global_load_lds((__attribute__((address_space(1))) void*)g,
                                   (__attribute__((address_space(3))) void*)l,
                                   16, 0, 0);
}

// ---------- transpose + f32->bf16: WT[n][k] = W[k][n] ----------
__global__ __launch_bounds__(256) void k_transpose_cast(
    const float* __restrict__ W, unsigned short* __restrict__ WT, int K, int N) {
  __shared__ unsigned short tile[32][33];
  const int n0 = blockIdx.x * 32, k0 = blockIdx.y * 32;
  const int tx = threadIdx.x & 31, ty = threadIdx.x >> 5;
#pragma unroll
  for (int i = 0; i < 4; ++i)
    tile[ty + 8 * i][tx] = f2bf(W[(size_t)(k0 + ty + 8 * i) * N + n0 + tx]);
  __syncthreads();
#pragma unroll
  for (int i = 0; i < 4; ++i)
    WT[(size_t)(n0 + ty + 8 * i) * K + k0 + tx] = tile[tx][ty + 8 * i];
}

// ---------- LayerNorm over C=2048 (f32 in, bf16 out + f32 last-row out) ----------
__global__ __launch_bounds__(256) void k_layernorm(
    const float* __restrict__ x, const float* __restrict__ g,
    const float* __restrict__ beta, unsigned short* __restrict__ y,
    float* __restrict__ last_out) {
  const int row = blockIdx.x;
  const int t = row & (T_ - 1);
  const int bi = row >> 11;
  const float* xr = x + (size_t)row * C_;
  const int base = threadIdx.x * 8;
  float lv[8];
  {
    float4 a = *(const float4*)(xr + base);
    float4 b = *(const float4*)(xr + base + 4);
    lv[0]=a.x; lv[1]=a.y; lv[2]=a.z; lv[3]=a.w; lv[4]=b.x; lv[5]=b.y; lv[6]=b.z; lv[7]=b.w;
  }
  float s = 0.f, q = 0.f;
#pragma unroll
  for (int j = 0; j < 8; ++j) { s += lv[j]; q += lv[j] * lv[j]; }
#pragma unroll
  for (int o = 32; o > 0; o >>= 1) { s += __shfl_down(s, o); q += __shfl_down(q, o); }
  __shared__ float rs[4], rq[4];
  if ((threadIdx.x & 63) == 0) { rs[threadIdx.x >> 6] = s; rq[threadIdx.x >> 6] = q; }
  __syncthreads();
  s = rs[0] + rs[1] + rs[2] + rs[3];
  q = rq[0] + rq[1] + rq[2] + rq[3];
  const float mean = s * (1.f / C_);
  const float var = q * (1.f / C_) - mean * mean;
  const float inv = 1.f / sqrtf(var + 1e-5f);
  float ov[8];
  unsigned short o8[8];
#pragma unroll
  for (int j = 0; j < 8; ++j) {
    ov[j] = (lv[j] - mean) * inv * g[base + j] + beta[base + j];
    o8[j] = f2bf(ov[j]);
  }
  *(uint4*)(y + (size_t)row * C_ + base) = *(uint4*)o8;
  if (last_out != nullptr && t == T_ - 1) {
    float* lp = last_out + (size_t)bi * C_ + base;
    *(float4*)lp = make_float4(ov[0], ov[1], ov[2], ov[3]);
    *(float4*)(lp + 4) = make_float4(ov[4], ov[5], ov[6], ov[7]);
  }
}

// ---------- token-shift mix (attention: 3 outputs), bf16 in/out ----------
__global__ __launch_bounds__(256) void k_mix3(
    const unsigned short* __restrict__ x1, const float* __restrict__ shift,
    const float* __restrict__ tmk, const float* __restrict__ tmv,
    const float* __restrict__ tmr,
    unsigned short* __restrict__ xk, unsigned short* __restrict__ xv,
    unsigned short* __restrict__ xr) {
  const int row = blockIdx.x;
  const int t = row & (T_ - 1);
  const int bi = row >> 11;
  const int c0 = threadIdx.x * 8;
  const size_t o = (size_t)row * C_ + c0;
  unsigned short cur8[8];
  *(uint4*)cur8 = *(const uint4*)(x1 + o);
  float pv[8];
  if (t == 0) {
    const float* sp = shift + (size_t)bi * C_ + c0;
#pragma unroll
    for (int j = 0; j < 8; ++j) pv[j] = sp[j];
  } else {
    unsigned short p8[8];
    *(uint4*)p8 = *(const uint4*)(x1 + o - C_);
#pragma unroll
    for (int j = 0; j < 8; ++j) pv[j] = b2f(p8[j]);
  }
  unsigned short ok[8], ov[8], orr[8];
#pragma unroll
  for (int j = 0; j < 8; ++j) {
    const float a = b2f(cur8[j]), p = pv[j];
    const float mk = tmk[c0 + j], mv = tmv[c0 + j], mr = tmr[c0 + j];
    ok[j]  = f2bf(a * mk + p * (1.f - mk));
    ov[j]  = f2bf(a * mv + p * (1.f - mv));
    orr[j] = f2bf(a * mr + p * (1.f - mr));
  }
  *(uint4*)(xk + o) = *(uint4*)ok;
  *(uint4*)(xv + o) = *(uint4*)ov;
  *(uint4*)(xr + o) = *(uint4*)orr;
}

// ---------- token-shift mix (ffn: 2 outputs) ----------
__global__ __launch_bounds__(256) void k_mix2(
    const unsigned short* __restrict__ x2, const float* __restrict__ shift,
    const float* __restrict__ fmk, const float* __restrict__ fmr,
    unsigned short* __restrict__ xk2, unsigned short* __restrict__ xr2) {
  const int row = blockIdx.x;
  const int t = row & (T_ - 1);
  const int bi = row >> 11;
  const int c0 = threadIdx.x * 8;
  const size_t o = (size_t)row * C_ + c0;
  unsigned short cur8[8];
  *(uint4*)cur8 = *(const uint4*)(x2 + o);
  float pv[8];
  if (t == 0) {
    const float* sp = shift + (size_t)bi * C_ + c0;
#pragma unroll
    for (int j = 0; j < 8; ++j) pv[j] = sp[j];
  } else {
    unsigned short p8[8];
    *(uint4*)p8 = *(const uint4*)(x2 + o - C_);
#pragma unroll
    for (int j = 0; j < 8; ++j) pv[j] = b2f(p8[j]);
  }
  unsigned short ok[8], orr[8];
#pragma unroll
  for (int j = 0; j < 8; ++j) {
    const float a = b2f(cur8[j]), p = pv[j];
    const float mk = fmk[c0 + j], mr = fmr[c0 + j];
    ok[j]  = f2bf(a * mk + p * (1.f - mk));
    orr[j] = f2bf(a * mr + p * (1.f - mr));
  }
  *(uint4*)(xk2 + o) = *(uint4*)ok;
  *(uint4*)(xr2 + o) = *(uint4*)orr;
}

// ---------- WKV: single-kernel block-local chunked scan (y f32 out) ----------
__global__ __launch_bounds__(256) void k_wkv_blk(
    const float* __restrict__ kk, const float* __restrict__ vv,
    const float* __restrict__ td, const float* __restrict__ tf,
    const float* __restrict__ st, float* __restrict__ y,
    float* __restrict__ out_state) {
  __shared__ float sA[TCH][CHB], sB[TCH][CHB], sP[TCH][CHB];
  const int blk = blockIdx.x;
  const int bi = blk >> 7;
  const int tx = threadIdx.x & 15;
  const int ty = threadIdx.x >> 4;
  const int c = ((blk & 127) * CHB) + tx;
  const float w = -expf(td[c]);
  const float u = tf[c];
  const size_t base = (size_t)bi * T_ * C_ + (size_t)ty * LC2 * C_ + c;
  const float* kp = kk + base;
  const float* vp = vv + base;
  float aa = 0.f, bb = 0.f, pp = -1e38f;
#pragma unroll 8
  for (int i = 0; i < LC2; ++i) {
    const float kt = kp[(size_t)i * C_], vt = vp[(size_t)i * C_];
    const float ww2 = pp + w;
    const float p2 = fmaxf(ww2, kt);
    const float e1b = expf(ww2 - p2), e2b = expf(kt - p2);
    aa = e1b * aa + e2b * vt;
    bb = e1b * bb + e2b;
    pp = p2;
  }
  sA[ty][tx] = aa; sB[ty][tx] = bb; sP[ty][tx] = pp;
  __syncthreads();
  if (ty == 0) {
    const float* s0 = st + (size_t)bi * 3 * C_;
    float ca = s0[c], cb = s0[C_ + c], cp = s0[2 * C_ + c];
    const float wL = w * (float)LC2;
#pragma unroll
    for (int j = 0; j < TCH; ++j) {
      const float a2 = sA[j][tx], b2 = sB[j][tx], p2 = sP[j][tx];
      sA[j][tx] = ca; sB[j][tx] = cb; sP[j][tx] = cp;   // exclusive start
      const float pd = cp + wL;
      const float pm = fmaxf(pd, p2);
      const float e1 = expf(pd - pm), e2 = expf(p2 - pm);
      ca = e1 * ca + e2 * a2;
      cb = e1 * cb + e2 * b2;
      cp = pm;
    }
  }
  __syncthreads();
  aa = sA[ty][tx]; bb = sB[ty][tx]; pp = sP[ty][tx];
  float* yp = y + base;
#pragma unroll 4
  for (int i = 0; i < LC2; ++i) {
    const float kt = kp[(size_t)i * C_], vt = vp[(size_t)i * C_];
    const float ww = u + kt;
    const float p = fmaxf(pp, ww);
    const float e1 = expf(pp - p), e2 = expf(ww - p);
    yp[(size_t)i * C_] = (e1 * aa + e2 * vt) / (e1 * bb + e2);
    const float ww2 = pp + w;
    const float p2 = fmaxf(ww2, kt);
    const float e1b = expf(ww2 - p2), e2b = expf(kt - p2);
    aa = e1b * aa + e2b * vt;
    bb = e1b * bb + e2b;
    pp = p2;
  }
  if (ty == TCH - 1) {
    float* ob = out_state + (size_t)bi * 3 * C_;
    ob[c] = aa; ob[C_ + c] = bb; ob[2 * C_ + c] = pp;
  }
}

// ---------- sigmoid(r)*y -> bf16 (r bf16, y f32) ----------
__global__ __launch_bounds__(256) void k_sry(
    const unsigned short* __restrict__ r, const float* __restrict__ y,
    unsigned short* __restrict__ sry) {
  const int nv = M_ * C_ / 8;
  for (int i = blockIdx.x * 256 + threadIdx.x; i < nv; i += gridDim.x * 256) {
    unsigned short r8[8];
    *(uint4*)r8 = ((const uint4*)r)[i];
    float4 ya = ((const float4*)y)[2 * i], yb = ((const float4*)y)[2 * i + 1];
    const float yv[8] = {ya.x, ya.y, ya.z, ya.w, yb.x, yb.y, yb.z, yb.w};
    unsigned short o8[8];
#pragma unroll
    for (int j = 0; j < 8; ++j) {
      const float s = 1.f / (1.f + expf(-b2f(r8[j])));
      o8[j] = f2bf(s * yv[j]);
    }
    ((uint4*)sry)[i] = *(uint4*)o8;
  }
}

// ---------- bf16 MFMA GEMM: 128x256 tile, BK=64, 8 waves, single-barrier tiles --
// TRIPLE-buffered 144KiB LDS, prefetch distance 2, counted vmcnt(6).
// SWZ=1: 2D-chunked XCD swizzle (m_r = 2*n_r).
// EPI 0: f32; 1: bf16(relu^2); 2: f32(aux1+acc); 3: f32(aux1+sig(acc)*aux2); 4: bf16
template <int EPI, int SWZ>
__global__ __launch_bounds__(512, 1) void k_gemm8(
    const unsigned short* __restrict__ A, const unsigned short* __restrict__ BT,
    int K, int Nn, void* __restrict__ out,
    const float* __restrict__ aux1, const float* __restrict__ aux2) {
  __shared__ unsigned short lds[73728];
  const int tid = threadIdx.x;
  const int lane = tid & 63;
  const int wid = tid >> 6;
  int mBase, nBase;
  if (SWZ) {
    const int gx = gridDim.x, gy = gridDim.y;
    const int wg = blockIdx.y * gx + blockIdx.x;
    const int per = (gx * gy) >> 3;
    const int p = 31 - __clz(per);
    const int nr = 1 << ((p - 1) >> 1);
    const int mr = per / nr;
    if ((gx % nr) == 0 && (gy % mr) == 0) {
      const int gxr = gx / nr;
      const int xcd = wg & 7, idx = wg >> 3;
      const int rr = xcd / gxr, rc = xcd % gxr;
      mBase = (rr * mr + idx / nr) * 128;
      nBase = (rc * nr + idx % nr) * 256;
    } else {
      int w2 = (wg & 7) * per + (wg >> 3);
      mBase = (w2 / gx) * 128;
      nBase = (w2 % gx) * 256;
    }
  } else {
    mBase = blockIdx.y * 128;
    nBase = blockIdx.x * 256;
  }
  const int wr = (wid >> 2) * 64;
  const int wc = (wid & 3) * 64;
  const int r16 = lane & 15, kq = lane >> 4;
  const int lrow = lane >> 3;
  const int lslot = (lane & 7) ^ lrow;
  const int xsw = r16 & 7;
  f32x4 acc[4][4] = {};

  const unsigned short* gA0 = A  + (size_t)(mBase + 0   + wid * 8 + lrow) * K + lslot * 8;
  const unsigned short* gA1 = A  + (size_t)(mBase + 64  + wid * 8 + lrow) * K + lslot * 8;
  const unsigned short* gB0 = BT + (size_t)(nBase + 0   + wid * 8 + lrow) * K + lslot * 8;
  const unsigned short* gB1 = BT + (size_t)(nBase + 64  + wid * 8 + lrow) * K + lslot * 8;
  const unsigned short* gB2 = BT + (size_t)(nBase + 128 + wid * 8 + lrow) * K + lslot * 8;
  const unsigned short* gB3 = BT + (size_t)(nBase + 192 + wid * 8 + lrow) * K + lslot * 8;
  const int wof = wid * 512;
  int aoff[4][2], boff[4][2];
#pragma unroll
  for (int m = 0; m < 4; ++m)
#pragma unroll
    for (int s = 0; s < 2; ++s)
      aoff[m][s] = (wr + m * 16 + r16) * 64 + (((s * 4 + kq) ^ xsw) * 8);
#pragma unroll
  for (int n = 0; n < 4; ++n)
#pragma unroll
    for (int s = 0; s < 2; ++s)
      boff[n][s] = 8192 + (wc + n * 16 + r16) * 64 + (((s * 4 + kq) ^ xsw) * 8);

  const int nt = K >> 6;
  gload16(gA0, &lds[0 + wof]);
  gload16(gA1, &lds[4096 + wof]);
  gload16(gB0, &lds[8192 + wof]);
  gload16(gB1, &lds[12288 + wof]);
  gload16(gB2, &lds[16384 + wof]);
  gload16(gB3, &lds[20480 + wof]);
  gload16(gA0 + 64, &lds[24576 + 0 + wof]);
  gload16(gA1 + 64, &lds[24576 + 4096 + wof]);
  gload16(gB0 + 64, &lds[24576 + 8192 + wof]);
  gload16(gB1 + 64, &lds[24576 + 12288 + wof]);
  gload16(gB2 + 64, &lds[24576 + 16384 + wof]);
  gload16(gB3 + 64, &lds[24576 + 20480 + wof]);
  asm volatile("s_waitcnt vmcnt(6)" ::: "memory");
  asm volatile("s_barrier" ::: "memory");

  int cb = 0;
  for (int t = 0; t < nt; ++t) {
    const int nb = (cb >= 1) ? cb - 1 : 2;
    const int ca = cb * 24576;
    const int nba = nb * 24576;
    const int kb2 = (t + 2) << 6;
    const bool pf = (t + 2) < nt;
    if (pf) {
      gload16(gA0 + kb2, &lds[nba + 0 + wof]);
      gload16(gA1 + kb2, &lds[nba + 4096 + wof]);
      gload16(gB0 + kb2, &lds[nba + 8192 + wof]);
      gload16(gB1 + kb2, &lds[nba + 12288 + wof]);
      gload16(gB2 + kb2, &lds[nba + 16384 + wof]);
      gload16(gB3 + kb2, &lds[nba + 20480 + wof]);
    }
    bf16x8 af[4][2], bq[4][2];
#pragma unroll
    for (int m = 0; m < 4; ++m)
#pragma unroll
      for (int s = 0; s < 2; ++s)
        af[m][s] = *(const bf16x8*)&lds[ca + aoff[m][s]];
#pragma unroll
    for (int n = 0; n < 4; ++n)
#pragma unroll
      for (int s = 0; s < 2; ++s)
        bq[n][s] = *(const bf16x8*)&lds[ca + boff[n][s]];
    __builtin_amdgcn_s_setprio(1);
#pragma unroll
    for (int m = 0; m < 4; ++m)
#pragma unroll
      for (int n = 0; n < 4; ++n)
#pragma unroll
        for (int s = 0; s < 2; ++s)
          acc[m][n] = __builtin_amdgcn_mfma_f32_16x16x32_bf16(
              af[m][s], bq[n][s], acc[m][n], 0, 0, 0);
    __builtin_amdgcn_s_setprio(0);
    if (pf) {
      asm volatile("s_waitcnt vmcnt(6)" ::: "memory");
    } else if (t + 1 < nt) {
      asm volatile("s_waitcnt vmcnt(0)" ::: "memory");
    }
    asm volatile("s_barrier" ::: "memory");
    cb = (cb == 2) ? 0 : cb + 1;
  }

  const int c0 = kq * 4;
#pragma unroll
  for (int m = 0; m < 4; ++m) {
#pragma unroll
    for (int n = 0; n < 4; ++n) {
      const int col = nBase + wc + n * 16 + r16;
#pragma unroll
      for (int e = 0; e < 4; ++e) {
        const int rowg = mBase + wr + m * 16 + c0 + e;
        const size_t idx = (size_t)rowg * Nn + col;
        const float va = acc[m][n][e];
        if (EPI == 0) {
          ((float*)out)[idx] = va;
        } else if (EPI == 1) {
          const float t = va > 0.f ? va : 0.f;
          ((unsigned short*)out)[idx] = f2bf(t * t);
        } else if (EPI == 2) {
          ((float*)out)[idx] = aux1[idx] + va;
        } else if (EPI == 3) {
          const float s = 1.f / (1.f + expf(-va));
          ((float*)out)[idx] = aux1[idx] + s * aux2[idx];
        } else {
          ((unsigned short*)out)[idx] = f2bf(va);
        }
      }
    }
  }
}

// ---------- bf16 MFMA GEMM: 256x256 tile, BK=64, 8 waves of 128x64 ----------
// MFMA:ds_read ratio 2.67 (MFMA-bound at CU level). Double-buffered 128KiB LDS,
// distance-1 prefetch (64 MFMA/wave/tile covers HBM latency). Square 2D XCD
// regions (A/B panels symmetric). Same XOR swizzle discipline as k_gemm8.
template <int EPI, int SWZ>
__global__ __launch_bounds__(512, 1) void k_gemm256(
    const unsigned short* __restrict__ A, const unsigned short* __restrict__ BT,
    int K, int Nn, void* __restrict__ out,
    const float* __restrict__ aux1, const float* __restrict__ aux2) {
  // 2 buffers x (A 16384 + B 16384) ushorts = 65536 ushorts = 128 KiB
  __shared__ unsigned short lds[65536];
  const int tid = threadIdx.x;
  const int lane = tid & 63;
  const int wid = tid >> 6;
  int mBase, nBase;
  if (SWZ) {
    const int gx = gridDim.x, gy = gridDim.y;
    const int wg = blockIdx.y * gx + blockIdx.x;
    const int per = (gx * gy) >> 3;
    const int p = 31 - __clz(per);
    const int nr = 1 << (p >> 1);               // square regions
    const int mr = per / nr;
    if ((gx % nr) == 0 && (gy % mr) == 0) {
      const int gxr = gx / nr;
      const int xcd = wg & 7, idx = wg >> 3;
      const int rr = xcd / gxr, rc = xcd % gxr;
      mBase = (rr * mr + idx / nr) * 256;
      nBase = (rc * nr + idx % nr) * 256;
    } else {
      int w2 = (wg & 7) * per + (wg >> 3);
      mBase = (w2 / gx) * 256;
      nBase = (w2 % gx) * 256;
    }
  } else {
    mBase = blockIdx.y * 256;
    nBase = blockIdx.x * 256;
  }
  const int wr = (wid >> 2) * 128;      // wave M offset (2 waves in M, 128 each)
  const int wc = (wid & 3) * 64;        // wave N offset (4 waves in N, 64 each)
  const int r16 = lane & 15, kq = lane >> 4;
  const int lrow = lane >> 3;
  const int lslot = (lane & 7) ^ lrow;
  const int xsw = r16 & 7;
  f32x4 acc[8][4] = {};

  // staging pointers: 4 A chunks (64 rows each), 4 B chunks
  const unsigned short* gA[4];
  const unsigned short* gB[4];
#pragma unroll
  for (int j = 0; j < 4; ++j) {
    gA[j] = A  + (size_t)(mBase + j * 64 + wid * 8 + lrow) * K + lslot * 8;
    gB[j] = BT + (size_t)(nBase + j * 64 + wid * 8 + lrow) * K + lslot * 8;
  }
  const int wof = wid * 512;

  const int nt = K >> 6;
  // prologue: stage tile 0 -> buf0 (8 loads/wave)
#pragma unroll
  for (int j = 0; j < 4; ++j) {
    gload16(gA[j], &lds[j * 4096 + wof]);
    gload16(gB[j], &lds[16384 + j * 4096 + wof]);
  }
  asm volatile("s_waitcnt vmcnt(0)" ::: "memory");
  asm volatile("s_barrier" ::: "memory");

  for (int t = 0; t < nt; ++t) {
    const int ca = (t & 1) * 32768;
    const int nba = ((t + 1) & 1) * 32768;
    const int kb1 = (t + 1) << 6;
    const bool pf = (t + 1) < nt;
    if (pf) {
#pragma unroll
      for (int j = 0; j < 4; ++j) {
        gload16(gA[j] + kb1, &lds[nba + j * 4096 + wof]);
        gload16(gB[j] + kb1, &lds[nba + 16384 + j * 4096 + wof]);
      }
    }
    // B fragments once (8 reads), A in two halves (8 reads each)
    bf16x8 bq[4][2];
#pragma unroll
    for (int n = 0; n < 4; ++n)
#pragma unroll
      for (int s = 0; s < 2; ++s)
        bq[n][s] = *(const bf16x8*)&lds[ca + 16384 + (wc + n * 16 + r16) * 64 +
                                        (((s * 4 + kq) ^ xsw) * 8)];
#pragma unroll
    for (int qm = 0; qm < 2; ++qm) {
      bf16x8 af[4][2];
#pragma unroll
      for (int m = 0; m < 4; ++m)
#pragma unroll
        for (int s = 0; s < 2; ++s)
          af[m][s] = *(const bf16x8*)&lds[ca + (wr + (qm * 4 + m) * 16 + r16) * 64 +
                                          (((s * 4 + kq) ^ xsw) * 8)];
      __builtin_amdgcn_s_setprio(1);
#pragma unroll
      for (int m = 0; m < 4; ++m)
#pragma unroll
        for (int n = 0; n < 4; ++n)
#pragma unroll
          for (int s = 0; s < 2; ++s)
            acc[qm * 4 + m][n] = __builtin_amdgcn_mfma_f32_16x16x32_bf16(
                af[m][s], bq[n][s], acc[qm * 4 + m][n], 0, 0, 0);
      __builtin_amdgcn_s_setprio(0);
    }
    if (pf) asm volatile("s_waitcnt vmcnt(0)" ::: "memory");
    asm volatile("s_barrier" ::: "memory");
  }

  const int c0 = kq * 4;
#pragma unroll
  for (int m = 0; m < 8; ++m) {
#pragma unroll
    for (int n = 0; n < 4; ++n) {
      const int col = nBase + wc + n * 16 + r16;
#pragma unroll
      for (int e = 0; e < 4; ++e) {
        const int rowg = mBase + wr + m * 16 + c0 + e;
        const size_t idx = (size_t)rowg * Nn + col;
        const float va = acc[m][n][e];
        if (EPI == 0) {
          ((float*)out)[idx] = va;
        } else if (EPI == 1) {
          const float t = va > 0.f ? va : 0.f;
          ((unsigned short*)out)[idx] = f2bf(t * t);
        } else if (EPI == 2) {
          ((float*)out)[idx] = aux1[idx] + va;
        } else if (EPI == 3) {
          const float s = 1.f / (1.f + expf(-va));
          ((float*)out)[idx] = aux1[idx] + s * aux2[idx];
        } else {
          ((unsigned short*)out)[idx] = f2bf(va);
        }
      }
    }
  }
}

extern "C" void kernel_launch(void* const* d_in, const int* in_sizes, int n_in,
                              void* d_out, int out_size, void* d_ws, size_t ws_size,
                              hipStream_t stream) {
  const float* x          = (const float*)d_in[0];
  const float* att_shift  = (const float*)d_in[1];
  const float* wkv_state  = (const float*)d_in[2];
  const float* ffn_shift  = (const float*)d_in[3];
  const float* ln1_g = (const float*)d_in[4];
  const float* ln1_b = (const float*)d_in[5];
  const float* ln2_g = (const float*)d_in[6];
  const float* ln2_b = (const float*)d_in[7];
  const float* tmk = (const float*)d_in[8];
  const float* tmv = (const float*)d_in[9];
  const float* tmr = (const float*)d_in[10];
  const float* time_decay = (const float*)d_in[11];
  const float* time_first = (const float*)d_in[12];
  const float* Wk = (const float*)d_in[13];
  const float* Wv = (const float*)d_in[14];
  const float* Wr = (const float*)d_in[15];
  const float* Wo = (const float*)d_in[16];
  const float* fmk = (const float*)d_in[17];
  const float* fmr = (const float*)d_in[18];
  const float* Fk = (const float*)d_in[19];
  const float* Fr = (const float*)d_in[20];
  const float* Fv = (const float*)d_in[21];

  // ---- 176 MiB workspace, strictly sequential reuse, zero in-flight overlap ----
  const size_t MB = 1ull << 20;
  char* ws = (char*)d_ws;
  if (ws_size < 176 * MB) return;

  unsigned short* Wslot = (unsigned short*)(ws);             //   0.. 32 weight slot
  float*          kBuf  = (float*)(ws + 32 * MB);            //  32.. 64 k f32
  float*          vBuf  = (float*)(ws + 64 * MB);            //  64.. 96 v f32
  float*          yBuf  = (float*)(ws + 96 * MB);            //  96..128 y f32 -> x_att f32
  unsigned short* h1    = (unsigned short*)(ws + 128 * MB);  // 128..144 x1 -> r -> x2
  unsigned short* h2    = (unsigned short*)(ws + 144 * MB);  // 144..160 xk -> sry -> xk2
  unsigned short* h3    = (unsigned short*)(ws + 160 * MB);  // 160..176 xv -> xr2
  unsigned short* xrT   = (unsigned short*)kBuf;             // xr bf16, before k exists
  unsigned short* kf    = (unsigned short*)kBuf;             // 64 MiB: 32..96 (k,v dead)
  float*          kv    = (float*)h1;                        // 32 MiB: 128..160 (x2,xk2 dead)

  // ---- f32 outputs, concatenated in reference return order ----
  float* outb    = (float*)d_out;
  float* x1_last = outb + (size_t)M_ * C_;        // [B,C]
  float* wkv_out = x1_last + (size_t)B_ * C_;     // [B,3,C]
  float* x2_last = wkv_out + (size_t)B_ * 3 * C_; // [B,C]

  const dim3 gCC(C_ / 32, C_ / 32);
  const dim3 gC8(C_ / 256, M_ / 128);      // 8 x 32 = 256 WGs
  const dim3 gF256(F_ / 256, M_ / 256);    // 32 x 16 = 512 WGs (256^2 tiles)

  // ---- attention path ----
  k_layernorm<<<M_, 256, 0, stream>>>(x, ln1_g, ln1_b, h1, x1_last);           // x1 -> h1
  k_mix3<<<M_, 256, 0, stream>>>(h1, att_shift, tmk, tmv, tmr, h2, h3, xrT);   // xk,xv,xr
  k_transpose_cast<<<gCC, 256, 0, stream>>>(Wr, Wslot, C_, C_);
  k_gemm8<4,1><<<gC8, 512, 0, stream>>>(xrT, Wslot, C_, C_, h1, nullptr, nullptr); // r bf16 -> h1
  k_transpose_cast<<<gCC, 256, 0, stream>>>(Wk, Wslot, C_, C_);
  k_gemm8<0,1><<<gC8, 512, 0, stream>>>(h2, Wslot, C_, C_, kBuf, nullptr, nullptr); // k f32 (over xr, dead)
  k_transpose_cast<<<gCC, 256, 0, stream>>>(Wv, Wslot, C_, C_);
  k_gemm8<0,1><<<gC8, 512, 0, stream>>>(h3, Wslot, C_, C_, vBuf, nullptr, nullptr); // v f32
  // WKV: single kernel, block-local scan (no cross-kernel scratch)
  k_wkv_blk<<<dim3(BC_ / CHB), 256, 0, stream>>>(kBuf, vBuf, time_decay, time_first,
                                                 wkv_state, yBuf, wkv_out);
  k_sry<<<1024, 256, 0, stream>>>(h1, yBuf, h2);                                // sry -> h2 (xk dead)
  k_transpose_cast<<<gCC, 256, 0, stream>>>(Wo, Wslot, C_, C_);
  k_gemm8<2,1><<<gC8, 512, 0, stream>>>(h2, Wslot, C_, C_, yBuf, x, nullptr);   // x_att f32 (over y, dead)

  // ---- ffn path ----
  k_layernorm<<<M_, 256, 0, stream>>>(yBuf, ln2_g, ln2_b, h1, x2_last);         // x2 -> h1 (r dead)
  k_mix2<<<M_, 256, 0, stream>>>(h1, ffn_shift, fmk, fmr, h2, h3);              // xk2,xr2 (sry,xv dead)
  k_transpose_cast<<<dim3(F_ / 32, C_ / 32), 256, 0, stream>>>(Fk, Wslot, C_, F_);
  k_gemm256<1,1><<<gF256, 512, 0, stream>>>(h2, Wslot, C_, F_, kf, nullptr, nullptr); // kf bf16 (k,v dead)
  k_transpose_cast<<<dim3(C_ / 32, F_ / 32), 256, 0, stream>>>(Fv, Wslot, F_, C_);
  k_gemm8<0,1><<<gC8, 512, 0, stream>>>(kf, Wslot, F_, C_, kv, nullptr, nullptr); // kv f32 (x2,xk2 dead)
  k_transpose_cast<<<gCC, 256, 0, stream>>>(Fr, Wslot, C_, C_);
  k_gemm8<3,1><<<gC8, 512, 0, stream>>>(h3, Wslot, C_, C_, d_out, yBuf, kv);    // final f32
}

// Round 16
// 629.428 us; speedup vs baseline: 1.3757x; 1.0234x over previous
//
#include <hip/hip_runtime.h>
#include <stdint.h>

#define B_ 2
#define T_ 2048
#define C_ 2048
#define F_ 8192
#define M_ 4096   // B_*T_
#define BC_ 4096  // B_*C_
#define CHB 16    // channels per WKV block
#define TCH 16    // time chunks per WKV block
#define LC2 128   // T_/TCH

typedef __attribute__((ext_vector_type(8))) __bf16 bf16x8;
typedef __attribute__((ext_vector_type(4))) float f32x4;

__device__ __forceinline__ unsigned short f2bf(float f) {
  union { float f; unsigned u; } v; v.f = f;
  unsigned r = v.u + 0x7fffu + ((v.u >> 16) & 1u);
  return (unsigned short)(r >> 16);
}
__device__ __forceinline__ float b2f(unsigned short h) {
  union { unsigned u; float f; } v; v.u = ((unsigned)h) << 16; return v.f;
}

__device__ __forceinline__ void gload16(const void* g, void* l) {
  __builtin_amdgcn_global_load_lds((__attribute__((address_space(1))) void*)g,
                                   (__attribute__((address_space(3))) void*)l,
                                   16, 0, 0);
}

// ---------- transpose + f32->bf16, vectorized uint writes ----------
// Tile: 64(k) x 32(n). LDS [32 n][66 pad] bf16 -> uint-packed coalesced writes.
__device__ __forceinline__ void transpose_tile(
    const float* __restrict__ W, unsigned short* __restrict__ out,
    int K, int N, int k0, int n0) {
  __shared__ unsigned short tile[32][66];
  const int tx = threadIdx.x & 31, ty = threadIdx.x >> 5;
#pragma unroll
  for (int i = 0; i < 8; ++i)
    tile[tx][ty + 8 * i] = f2bf(W[(size_t)(k0 + ty + 8 * i) * N + n0 + tx]);
  __syncthreads();
#pragma unroll
  for (int j = 0; j < 4; ++j) {
    const int nn = ty + 8 * j;
    const unsigned pk = *(const unsigned*)&tile[nn][2 * tx];
    *(unsigned*)&out[(size_t)(n0 + nn) * K + k0 + 2 * tx] = pk;
  }
}

// batched: 4 C_xC_ weights into 4 consecutive 8MB slots
__global__ __launch_bounds__(256) void k_transpose4(
    const float* __restrict__ W0, const float* __restrict__ W1,
    const float* __restrict__ W2, const float* __restrict__ W3,
    unsigned short* __restrict__ WT) {
  const float* W = (blockIdx.z == 0) ? W0 : (blockIdx.z == 1) ? W1
                   : (blockIdx.z == 2) ? W2 : W3;
  unsigned short* out = WT + (size_t)blockIdx.z * C_ * C_;
  transpose_tile(W, out, C_, C_, blockIdx.x * 64, blockIdx.y * 32);
}

// single, generic KxN
__global__ __launch_bounds__(256) void k_transpose1(
    const float* __restrict__ W, unsigned short* __restrict__ WT, int K, int N) {
  transpose_tile(W, WT, K, N, blockIdx.x * 64, blockIdx.y * 32);
}

// ---------- LayerNorm over C=2048 (f32 in, bf16 out + f32 last-row out) ----------
__global__ __launch_bounds__(256) void k_layernorm(
    const float* __restrict__ x, const float* __restrict__ g,
    const float* __restrict__ beta, unsigned short* __restrict__ y,
    float* __restrict__ last_out) {
  const int row = blockIdx.x;
  const int t = row & (T_ - 1);
  const int bi = row >> 11;
  const float* xr = x + (size_t)row * C_;
  const int base = threadIdx.x * 8;
  float lv[8];
  {
    float4 a = *(const float4*)(xr + base);
    float4 b = *(const float4*)(xr + base + 4);
    lv[0]=a.x; lv[1]=a.y; lv[2]=a.z; lv[3]=a.w; lv[4]=b.x; lv[5]=b.y; lv[6]=b.z; lv[7]=b.w;
  }
  float s = 0.f, q = 0.f;
#pragma unroll
  for (int j = 0; j < 8; ++j) { s += lv[j]; q += lv[j] * lv[j]; }
#pragma unroll
  for (int o = 32; o > 0; o >>= 1) { s += __shfl_down(s, o); q += __shfl_down(q, o); }
  __shared__ float rs[4], rq[4];
  if ((threadIdx.x & 63) == 0) { rs[threadIdx.x >> 6] = s; rq[threadIdx.x >> 6] = q; }
  __syncthreads();
  s = rs[0] + rs[1] + rs[2] + rs[3];
  q = rq[0] + rq[1] + rq[2] + rq[3];
  const float mean = s * (1.f / C_);
  const float var = q * (1.f / C_) - mean * mean;
  const float inv = 1.f / sqrtf(var + 1e-5f);
  float ov[8];
  unsigned short o8[8];
#pragma unroll
  for (int j = 0; j < 8; ++j) {
    ov[j] = (lv[j] - mean) * inv * g[base + j] + beta[base + j];
    o8[j] = f2bf(ov[j]);
  }
  *(uint4*)(y + (size_t)row * C_ + base) = *(uint4*)o8;
  if (last_out != nullptr && t == T_ - 1) {
    float* lp = last_out + (size_t)bi * C_ + base;
    *(float4*)lp = make_float4(ov[0], ov[1], ov[2], ov[3]);
    *(float4*)(lp + 4) = make_float4(ov[4], ov[5], ov[6], ov[7]);
  }
}

// ---------- token-shift mix (attention: 3 outputs), bf16 in/out ----------
__global__ __launch_bounds__(256) void k_mix3(
    const unsigned short* __restrict__ x1, const float* __restrict__ shift,
    const float* __restrict__ tmk, const float* __restrict__ tmv,
    const float* __restrict__ tmr,
    unsigned short* __restrict__ xk, unsigned short* __restrict__ xv,
    unsigned short* __restrict__ xr) {
  const int row = blockIdx.x;
  const int t = row & (T_ - 1);
  const int bi = row >> 11;
  const int c0 = threadIdx.x * 8;
  const size_t o = (size_t)row * C_ + c0;
  unsigned short cur8[8];
  *(uint4*)cur8 = *(const uint4*)(x1 + o);
  float pv[8];
  if (t == 0) {
    const float* sp = shift + (size_t)bi * C_ + c0;
#pragma unroll
    for (int j = 0; j < 8; ++j) pv[j] = sp[j];
  } else {
    unsigned short p8[8];
    *(uint4*)p8 = *(const uint4*)(x1 + o - C_);
#pragma unroll
    for (int j = 0; j < 8; ++j) pv[j] = b2f(p8[j]);
  }
  unsigned short ok[8], ov[8], orr[8];
#pragma unroll
  for (int j = 0; j < 8; ++j) {
    const float a = b2f(cur8[j]), p = pv[j];
    const float mk = tmk[c0 + j], mv = tmv[c0 + j], mr = tmr[c0 + j];
    ok[j]  = f2bf(a * mk + p * (1.f - mk));
    ov[j]  = f2bf(a * mv + p * (1.f - mv));
    orr[j] = f2bf(a * mr + p * (1.f - mr));
  }
  *(uint4*)(xk + o) = *(uint4*)ok;
  *(uint4*)(xv + o) = *(uint4*)ov;
  *(uint4*)(xr + o) = *(uint4*)orr;
}

// ---------- token-shift mix (ffn: 2 outputs) ----------
__global__ __launch_bounds__(256) void k_mix2(
    const unsigned short* __restrict__ x2, const float* __restrict__ shift,
    const float* __restrict__ fmk, const float* __restrict__ fmr,
    unsigned short* __restrict__ xk2, unsigned short* __restrict__ xr2) {
  const int row = blockIdx.x;
  const int t = row & (T_ - 1);
  const int bi = row >> 11;
  const int c0 = threadIdx.x * 8;
  const size_t o = (size_t)row * C_ + c0;
  unsigned short cur8[8];
  *(uint4*)cur8 = *(const uint4*)(x2 + o);
  float pv[8];
  if (t == 0) {
    const float* sp = shift + (size_t)bi * C_ + c0;
#pragma unroll
    for (int j = 0; j < 8; ++j) pv[j] = sp[j];
  } else {
    unsigned short p8[8];
    *(uint4*)p8 = *(const uint4*)(x2 + o - C_);
#pragma unroll
    for (int j = 0; j < 8; ++j) pv[j] = b2f(p8[j]);
  }
  unsigned short ok[8], orr[8];
#pragma unroll
  for (int j = 0; j < 8; ++j) {
    const float a = b2f(cur8[j]), p = pv[j];
    const float mk = fmk[c0 + j], mr = fmr[c0 + j];
    ok[j]  = f2bf(a * mk + p * (1.f - mk));
    orr[j] = f2bf(a * mr + p * (1.f - mr));
  }
  *(uint4*)(xk2 + o) = *(uint4*)ok;
  *(uint4*)(xr2 + o) = *(uint4*)orr;
}

// ---------- WKV block-local chunked scan, fused with sigmoid(r)*y -> sry bf16 ----
__global__ __launch_bounds__(256) void k_wkv_sry(
    const float* __restrict__ kk, const float* __restrict__ vv,
    const unsigned short* __restrict__ rr,
    const float* __restrict__ td, const float* __restrict__ tf,
    const float* __restrict__ st, unsigned short* __restrict__ sry,
    float* __restrict__ out_state) {
  __shared__ float sA[TCH][CHB], sB[TCH][CHB], sP[TCH][CHB];
  const int blk = blockIdx.x;
  const int bi = blk >> 7;
  const int tx = threadIdx.x & 15;
  const int ty = threadIdx.x >> 4;
  const int c = ((blk & 127) * CHB) + tx;
  const float w = -expf(td[c]);
  const float u = tf[c];
  const size_t base = (size_t)bi * T_ * C_ + (size_t)ty * LC2 * C_ + c;
  const float* kp = kk + base;
  const float* vp = vv + base;
  float aa = 0.f, bb = 0.f, pp = -1e38f;
#pragma unroll 8
  for (int i = 0; i < LC2; ++i) {
    const float kt = kp[(size_t)i * C_], vt = vp[(size_t)i * C_];
    const float ww2 = pp + w;
    const float p2 = fmaxf(ww2, kt);
    const float e1b = expf(ww2 - p2), e2b = expf(kt - p2);
    aa = e1b * aa + e2b * vt;
    bb = e1b * bb + e2b;
    pp = p2;
  }
  sA[ty][tx] = aa; sB[ty][tx] = bb; sP[ty][tx] = pp;
  __syncthreads();
  if (ty == 0) {
    const float* s0 = st + (size_t)bi * 3 * C_;
    float ca = s0[c], cb = s0[C_ + c], cp = s0[2 * C_ + c];
    const float wL = w * (float)LC2;
#pragma unroll
    for (int j = 0; j < TCH; ++j) {
      const float a2 = sA[j][tx], b2 = sB[j][tx], p2 = sP[j][tx];
      sA[j][tx] = ca; sB[j][tx] = cb; sP[j][tx] = cp;   // exclusive start
      const float pd = cp + wL;
      const float pm = fmaxf(pd, p2);
      const float e1 = expf(pd - pm), e2 = expf(p2 - pm);
      ca = e1 * ca + e2 * a2;
      cb = e1 * cb + e2 * b2;
      cp = pm;
    }
  }
  __syncthreads();
  aa = sA[ty][tx]; bb = sB[ty][tx]; pp = sP[ty][tx];
  const unsigned short* rp = rr + base;
  unsigned short* sp2 = sry + base;
#pragma unroll 4
  for (int i = 0; i < LC2; ++i) {
    const float kt = kp[(size_t)i * C_], vt = vp[(size_t)i * C_];
    const float ww = u + kt;
    const float p = fmaxf(pp, ww);
    const float e1 = expf(pp - p), e2 = expf(ww - p);
    const float yv = (e1 * aa + e2 * vt) / (e1 * bb + e2);
    const float rv = b2f(rp[(size_t)i * C_]);
    const float sg = 1.f / (1.f + expf(-rv));
    sp2[(size_t)i * C_] = f2bf(sg * yv);
    const float ww2 = pp + w;
    const float p2 = fmaxf(ww2, kt);
    const float e1b = expf(ww2 - p2), e2b = expf(kt - p2);
    aa = e1b * aa + e2b * vt;
    bb = e1b * bb + e2b;
    pp = p2;
  }
  if (ty == TCH - 1) {
    float* ob = out_state + (size_t)bi * 3 * C_;
    ob[c] = aa; ob[C_ + c] = bb; ob[2 * C_ + c] = pp;
  }
}

// ---------- bf16 MFMA GEMM: 128x256 tile, BK=64, 8 waves, single-barrier tiles --
// TRIPLE-buffered 144KiB LDS, prefetch distance 2, counted vmcnt(6).
// SWZ=1: 2D-chunked XCD swizzle (m_r = 2*n_r).
// EPI 0: f32; 1: bf16(relu^2); 2: f32(aux1+acc); 3: f32(aux1+sig(acc)*aux2); 4: bf16
template <int EPI, int SWZ>
__global__ __launch_bounds__(512, 1) void k_gemm8(
    const unsigned short* __restrict__ A, const unsigned short* __restrict__ BT,
    int K, int Nn, void* __restrict__ out,
    const float* __restrict__ aux1, const float* __restrict__ aux2) {
  __shared__ unsigned short lds[73728];
  const int tid = threadIdx.x;
  const int lane = tid & 63;
  const int wid = tid >> 6;
  int mBase, nBase;
  if (SWZ) {
    const int gx = gridDim.x, gy = gridDim.y;
    const int wg = blockIdx.y * gx + blockIdx.x;
    const int per = (gx * gy) >> 3;
    const int p = 31 - __clz(per);
    const int nr = 1 << ((p - 1) >> 1);
    const int mr = per / nr;
    if ((gx % nr) == 0 && (gy % mr) == 0) {
      const int gxr = gx / nr;
      const int xcd = wg & 7, idx = wg >> 3;
      const int rr = xcd / gxr, rc = xcd % gxr;
      mBase = (rr * mr + idx / nr) * 128;
      nBase = (rc * nr + idx % nr) * 256;
    } else {
      int w2 = (wg & 7) * per + (wg >> 3);
      mBase = (w2 / gx) * 128;
      nBase = (w2 % gx) * 256;
    }
  } else {
    mBase = blockIdx.y * 128;
    nBase = blockIdx.x * 256;
  }
  const int wr = (wid >> 2) * 64;
  const int wc = (wid & 3) * 64;
  const int r16 = lane & 15, kq = lane >> 4;
  const int lrow = lane >> 3;
  const int lslot = (lane & 7) ^ lrow;
  const int xsw = r16 & 7;
  f32x4 acc[4][4] = {};

  const unsigned short* gA0 = A  + (size_t)(mBase + 0   + wid * 8 + lrow) * K + lslot * 8;
  const unsigned short* gA1 = A  + (size_t)(mBase + 64  + wid * 8 + lrow) * K + lslot * 8;
  const unsigned short* gB0 = BT + (size_t)(nBase + 0   + wid * 8 + lrow) * K + lslot * 8;
  const unsigned short* gB1 = BT + (size_t)(nBase + 64  + wid * 8 + lrow) * K + lslot * 8;
  const unsigned short* gB2 = BT + (size_t)(nBase + 128 + wid * 8 + lrow) * K + lslot * 8;
  const unsigned short* gB3 = BT + (size_t)(nBase + 192 + wid * 8 + lrow) * K + lslot * 8;
  const int wof = wid * 512;
  int aoff[4][2], boff[4][2];
#pragma unroll
  for (int m = 0; m < 4; ++m)
#pragma unroll
    for (int s = 0; s < 2; ++s)
      aoff[m][s] = (wr + m * 16 + r16) * 64 + (((s * 4 + kq) ^ xsw) * 8);
#pragma unroll
  for (int n = 0; n < 4; ++n)
#pragma unroll
    for (int s = 0; s < 2; ++s)
      boff[n][s] = 8192 + (wc + n * 16 + r16) * 64 + (((s * 4 + kq) ^ xsw) * 8);

  const int nt = K >> 6;
  gload16(gA0, &lds[0 + wof]);
  gload16(gA1, &lds[4096 + wof]);
  gload16(gB0, &lds[8192 + wof]);
  gload16(gB1, &lds[12288 + wof]);
  gload16(gB2, &lds[16384 + wof]);
  gload16(gB3, &lds[20480 + wof]);
  gload16(gA0 + 64, &lds[24576 + 0 + wof]);
  gload16(gA1 + 64, &lds[24576 + 4096 + wof]);
  gload16(gB0 + 64, &lds[24576 + 8192 + wof]);
  gload16(gB1 + 64, &lds[24576 + 12288 + wof]);
  gload16(gB2 + 64, &lds[24576 + 16384 + wof]);
  gload16(gB3 + 64, &lds[24576 + 20480 + wof]);
  asm volatile("s_waitcnt vmcnt(6)" ::: "memory");
  asm volatile("s_barrier" ::: "memory");

  int cb = 0;
  for (int t = 0; t < nt; ++t) {
    const int nb = (cb >= 1) ? cb - 1 : 2;
    const int ca = cb * 24576;
    const int nba = nb * 24576;
    const int kb2 = (t + 2) << 6;
    const bool pf = (t + 2) < nt;
    if (pf) {
      gload16(gA0 + kb2, &lds[nba + 0 + wof]);
      gload16(gA1 + kb2, &lds[nba + 4096 + wof]);
      gload16(gB0 + kb2, &lds[nba + 8192 + wof]);
      gload16(gB1 + kb2, &lds[nba + 12288 + wof]);
      gload16(gB2 + kb2, &lds[nba + 16384 + wof]);
      gload16(gB3 + kb2, &lds[nba + 20480 + wof]);
    }
    bf16x8 af[4][2], bq[4][2];
#pragma unroll
    for (int m = 0; m < 4; ++m)
#pragma unroll
      for (int s = 0; s < 2; ++s)
        af[m][s] = *(const bf16x8*)&lds[ca + aoff[m][s]];
#pragma unroll
    for (int n = 0; n < 4; ++n)
#pragma unroll
      for (int s = 0; s < 2; ++s)
        bq[n][s] = *(const bf16x8*)&lds[ca + boff[n][s]];
    __builtin_amdgcn_s_setprio(1);
#pragma unroll
    for (int m = 0; m < 4; ++m)
#pragma unroll
      for (int n = 0; n < 4; ++n)
#pragma unroll
        for (int s = 0; s < 2; ++s)
          acc[m][n] = __builtin_amdgcn_mfma_f32_16x16x32_bf16(
              af[m][s], bq[n][s], acc[m][n], 0, 0, 0);
    __builtin_amdgcn_s_setprio(0);
    if (pf) {
      asm volatile("s_waitcnt vmcnt(6)" ::: "memory");
    } else if (t + 1 < nt) {
      asm volatile("s_waitcnt vmcnt(0)" ::: "memory");
    }
    asm volatile("s_barrier" ::: "memory");
    cb = (cb == 2) ? 0 : cb + 1;
  }

  const int c0 = kq * 4;
#pragma unroll
  for (int m = 0; m < 4; ++m) {
#pragma unroll
    for (int n = 0; n < 4; ++n) {
      const int col = nBase + wc + n * 16 + r16;
#pragma unroll
      for (int e = 0; e < 4; ++e) {
        const int rowg = mBase + wr + m * 16 + c0 + e;
        const size_t idx = (size_t)rowg * Nn + col;
        const float va = acc[m][n][e];
        if (EPI == 0) {
          ((float*)out)[idx] = va;
        } else if (EPI == 1) {
          const float t = va > 0.f ? va : 0.f;
          ((unsigned short*)out)[idx] = f2bf(t * t);
        } else if (EPI == 2) {
          ((float*)out)[idx] = aux1[idx] + va;
        } else if (EPI == 3) {
          const float s = 1.f / (1.f + expf(-va));
          ((float*)out)[idx] = aux1[idx] + s * aux2[idx];
        } else {
          ((unsigned short*)out)[idx] = f2bf(va);
        }
      }
    }
  }
}

// ---------- bf16 MFMA GEMM: 256x256 tile, BK=64, 8 waves of 128x64 ----------
template <int EPI, int SWZ>
__global__ __launch_bounds__(512, 1) void k_gemm256(
    const unsigned short* __restrict__ A, const unsigned short* __restrict__ BT,
    int K, int Nn, void* __restrict__ out,
    const float* __restrict__ aux1, const float* __restrict__ aux2) {
  __shared__ unsigned short lds[65536];
  const int tid = threadIdx.x;
  const int lane = tid & 63;
  const int wid = tid >> 6;
  int mBase, nBase;
  if (SWZ) {
    const int gx = gridDim.x, gy = gridDim.y;
    const int wg = blockIdx.y * gx + blockIdx.x;
    const int per = (gx * gy) >> 3;
    const int p = 31 - __clz(per);
    const int nr = 1 << (p >> 1);
    const int mr = per / nr;
    if ((gx % nr) == 0 && (gy % mr) == 0) {
      const int gxr = gx / nr;
      const int xcd = wg & 7, idx = wg >> 3;
      const int rr = xcd / gxr, rc = xcd % gxr;
      mBase = (rr * mr + idx / nr) * 256;
      nBase = (rc * nr + idx % nr) * 256;
    } else {
      int w2 = (wg & 7) * per + (wg >> 3);
      mBase = (w2 / gx) * 256;
      nBase = (w2 % gx) * 256;
    }
  } else {
    mBase = blockIdx.y * 256;
    nBase = blockIdx.x * 256;
  }
  const int wr = (wid >> 2) * 128;
  const int wc = (wid & 3) * 64;
  const int r16 = lane & 15, kq = lane >> 4;
  const int lrow = lane >> 3;
  const int lslot = (lane & 7) ^ lrow;
  const int xsw = r16 & 7;
  f32x4 acc[8][4] = {};

  const unsigned short* gA[4];
  const unsigned short* gB[4];
#pragma unroll
  for (int j = 0; j < 4; ++j) {
    gA[j] = A  + (size_t)(mBase + j * 64 + wid * 8 + lrow) * K + lslot * 8;
    gB[j] = BT + (size_t)(nBase + j * 64 + wid * 8 + lrow) * K + lslot * 8;
  }
  const int wof = wid * 512;

  const int nt = K >> 6;
#pragma unroll
  for (int j = 0; j < 4; ++j) {
    gload16(gA[j], &lds[j * 4096 + wof]);
    gload16(gB[j], &lds[16384 + j * 4096 + wof]);
  }
  asm volatile("s_waitcnt vmcnt(0)" ::: "memory");
  asm volatile("s_barrier" ::: "memory");

  for (int t = 0; t < nt; ++t) {
    const int ca = (t & 1) * 32768;
    const int nba = ((t + 1) & 1) * 32768;
    const int kb1 = (t + 1) << 6;
    const bool pf = (t + 1) < nt;
    if (pf) {
#pragma unroll
      for (int j = 0; j < 4; ++j) {
        gload16(gA[j] + kb1, &lds[nba + j * 4096 + wof]);
        gload16(gB[j] + kb1, &lds[nba + 16384 + j * 4096 + wof]);
      }
    }
    bf16x8 bq[4][2];
#pragma unroll
    for (int n = 0; n < 4; ++n)
#pragma unroll
      for (int s = 0; s < 2; ++s)
        bq[n][s] = *(const bf16x8*)&lds[ca + 16384 + (wc + n * 16 + r16) * 64 +
                                        (((s * 4 + kq) ^ xsw) * 8)];
#pragma unroll
    for (int qm = 0; qm < 2; ++qm) {
      bf16x8 af[4][2];
#pragma unroll
      for (int m = 0; m < 4; ++m)
#pragma unroll
        for (int s = 0; s < 2; ++s)
          af[m][s] = *(const bf16x8*)&lds[ca + (wr + (qm * 4 + m) * 16 + r16) * 64 +
                                          (((s * 4 + kq) ^ xsw) * 8)];
      __builtin_amdgcn_s_setprio(1);
#pragma unroll
      for (int m = 0; m < 4; ++m)
#pragma unroll
        for (int n = 0; n < 4; ++n)
#pragma unroll
          for (int s = 0; s < 2; ++s)
            acc[qm * 4 + m][n] = __builtin_amdgcn_mfma_f32_16x16x32_bf16(
                af[m][s], bq[n][s], acc[qm * 4 + m][n], 0, 0, 0);
      __builtin_amdgcn_s_setprio(0);
    }
    if (pf) asm volatile("s_waitcnt vmcnt(0)" ::: "memory");
    asm volatile("s_barrier" ::: "memory");
  }

  const int c0 = kq * 4;
#pragma unroll
  for (int m = 0; m < 8; ++m) {
#pragma unroll
    for (int n = 0; n < 4; ++n) {
      const int col = nBase + wc + n * 16 + r16;
#pragma unroll
      for (int e = 0; e < 4; ++e) {
        const int rowg = mBase + wr + m * 16 + c0 + e;
        const size_t idx = (size_t)rowg * Nn + col;
        const float va = acc[m][n][e];
        if (EPI == 0) {
          ((float*)out)[idx] = va;
        } else if (EPI == 1) {
          const float t = va > 0.f ? va : 0.f;
          ((unsigned short*)out)[idx] = f2bf(t * t);
        } else if (EPI == 2) {
          ((float*)out)[idx] = aux1[idx] + va;
        } else if (EPI == 3) {
          const float s = 1.f / (1.f + expf(-va));
          ((float*)out)[idx] = aux1[idx] + s * aux2[idx];
        } else {
          ((unsigned short*)out)[idx] = f2bf(va);
        }
      }
    }
  }
}

extern "C" void kernel_launch(void* const* d_in, const int* in_sizes, int n_in,
                              void* d_out, int out_size, void* d_ws, size_t ws_size,
                              hipStream_t stream) {
  const float* x          = (const float*)d_in[0];
  const float* att_shift  = (const float*)d_in[1];
  const float* wkv_state  = (const float*)d_in[2];
  const float* ffn_shift  = (const float*)d_in[3];
  const float* ln1_g = (const float*)d_in[4];
  const float* ln1_b = (const float*)d_in[5];
  const float* ln2_g = (const float*)d_in[6];
  const float* ln2_b = (const float*)d_in[7];
  const float* tmk = (const float*)d_in[8];
  const float* tmv = (const float*)d_in[9];
  const float* tmr = (const float*)d_in[10];
  const float* time_decay = (const float*)d_in[11];
  const float* time_first = (const float*)d_in[12];
  const float* Wk = (const float*)d_in[13];
  const float* Wv = (const float*)d_in[14];
  const float* Wr = (const float*)d_in[15];
  const float* Wo = (const float*)d_in[16];
  const float* fmk = (const float*)d_in[17];
  const float* fmr = (const float*)d_in[18];
  const float* Fk = (const float*)d_in[19];
  const float* Fr = (const float*)d_in[20];
  const float* Fv = (const float*)d_in[21];

  // ---- 176 MiB workspace, strictly sequential reuse, zero in-flight overlap ----
  const size_t MB = 1ull << 20;
  char* ws = (char*)d_ws;
  if (ws_size < 176 * MB) return;

  unsigned short* Wslot = (unsigned short*)(ws);             //   0.. 32 weight slots
  float*          kBuf  = (float*)(ws + 32 * MB);            //  32.. 64 k f32
  float*          vBuf  = (float*)(ws + 64 * MB);            //  64.. 96 v f32
  float*          yBuf  = (float*)(ws + 96 * MB);            //  96..128 x_att f32
  unsigned short* h1    = (unsigned short*)(ws + 128 * MB);  // 128..144 x1 -> r -> x2
  unsigned short* h2    = (unsigned short*)(ws + 144 * MB);  // 144..160 xk -> sry -> xk2
  unsigned short* h3    = (unsigned short*)(ws + 160 * MB);  // 160..176 xv -> xr2
  unsigned short* xrT   = (unsigned short*)kBuf;             // xr bf16, before k exists
  unsigned short* kf    = (unsigned short*)kBuf;             // 64 MiB: 32..96 (k,v dead)
  float*          kv    = (float*)h1;                        // 32 MiB: 128..160 (x2,xk2 dead)
  // 4 transposed C_xC_ weight slots inside Wslot (8 MiB each)
  unsigned short* sWr = Wslot + 0 * (size_t)C_ * C_;
  unsigned short* sWk = Wslot + 1 * (size_t)C_ * C_;
  unsigned short* sWv = Wslot + 2 * (size_t)C_ * C_;
  unsigned short* sWo = Wslot + 3 * (size_t)C_ * C_;

  // ---- f32 outputs, concatenated in reference return order ----
  float* outb    = (float*)d_out;
  float* x1_last = outb + (size_t)M_ * C_;        // [B,C]
  float* wkv_out = x1_last + (size_t)B_ * C_;     // [B,3,C]
  float* x2_last = wkv_out + (size_t)B_ * 3 * C_; // [B,C]

  const dim3 gC8(C_ / 256, M_ / 128);      // 8 x 32 = 256 WGs
  const dim3 gF256(F_ / 256, M_ / 256);    // 32 x 16 = 512 WGs (256^2 tiles)

  // ---- attention path ----
  k_transpose4<<<dim3(C_ / 64, C_ / 32, 4), 256, 0, stream>>>(Wr, Wk, Wv, Wo, Wslot);
  k_layernorm<<<M_, 256, 0, stream>>>(x, ln1_g, ln1_b, h1, x1_last);           // x1 -> h1
  k_mix3<<<M_, 256, 0, stream>>>(h1, att_shift, tmk, tmv, tmr, h2, h3, xrT);   // xk,xv,xr
  k_gemm8<4,1><<<gC8, 512, 0, stream>>>(xrT, sWr, C_, C_, h1, nullptr, nullptr); // r bf16 -> h1
  k_gemm8<0,1><<<gC8, 512, 0, stream>>>(h2, sWk, C_, C_, kBuf, nullptr, nullptr); // k f32 (over xr, dead)
  k_gemm8<0,1><<<gC8, 512, 0, stream>>>(h3, sWv, C_, C_, vBuf, nullptr, nullptr); // v f32
  // WKV fused with sigmoid(r)*y -> sry bf16 in h2 (xk dead)
  k_wkv_sry<<<dim3(BC_ / CHB), 256, 0, stream>>>(kBuf, vBuf, h1, time_decay, time_first,
                                                 wkv_state, h2, wkv_out);
  k_gemm8<2,1><<<gC8, 512, 0, stream>>>(h2, sWo, C_, C_, yBuf, x, nullptr);     // x_att f32

  // ---- ffn path ----
  k_layernorm<<<M_, 256, 0, stream>>>(yBuf, ln2_g, ln2_b, h1, x2_last);         // x2 -> h1 (r dead)
  k_mix2<<<M_, 256, 0, stream>>>(h1, ffn_shift, fmk, fmr, h2, h3);              // xk2,xr2 (sry,xv dead)
  k_transpose1<<<dim3(C_ / 64, F_ / 32), 256, 0, stream>>>(Fk, Wslot, C_, F_);
  k_gemm256<1,1><<<gF256, 512, 0, stream>>>(h2, Wslot, C_, F_, kf, nullptr, nullptr); // kf bf16 (k,v dead)
  k_transpose1<<<dim3(F_ / 64, C_ / 32), 256, 0, stream>>>(Fv, Wslot, F_, C_);
  k_gemm8<0,1><<<gC8, 512, 0, stream>>>(kf, Wslot, F_, C_, kv, nullptr, nullptr); // kv f32 (x2,xk2 dead)
  k_transpose1<<<dim3(C_ / 64, C_ / 32), 256, 0, stream>>>(Fr, Wslot, C_, C_);
  k_gemm8<3,1><<<gC8, 512, 0, stream>>>(h3, Wslot, C_, C_, d_out, yBuf, kv);    // final f32
}

// Round 17
// 618.001 us; speedup vs baseline: 1.4012x; 1.0185x over previous
//
#include <hip/hip_runtime.h>
#include <stdint.h>

#define B_ 2
#define T_ 2048
#define C_ 2048
#define F_ 8192
#define M_ 4096   // B_*T_
#define BC_ 4096  // B_*C_
#define CHB 16    // channels per WKV block
#define TCH 16    // time chunks per WKV block
#define LC2 128   // T_/TCH

typedef __attribute__((ext_vector_type(8))) __bf16 bf16x8;
typedef __attribute__((ext_vector_type(4))) float f32x4;

__device__ __forceinline__ unsigned short f2bf(float f) {
  union { float f; unsigned u; } v; v.f = f;
  unsigned r = v.u + 0x7fffu + ((v.u >> 16) & 1u);
  return (unsigned short)(r >> 16);
}
__device__ __forceinline__ float b2f(unsigned short h) {
  union { unsigned u; float f; } v; v.u = ((unsigned)h) << 16; return v.f;
}

__device__ __forceinline__ void gload16(const void* g, void* l) {
  __builtin_amdgcn_global_load_lds((__attribute__((address_space(1))) void*)g,
                                   (__attribute__((address_space(3))) void*)l,
                                   16, 0, 0);
}

// ---------- transpose + f32->bf16, vectorized uint writes ----------
__device__ __forceinline__ void transpose_tile(
    const float* __restrict__ W, unsigned short* __restrict__ out,
    int K, int N, int k0, int n0) {
  __shared__ unsigned short tile[32][66];
  const int tx = threadIdx.x & 31, ty = threadIdx.x >> 5;
#pragma unroll
  for (int i = 0; i < 8; ++i)
    tile[tx][ty + 8 * i] = f2bf(W[(size_t)(k0 + ty + 8 * i) * N + n0 + tx]);
  __syncthreads();
#pragma unroll
  for (int j = 0; j < 4; ++j) {
    const int nn = ty + 8 * j;
    const unsigned pk = *(const unsigned*)&tile[nn][2 * tx];
    *(unsigned*)&out[(size_t)(n0 + nn) * K + k0 + 2 * tx] = pk;
  }
}

__global__ __launch_bounds__(256) void k_transpose4(
    const float* __restrict__ W0, const float* __restrict__ W1,
    const float* __restrict__ W2, const float* __restrict__ W3,
    unsigned short* __restrict__ WT) {
  const float* W = (blockIdx.z == 0) ? W0 : (blockIdx.z == 1) ? W1
                   : (blockIdx.z == 2) ? W2 : W3;
  unsigned short* out = WT + (size_t)blockIdx.z * C_ * C_;
  transpose_tile(W, out, C_, C_, blockIdx.x * 64, blockIdx.y * 32);
}

__global__ __launch_bounds__(256) void k_transpose1(
    const float* __restrict__ W, unsigned short* __restrict__ WT, int K, int N) {
  transpose_tile(W, WT, K, N, blockIdx.x * 64, blockIdx.y * 32);
}

// ---------- LayerNorm over C=2048 (f32 in, bf16 out + f32 last-row out) ----------
__global__ __launch_bounds__(256) void k_layernorm(
    const float* __restrict__ x, const float* __restrict__ g,
    const float* __restrict__ beta, unsigned short* __restrict__ y,
    float* __restrict__ last_out) {
  const int row = blockIdx.x;
  const int t = row & (T_ - 1);
  const int bi = row >> 11;
  const float* xr = x + (size_t)row * C_;
  const int base = threadIdx.x * 8;
  float lv[8];
  {
    float4 a = *(const float4*)(xr + base);
    float4 b = *(const float4*)(xr + base + 4);
    lv[0]=a.x; lv[1]=a.y; lv[2]=a.z; lv[3]=a.w; lv[4]=b.x; lv[5]=b.y; lv[6]=b.z; lv[7]=b.w;
  }
  float s = 0.f, q = 0.f;
#pragma unroll
  for (int j = 0; j < 8; ++j) { s += lv[j]; q += lv[j] * lv[j]; }
#pragma unroll
  for (int o = 32; o > 0; o >>= 1) { s += __shfl_down(s, o); q += __shfl_down(q, o); }
  __shared__ float rs[4], rq[4];
  if ((threadIdx.x & 63) == 0) { rs[threadIdx.x >> 6] = s; rq[threadIdx.x >> 6] = q; }
  __syncthreads();
  s = rs[0] + rs[1] + rs[2] + rs[3];
  q = rq[0] + rq[1] + rq[2] + rq[3];
  const float mean = s * (1.f / C_);
  const float var = q * (1.f / C_) - mean * mean;
  const float inv = 1.f / sqrtf(var + 1e-5f);
  float ov[8];
  unsigned short o8[8];
#pragma unroll
  for (int j = 0; j < 8; ++j) {
    ov[j] = (lv[j] - mean) * inv * g[base + j] + beta[base + j];
    o8[j] = f2bf(ov[j]);
  }
  *(uint4*)(y + (size_t)row * C_ + base) = *(uint4*)o8;
  if (last_out != nullptr && t == T_ - 1) {
    float* lp = last_out + (size_t)bi * C_ + base;
    *(float4*)lp = make_float4(ov[0], ov[1], ov[2], ov[3]);
    *(float4*)(lp + 4) = make_float4(ov[4], ov[5], ov[6], ov[7]);
  }
}

// ---------- token-shift mix (attention: 3 outputs), bf16 in/out ----------
__global__ __launch_bounds__(256) void k_mix3(
    const unsigned short* __restrict__ x1, const float* __restrict__ shift,
    const float* __restrict__ tmk, const float* __restrict__ tmv,
    const float* __restrict__ tmr,
    unsigned short* __restrict__ xk, unsigned short* __restrict__ xv,
    unsigned short* __restrict__ xr) {
  const int row = blockIdx.x;
  const int t = row & (T_ - 1);
  const int bi = row >> 11;
  const int c0 = threadIdx.x * 8;
  const size_t o = (size_t)row * C_ + c0;
  unsigned short cur8[8];
  *(uint4*)cur8 = *(const uint4*)(x1 + o);
  float pv[8];
  if (t == 0) {
    const float* sp = shift + (size_t)bi * C_ + c0;
#pragma unroll
    for (int j = 0; j < 8; ++j) pv[j] = sp[j];
  } else {
    unsigned short p8[8];
    *(uint4*)p8 = *(const uint4*)(x1 + o - C_);
#pragma unroll
    for (int j = 0; j < 8; ++j) pv[j] = b2f(p8[j]);
  }
  unsigned short ok[8], ov[8], orr[8];
#pragma unroll
  for (int j = 0; j < 8; ++j) {
    const float a = b2f(cur8[j]), p = pv[j];
    const float mk = tmk[c0 + j], mv = tmv[c0 + j], mr = tmr[c0 + j];
    ok[j]  = f2bf(a * mk + p * (1.f - mk));
    ov[j]  = f2bf(a * mv + p * (1.f - mv));
    orr[j] = f2bf(a * mr + p * (1.f - mr));
  }
  *(uint4*)(xk + o) = *(uint4*)ok;
  *(uint4*)(xv + o) = *(uint4*)ov;
  *(uint4*)(xr + o) = *(uint4*)orr;
}

// ---------- token-shift mix (ffn: 2 outputs) ----------
__global__ __launch_bounds__(256) void k_mix2(
    const unsigned short* __restrict__ x2, const float* __restrict__ shift,
    const float* __restrict__ fmk, const float* __restrict__ fmr,
    unsigned short* __restrict__ xk2, unsigned short* __restrict__ xr2) {
  const int row = blockIdx.x;
  const int t = row & (T_ - 1);
  const int bi = row >> 11;
  const int c0 = threadIdx.x * 8;
  const size_t o = (size_t)row * C_ + c0;
  unsigned short cur8[8];
  *(uint4*)cur8 = *(const uint4*)(x2 + o);
  float pv[8];
  if (t == 0) {
    const float* sp = shift + (size_t)bi * C_ + c0;
#pragma unroll
    for (int j = 0; j < 8; ++j) pv[j] = sp[j];
  } else {
    unsigned short p8[8];
    *(uint4*)p8 = *(const uint4*)(x2 + o - C_);
#pragma unroll
    for (int j = 0; j < 8; ++j) pv[j] = b2f(p8[j]);
  }
  unsigned short ok[8], orr[8];
#pragma unroll
  for (int j = 0; j < 8; ++j) {
    const float a = b2f(cur8[j]), p = pv[j];
    const float mk = fmk[c0 + j], mr = fmr[c0 + j];
    ok[j]  = f2bf(a * mk + p * (1.f - mk));
    orr[j] = f2bf(a * mr + p * (1.f - mr));
  }
  *(uint4*)(xk2 + o) = *(uint4*)ok;
  *(uint4*)(xr2 + o) = *(uint4*)orr;
}

// ---------- WKV block-local chunked scan, fused with sigmoid(r)*y -> sry bf16 ----
__global__ __launch_bounds__(256) void k_wkv_sry(
    const float* __restrict__ kk, const float* __restrict__ vv,
    const unsigned short* __restrict__ rr,
    const float* __restrict__ td, const float* __restrict__ tf,
    const float* __restrict__ st, unsigned short* __restrict__ sry,
    float* __restrict__ out_state) {
  __shared__ float sA[TCH][CHB], sB[TCH][CHB], sP[TCH][CHB];
  const int blk = blockIdx.x;
  const int bi = blk >> 7;
  const int tx = threadIdx.x & 15;
  const int ty = threadIdx.x >> 4;
  const int c = ((blk & 127) * CHB) + tx;
  const float w = -expf(td[c]);
  const float u = tf[c];
  const size_t base = (size_t)bi * T_ * C_ + (size_t)ty * LC2 * C_ + c;
  const float* kp = kk + base;
  const float* vp = vv + base;
  float aa = 0.f, bb = 0.f, pp = -1e38f;
#pragma unroll 8
  for (int i = 0; i < LC2; ++i) {
    const float kt = kp[(size_t)i * C_], vt = vp[(size_t)i * C_];
    const float ww2 = pp + w;
    const float p2 = fmaxf(ww2, kt);
    const float e1b = expf(ww2 - p2), e2b = expf(kt - p2);
    aa = e1b * aa + e2b * vt;
    bb = e1b * bb + e2b;
    pp = p2;
  }
  sA[ty][tx] = aa; sB[ty][tx] = bb; sP[ty][tx] = pp;
  __syncthreads();
  if (ty == 0) {
    const float* s0 = st + (size_t)bi * 3 * C_;
    float ca = s0[c], cb = s0[C_ + c], cp = s0[2 * C_ + c];
    const float wL = w * (float)LC2;
#pragma unroll
    for (int j = 0; j < TCH; ++j) {
      const float a2 = sA[j][tx], b2 = sB[j][tx], p2 = sP[j][tx];
      sA[j][tx] = ca; sB[j][tx] = cb; sP[j][tx] = cp;   // exclusive start
      const float pd = cp + wL;
      const float pm = fmaxf(pd, p2);
      const float e1 = expf(pd - pm), e2 = expf(p2 - pm);
      ca = e1 * ca + e2 * a2;
      cb = e1 * cb + e2 * b2;
      cp = pm;
    }
  }
  __syncthreads();
  aa = sA[ty][tx]; bb = sB[ty][tx]; pp = sP[ty][tx];
  const unsigned short* rp = rr + base;
  unsigned short* sp2 = sry + base;
#pragma unroll 4
  for (int i = 0; i < LC2; ++i) {
    const float kt = kp[(size_t)i * C_], vt = vp[(size_t)i * C_];
    const float ww = u + kt;
    const float p = fmaxf(pp, ww);
    const float e1 = expf(pp - p), e2 = expf(ww - p);
    const float yv = (e1 * aa + e2 * vt) / (e1 * bb + e2);
    const float rv = b2f(rp[(size_t)i * C_]);
    const float sg = 1.f / (1.f + expf(-rv));
    sp2[(size_t)i * C_] = f2bf(sg * yv);
    const float ww2 = pp + w;
    const float p2 = fmaxf(ww2, kt);
    const float e1b = expf(ww2 - p2), e2b = expf(kt - p2);
    aa = e1b * aa + e2b * vt;
    bb = e1b * bb + e2b;
    pp = p2;
  }
  if (ty == TCH - 1) {
    float* ob = out_state + (size_t)bi * 3 * C_;
    ob[c] = aa; ob[C_ + c] = bb; ob[2 * C_ + c] = pp;
  }
}

// ---------- bf16 MFMA GEMM: 128x256 tile, BK=64, 8 waves, single-barrier tiles --
// EPI 0: f32; 1: bf16(relu^2); 2: f32(aux1+acc); 3: f32(aux1+sig(acc)*aux2f32);
// 4: bf16 plain; 5: f32(aux1 + sig(acc)*(b2f(aux2bf)+b2f(aux3bf)))
template <int EPI, int SWZ>
__global__ __launch_bounds__(512, 1) void k_gemm8(
    const unsigned short* __restrict__ A, const unsigned short* __restrict__ BT,
    int K, int Nn, void* __restrict__ out,
    const float* __restrict__ aux1, const void* __restrict__ aux2,
    const void* __restrict__ aux3) {
  __shared__ unsigned short lds[73728];
  const int tid = threadIdx.x;
  const int lane = tid & 63;
  const int wid = tid >> 6;
  int mBase, nBase;
  if (SWZ) {
    const int gx = gridDim.x, gy = gridDim.y;
    const int wg = blockIdx.y * gx + blockIdx.x;
    const int per = (gx * gy) >> 3;
    const int p = 31 - __clz(per);
    const int nr = 1 << ((p - 1) >> 1);
    const int mr = per / nr;
    if ((gx % nr) == 0 && (gy % mr) == 0) {
      const int gxr = gx / nr;
      const int xcd = wg & 7, idx = wg >> 3;
      const int rr = xcd / gxr, rc = xcd % gxr;
      mBase = (rr * mr + idx / nr) * 128;
      nBase = (rc * nr + idx % nr) * 256;
    } else {
      int w2 = (wg & 7) * per + (wg >> 3);
      mBase = (w2 / gx) * 128;
      nBase = (w2 % gx) * 256;
    }
  } else {
    mBase = blockIdx.y * 128;
    nBase = blockIdx.x * 256;
  }
  const int wr = (wid >> 2) * 64;
  const int wc = (wid & 3) * 64;
  const int r16 = lane & 15, kq = lane >> 4;
  const int lrow = lane >> 3;
  const int lslot = (lane & 7) ^ lrow;
  const int xsw = r16 & 7;
  f32x4 acc[4][4] = {};

  const unsigned short* gA0 = A  + (size_t)(mBase + 0   + wid * 8 + lrow) * K + lslot * 8;
  const unsigned short* gA1 = A  + (size_t)(mBase + 64  + wid * 8 + lrow) * K + lslot * 8;
  const unsigned short* gB0 = BT + (size_t)(nBase + 0   + wid * 8 + lrow) * K + lslot * 8;
  const unsigned short* gB1 = BT + (size_t)(nBase + 64  + wid * 8 + lrow) * K + lslot * 8;
  const unsigned short* gB2 = BT + (size_t)(nBase + 128 + wid * 8 + lrow) * K + lslot * 8;
  const unsigned short* gB3 = BT + (size_t)(nBase + 192 + wid * 8 + lrow) * K + lslot * 8;
  const int wof = wid * 512;
  int aoff[4][2], boff[4][2];
#pragma unroll
  for (int m = 0; m < 4; ++m)
#pragma unroll
    for (int s = 0; s < 2; ++s)
      aoff[m][s] = (wr + m * 16 + r16) * 64 + (((s * 4 + kq) ^ xsw) * 8);
#pragma unroll
  for (int n = 0; n < 4; ++n)
#pragma unroll
    for (int s = 0; s < 2; ++s)
      boff[n][s] = 8192 + (wc + n * 16 + r16) * 64 + (((s * 4 + kq) ^ xsw) * 8);

  const int nt = K >> 6;
  gload16(gA0, &lds[0 + wof]);
  gload16(gA1, &lds[4096 + wof]);
  gload16(gB0, &lds[8192 + wof]);
  gload16(gB1, &lds[12288 + wof]);
  gload16(gB2, &lds[16384 + wof]);
  gload16(gB3, &lds[20480 + wof]);
  gload16(gA0 + 64, &lds[24576 + 0 + wof]);
  gload16(gA1 + 64, &lds[24576 + 4096 + wof]);
  gload16(gB0 + 64, &lds[24576 + 8192 + wof]);
  gload16(gB1 + 64, &lds[24576 + 12288 + wof]);
  gload16(gB2 + 64, &lds[24576 + 16384 + wof]);
  gload16(gB3 + 64, &lds[24576 + 20480 + wof]);
  asm volatile("s_waitcnt vmcnt(6)" ::: "memory");
  asm volatile("s_barrier" ::: "memory");

  int cb = 0;
  for (int t = 0; t < nt; ++t) {
    const int nb = (cb >= 1) ? cb - 1 : 2;
    const int ca = cb * 24576;
    const int nba = nb * 24576;
    const int kb2 = (t + 2) << 6;
    const bool pf = (t + 2) < nt;
    if (pf) {
      gload16(gA0 + kb2, &lds[nba + 0 + wof]);
      gload16(gA1 + kb2, &lds[nba + 4096 + wof]);
      gload16(gB0 + kb2, &lds[nba + 8192 + wof]);
      gload16(gB1 + kb2, &lds[nba + 12288 + wof]);
      gload16(gB2 + kb2, &lds[nba + 16384 + wof]);
      gload16(gB3 + kb2, &lds[nba + 20480 + wof]);
    }
    bf16x8 af[4][2], bq[4][2];
#pragma unroll
    for (int m = 0; m < 4; ++m)
#pragma unroll
      for (int s = 0; s < 2; ++s)
        af[m][s] = *(const bf16x8*)&lds[ca + aoff[m][s]];
#pragma unroll
    for (int n = 0; n < 4; ++n)
#pragma unroll
      for (int s = 0; s < 2; ++s)
        bq[n][s] = *(const bf16x8*)&lds[ca + boff[n][s]];
    __builtin_amdgcn_s_setprio(1);
#pragma unroll
    for (int m = 0; m < 4; ++m)
#pragma unroll
      for (int n = 0; n < 4; ++n)
#pragma unroll
        for (int s = 0; s < 2; ++s)
          acc[m][n] = __builtin_amdgcn_mfma_f32_16x16x32_bf16(
              af[m][s], bq[n][s], acc[m][n], 0, 0, 0);
    __builtin_amdgcn_s_setprio(0);
    if (pf) {
      asm volatile("s_waitcnt vmcnt(6)" ::: "memory");
    } else if (t + 1 < nt) {
      asm volatile("s_waitcnt vmcnt(0)" ::: "memory");
    }
    asm volatile("s_barrier" ::: "memory");
    cb = (cb == 2) ? 0 : cb + 1;
  }

  const int c0 = kq * 4;
#pragma unroll
  for (int m = 0; m < 4; ++m) {
#pragma unroll
    for (int n = 0; n < 4; ++n) {
      const int col = nBase + wc + n * 16 + r16;
#pragma unroll
      for (int e = 0; e < 4; ++e) {
        const int rowg = mBase + wr + m * 16 + c0 + e;
        const size_t idx = (size_t)rowg * Nn + col;
        const float va = acc[m][n][e];
        if (EPI == 0) {
          ((float*)out)[idx] = va;
        } else if (EPI == 1) {
          const float t = va > 0.f ? va : 0.f;
          ((unsigned short*)out)[idx] = f2bf(t * t);
        } else if (EPI == 2) {
          ((float*)out)[idx] = aux1[idx] + va;
        } else if (EPI == 3) {
          const float s = 1.f / (1.f + expf(-va));
          ((float*)out)[idx] = aux1[idx] + s * ((const float*)aux2)[idx];
        } else if (EPI == 5) {
          const float s = 1.f / (1.f + expf(-va));
          const float kvv = b2f(((const unsigned short*)aux2)[idx]) +
                            b2f(((const unsigned short*)aux3)[idx]);
          ((float*)out)[idx] = aux1[idx] + s * kvv;
        } else {
          ((unsigned short*)out)[idx] = f2bf(va);
        }
      }
    }
  }
}

// ---------- bf16 MFMA GEMM: 256x256 tile, BK=64, 8 waves of 128x64 ----------
// Supports K-split via blockIdx.z: Koff = z*Klen, out += z*outStride (bytes).
template <int EPI, int SWZ>
__global__ __launch_bounds__(512, 1) void k_gemm256(
    const unsigned short* __restrict__ A, const unsigned short* __restrict__ BT,
    int K, int Klen, int Nn, void* __restrict__ out, size_t outStride) {
  __shared__ unsigned short lds[65536];
  const int tid = threadIdx.x;
  const int lane = tid & 63;
  const int wid = tid >> 6;
  const int Koff = blockIdx.z * Klen;
  void* outz = (char*)out + (size_t)blockIdx.z * outStride;
  int mBase, nBase;
  if (SWZ) {
    const int gx = gridDim.x, gy = gridDim.y;
    const int wg = blockIdx.y * gx + blockIdx.x;
    const int per = (gx * gy) >> 3;
    const int p = 31 - __clz(per);
    const int nr = 1 << (p >> 1);
    const int mr = per / nr;
    if ((gx % nr) == 0 && (gy % mr) == 0) {
      const int gxr = gx / nr;
      const int xcd = wg & 7, idx = wg >> 3;
      const int rr = xcd / gxr, rc = xcd % gxr;
      mBase = (rr * mr + idx / nr) * 256;
      nBase = (rc * nr + idx % nr) * 256;
    } else {
      int w2 = (wg & 7) * per + (wg >> 3);
      mBase = (w2 / gx) * 256;
      nBase = (w2 % gx) * 256;
    }
  } else {
    mBase = blockIdx.y * 256;
    nBase = blockIdx.x * 256;
  }
  const int wr = (wid >> 2) * 128;
  const int wc = (wid & 3) * 64;
  const int r16 = lane & 15, kq = lane >> 4;
  const int lrow = lane >> 3;
  const int lslot = (lane & 7) ^ lrow;
  const int xsw = r16 & 7;
  f32x4 acc[8][4] = {};

  const unsigned short* gA[4];
  const unsigned short* gB[4];
#pragma unroll
  for (int j = 0; j < 4; ++j) {
    gA[j] = A  + (size_t)(mBase + j * 64 + wid * 8 + lrow) * K + Koff + lslot * 8;
    gB[j] = BT + (size_t)(nBase + j * 64 + wid * 8 + lrow) * K + Koff + lslot * 8;
  }
  const int wof = wid * 512;

  const int nt = Klen >> 6;
#pragma unroll
  for (int j = 0; j < 4; ++j) {
    gload16(gA[j], &lds[j * 4096 + wof]);
    gload16(gB[j], &lds[16384 + j * 4096 + wof]);
  }
  asm volatile("s_waitcnt vmcnt(0)" ::: "memory");
  asm volatile("s_barrier" ::: "memory");

  for (int t = 0; t < nt; ++t) {
    const int ca = (t & 1) * 32768;
    const int nba = ((t + 1) & 1) * 32768;
    const int kb1 = (t + 1) << 6;
    const bool pf = (t + 1) < nt;
    if (pf) {
#pragma unroll
      for (int j = 0; j < 4; ++j) {
        gload16(gA[j] + kb1, &lds[nba + j * 4096 + wof]);
        gload16(gB[j] + kb1, &lds[nba + 16384 + j * 4096 + wof]);
      }
    }
    bf16x8 bq[4][2];
#pragma unroll
    for (int n = 0; n < 4; ++n)
#pragma unroll
      for (int s = 0; s < 2; ++s)
        bq[n][s] = *(const bf16x8*)&lds[ca + 16384 + (wc + n * 16 + r16) * 64 +
                                        (((s * 4 + kq) ^ xsw) * 8)];
#pragma unroll
    for (int qm = 0; qm < 2; ++qm) {
      bf16x8 af[4][2];
#pragma unroll
      for (int m = 0; m < 4; ++m)
#pragma unroll
        for (int s = 0; s < 2; ++s)
          af[m][s] = *(const bf16x8*)&lds[ca + (wr + (qm * 4 + m) * 16 + r16) * 64 +
                                          (((s * 4 + kq) ^ xsw) * 8)];
      __builtin_amdgcn_s_setprio(1);
#pragma unroll
      for (int m = 0; m < 4; ++m)
#pragma unroll
        for (int n = 0; n < 4; ++n)
#pragma unroll
          for (int s = 0; s < 2; ++s)
            acc[qm * 4 + m][n] = __builtin_amdgcn_mfma_f32_16x16x32_bf16(
                af[m][s], bq[n][s], acc[qm * 4 + m][n], 0, 0, 0);
      __builtin_amdgcn_s_setprio(0);
    }
    if (pf) asm volatile("s_waitcnt vmcnt(0)" ::: "memory");
    asm volatile("s_barrier" ::: "memory");
  }

  const int c0 = kq * 4;
#pragma unroll
  for (int m = 0; m < 8; ++m) {
#pragma unroll
    for (int n = 0; n < 4; ++n) {
      const int col = nBase + wc + n * 16 + r16;
#pragma unroll
      for (int e = 0; e < 4; ++e) {
        const int rowg = mBase + wr + m * 16 + c0 + e;
        const size_t idx = (size_t)rowg * Nn + col;
        const float va = acc[m][n][e];
        if (EPI == 0) {
          ((float*)outz)[idx] = va;
        } else if (EPI == 1) {
          const float t = va > 0.f ? va : 0.f;
          ((unsigned short*)outz)[idx] = f2bf(t * t);
        } else {
          ((unsigned short*)outz)[idx] = f2bf(va);
        }
      }
    }
  }
}

extern "C" void kernel_launch(void* const* d_in, const int* in_sizes, int n_in,
                              void* d_out, int out_size, void* d_ws, size_t ws_size,
                              hipStream_t stream) {
  const float* x          = (const float*)d_in[0];
  const float* att_shift  = (const float*)d_in[1];
  const float* wkv_state  = (const float*)d_in[2];
  const float* ffn_shift  = (const float*)d_in[3];
  const float* ln1_g = (const float*)d_in[4];
  const float* ln1_b = (const float*)d_in[5];
  const float* ln2_g = (const float*)d_in[6];
  const float* ln2_b = (const float*)d_in[7];
  const float* tmk = (const float*)d_in[8];
  const float* tmv = (const float*)d_in[9];
  const float* tmr = (const float*)d_in[10];
  const float* time_decay = (const float*)d_in[11];
  const float* time_first = (const float*)d_in[12];
  const float* Wk = (const float*)d_in[13];
  const float* Wv = (const float*)d_in[14];
  const float* Wr = (const float*)d_in[15];
  const float* Wo = (const float*)d_in[16];
  const float* fmk = (const float*)d_in[17];
  const float* fmr = (const float*)d_in[18];
  const float* Fk = (const float*)d_in[19];
  const float* Fr = (const float*)d_in[20];
  const float* Fv = (const float*)d_in[21];

  // ---- 176 MiB workspace, strictly sequential reuse, zero in-flight overlap ----
  const size_t MB = 1ull << 20;
  char* ws = (char*)d_ws;
  if (ws_size < 176 * MB) return;

  unsigned short* Wslot = (unsigned short*)(ws);             //   0.. 32 weight slots
  float*          kBuf  = (float*)(ws + 32 * MB);            //  32.. 64 k f32
  float*          vBuf  = (float*)(ws + 64 * MB);            //  64.. 96 v f32
  float*          yBuf  = (float*)(ws + 96 * MB);            //  96..128 x_att f32
  unsigned short* h1    = (unsigned short*)(ws + 128 * MB);  // 128..144 x1 -> r -> x2
  unsigned short* h2    = (unsigned short*)(ws + 144 * MB);  // 144..160 xk -> sry -> xk2
  unsigned short* h3    = (unsigned short*)(ws + 160 * MB);  // 160..176 xv -> xr2
  unsigned short* xrT   = (unsigned short*)kBuf;             // xr bf16, before k exists
  unsigned short* kf    = (unsigned short*)kBuf;             // 64 MiB: 32..96 (k,v dead)
  unsigned short* kvp   = (unsigned short*)h1;               // 2x16 MiB bf16 partials:
                                                             // 128..160 (x2,xk2 dead)
  // 4 transposed C_xC_ weight slots inside Wslot (8 MiB each)
  unsigned short* sWr = Wslot + 0 * (size_t)C_ * C_;
  unsigned short* sWk = Wslot + 1 * (size_t)C_ * C_;
  unsigned short* sWv = Wslot + 2 * (size_t)C_ * C_;
  unsigned short* sWo = Wslot + 3 * (size_t)C_ * C_;

  // ---- f32 outputs, concatenated in reference return order ----
  float* outb    = (float*)d_out;
  float* x1_last = outb + (size_t)M_ * C_;        // [B,C]
  float* wkv_out = x1_last + (size_t)B_ * C_;     // [B,3,C]
  float* x2_last = wkv_out + (size_t)B_ * 3 * C_; // [B,C]

  const dim3 gC8(C_ / 256, M_ / 128);       // 8 x 32 = 256 WGs
  const dim3 gF256(F_ / 256, M_ / 256);     // 32 x 16 = 512 WGs
  const dim3 gKV(C_ / 256, M_ / 256, 2);    // 8 x 16 x 2 = 256 WGs (split-K)

  // ---- attention path ----
  k_transpose4<<<dim3(C_ / 64, C_ / 32, 4), 256, 0, stream>>>(Wr, Wk, Wv, Wo, Wslot);
  k_layernorm<<<M_, 256, 0, stream>>>(x, ln1_g, ln1_b, h1, x1_last);           // x1 -> h1
  k_mix3<<<M_, 256, 0, stream>>>(h1, att_shift, tmk, tmv, tmr, h2, h3, xrT);   // xk,xv,xr
  k_gemm8<4,1><<<gC8, 512, 0, stream>>>(xrT, sWr, C_, C_, h1, nullptr, nullptr, nullptr); // r
  k_gemm8<0,1><<<gC8, 512, 0, stream>>>(h2, sWk, C_, C_, kBuf, nullptr, nullptr, nullptr); // k
  k_gemm8<0,1><<<gC8, 512, 0, stream>>>(h3, sWv, C_, C_, vBuf, nullptr, nullptr, nullptr); // v
  k_wkv_sry<<<dim3(BC_ / CHB), 256, 0, stream>>>(kBuf, vBuf, h1, time_decay, time_first,
                                                 wkv_state, h2, wkv_out);      // sry -> h2
  k_gemm8<2,1><<<gC8, 512, 0, stream>>>(h2, sWo, C_, C_, yBuf, x, nullptr, nullptr); // x_att

  // ---- ffn path ----
  k_layernorm<<<M_, 256, 0, stream>>>(yBuf, ln2_g, ln2_b, h1, x2_last);         // x2 -> h1
  k_mix2<<<M_, 256, 0, stream>>>(h1, ffn_shift, fmk, fmr, h2, h3);              // xk2,xr2
  k_transpose1<<<dim3(C_ / 64, F_ / 32), 256, 0, stream>>>(Fk, Wslot, C_, F_);
  k_gemm256<1,1><<<gF256, 512, 0, stream>>>(h2, Wslot, C_, C_, F_, kf, 0);      // kf bf16
  k_transpose1<<<dim3(F_ / 64, C_ / 32), 256, 0, stream>>>(Fv, Wslot, F_, C_);
  // kv split-K=2: two bf16 partials (16 MiB apart) over full machine
  k_gemm256<4,1><<<gKV, 512, 0, stream>>>(kf, Wslot, F_, F_ / 2, C_, kvp, 16 * MB);
  k_transpose1<<<dim3(C_ / 64, C_ / 32), 256, 0, stream>>>(Fr, Wslot, C_, C_);
  k_gemm8<5,1><<<gC8, 512, 0, stream>>>(h3, Wslot, C_, C_, d_out, yBuf,
                                        kvp, kvp + 8 * (size_t)MB);             // final f32
}